// Round 1
// baseline (2580.228 us; speedup 1.0000x reference)
//
#include <hip/hip_runtime.h>
#include <hip/hip_bf16.h>
#include <math.h>

// ---------------- problem constants ----------------
#define BATCH 2
#define CDIM 128
#define SS 16
#define HH_ 32
#define WW_ 32
#define NSP (SS*HH_*WW_)          // 16384 spatial tokens per batch (local)
#define GS 8
#define GH 16
#define GW 16
#define GN (GS*GH*GW)             // 2048 global tokens per batch
#define HEADS 8
#define DH 16
#define NW 256                    // p1*p2*p3 = 4*8*8
#define P1 4
#define P2 8
#define P3 8
#define W3L 64                    // 4*4*4 local tokens per window
#define W3G 8                     // 2*2*2 global tokens per window
#define TOPK 4
#define W3 (W3L + TOPK*W3G)       // 96
#define LN_EPS 1e-6f
#define ROUTE_SCALE 0.08838834764831845f   // 128^-0.5
#define GATTN_SCALE 0.25f                  // DH^-0.5

__device__ __forceinline__ float block_sum_128(float v, float* red, int c) {
    red[c] = v; __syncthreads();
#pragma unroll
    for (int s = 64; s > 0; s >>= 1) { if (c < s) red[c] += red[c + s]; __syncthreads(); }
    float r = red[0]; __syncthreads();
    return r;
}

__device__ __forceinline__ float gelu_exact(float x) {
    return 0.5f * x * (1.0f + erff(x * 0.70710678118654752f));
}

// K1: transpose x_g_in -> xg [B,GN,C]; LN; qkv proj -> qg/kg/vg [B,H,GN,DH]
__global__ void k_global_qkv(const float* __restrict__ xg_in,
                             const float* __restrict__ qkv_w, const float* __restrict__ qkv_b,
                             const float* __restrict__ ln_g, const float* __restrict__ ln_b,
                             float* __restrict__ xg, float* __restrict__ qg,
                             float* __restrict__ kg, float* __restrict__ vg) {
    int t = blockIdx.x;            // b*GN + n
    int b = t / GN, n = t % GN;
    int c = threadIdx.x;
    __shared__ float h[CDIM];
    __shared__ float red[CDIM];
    float v = xg_in[((size_t)(b * CDIM + c)) * GN + n];
    xg[(size_t)t * CDIM + c] = v;
    float mu = block_sum_128(v, red, c) * (1.0f / CDIM);
    float d = v - mu;
    float var = block_sum_128(d * d, red, c) * (1.0f / CDIM);
    float hn = d * rsqrtf(var + LN_EPS) * ln_g[c] + ln_b[c];
    h[c] = hn; __syncthreads();
#pragma unroll
    for (int part = 0; part < 3; part++) {
        int j = part * CDIM + c;
        float acc = qkv_b[j];
        for (int k = 0; k < CDIM; k++) acc += h[k] * qkv_w[k * (3 * CDIM) + j];
        int head = c / DH, dd = c % DH;
        float* dst = (part == 0) ? qg : (part == 1) ? kg : vg;
        dst[(((size_t)(b * HEADS + head)) * GN + n) * DH + dd] = acc;
    }
}

// K2: flash attention, one query per thread. grid = B*H*(GN/256), block 256.
#define KT 64
__global__ void k_global_attn(const float* __restrict__ qg, const float* __restrict__ kg,
                              const float* __restrict__ vg, float* __restrict__ og) {
    int blk = blockIdx.x;
    int chunks = GN / 256;
    int qchunk = blk % chunks;
    int bh = blk / chunks;
    int b = bh / HEADS, h = bh % HEADS;
    const float* qp = qg + (size_t)bh * GN * DH;
    const float* kp = kg + (size_t)bh * GN * DH;
    const float* vp = vg + (size_t)bh * GN * DH;
    int q = qchunk * 256 + threadIdx.x;
    float qv[DH];
#pragma unroll
    for (int d = 0; d < DH; d++) qv[d] = qp[q * DH + d] * GATTN_SCALE;
    float m = -1e30f, l = 0.f, o[DH];
#pragma unroll
    for (int d = 0; d < DH; d++) o[d] = 0.f;
    __shared__ float ks[KT][DH];
    __shared__ float vs[KT][DH];
    for (int t0 = 0; t0 < GN; t0 += KT) {
        for (int i = threadIdx.x; i < KT * DH; i += 256) {
            ks[i / DH][i % DH] = kp[(t0 + i / DH) * DH + i % DH];
            vs[i / DH][i % DH] = vp[(t0 + i / DH) * DH + i % DH];
        }
        __syncthreads();
        for (int j = 0; j < KT; j++) {
            float s = 0.f;
#pragma unroll
            for (int d = 0; d < DH; d++) s += qv[d] * ks[j][d];
            float mn = fmaxf(m, s);
            float corr = __expf(m - mn);
            float p = __expf(s - mn);
            l = l * corr + p;
#pragma unroll
            for (int d = 0; d < DH; d++) o[d] = o[d] * corr + p * vs[j][d];
            m = mn;
        }
        __syncthreads();
    }
    float inv = 1.f / l;
#pragma unroll
    for (int d = 0; d < DH; d++)
        og[((size_t)(b * GN + q)) * CDIM + h * DH + d] = o[d] * inv;
}

// K3: proj + residual + LN + MLP + residual -> xg4; also write g_out (transposed)
__global__ void k_global_mlp(const float* __restrict__ og, const float* __restrict__ xg,
                             const float* __restrict__ proj_w, const float* __restrict__ proj_b,
                             const float* __restrict__ ln_g, const float* __restrict__ ln_b,
                             const float* __restrict__ w1, const float* __restrict__ b1,
                             const float* __restrict__ w2, const float* __restrict__ b2,
                             float* __restrict__ xg4, float* __restrict__ gout) {
    int t = blockIdx.x; int b = t / GN, n = t % GN;
    int c = threadIdx.x;
    __shared__ float orow[CDIM];
    __shared__ float h[CDIM];
    __shared__ float h1[4 * CDIM];
    __shared__ float red[CDIM];
    orow[c] = og[(size_t)t * CDIM + c];
    float xv = xg[(size_t)t * CDIM + c];
    __syncthreads();
    float acc = proj_b[c];
    for (int k = 0; k < CDIM; k++) acc += orow[k] * proj_w[k * CDIM + c];
    float xn = acc + xv;
    float mu = block_sum_128(xn, red, c) * (1.0f / CDIM);
    float d = xn - mu;
    float var = block_sum_128(d * d, red, c) * (1.0f / CDIM);
    h[c] = d * rsqrtf(var + LN_EPS) * ln_g[c] + ln_b[c];
    __syncthreads();
#pragma unroll
    for (int part = 0; part < 4; part++) {
        int j = part * CDIM + c;
        float a = b1[j];
        for (int k = 0; k < CDIM; k++) a += h[k] * w1[k * (4 * CDIM) + j];
        h1[j] = gelu_exact(a);
    }
    __syncthreads();
    float a2 = b2[c];
    for (int k = 0; k < 4 * CDIM; k++) a2 += h1[k] * w2[k * CDIM + c];
    float outv = xn + a2;
    xg4[(size_t)t * CDIM + c] = outv;
    gout[((size_t)(b * CDIM + c)) * GN + n] = outv;
}

// K4a: per-window mean over 8 global tokens; qh/kh projections. grid B*NW, block 128.
__global__ void k_routing_qk(const float* __restrict__ xg4,
                             const float* __restrict__ rq_w, const float* __restrict__ rq_b,
                             const float* __restrict__ rk_w, const float* __restrict__ rk_b,
                             float* __restrict__ qh, float* __restrict__ kh) {
    int wid = blockIdx.x; int b = wid / NW, n = wid % NW;
    int c = threadIdx.x;
    int i1 = n / (P2 * P3), i2 = (n / P3) % P2, i3 = n % P3;
    __shared__ float g[CDIM];
    float s = 0.f;
#pragma unroll
    for (int j = 0; j < W3G; j++) {
        int ds = j >> 2, dh = (j >> 1) & 1, dw = j & 1;
        int gs = i1 * 2 + ds, gh = i2 * 2 + dh, gw = i3 * 2 + dw;
        int gi = (gs * GH + gh) * GW + gw;
        s += xg4[((size_t)(b * GN + gi)) * CDIM + c];
    }
    g[c] = s * (1.0f / W3G);
    __syncthreads();
    float aq = rq_b[c], ak = rk_b[c];
    for (int k = 0; k < CDIM; k++) { float gv = g[k]; aq += gv * rq_w[k * CDIM + c]; ak += gv * rk_w[k * CDIM + c]; }
    qh[(size_t)wid * CDIM + c] = aq;
    kh[(size_t)wid * CDIM + c] = ak;
}

// K4b: logits (256 per window) + top-4 argmax. grid B*NW, block 256.
__global__ void k_topk(const float* __restrict__ qh, const float* __restrict__ kh,
                       int* __restrict__ tidx) {
    int wid = blockIdx.x; int b = wid / NW;
    int m = threadIdx.x;
    __shared__ float q[CDIM];
    __shared__ float lv[NW];
    __shared__ int li[NW];
    if (m < CDIM) q[m] = qh[(size_t)wid * CDIM + m] * ROUTE_SCALE;
    __syncthreads();
    float acc = 0.f;
    const float* kr = kh + ((size_t)b * NW + m) * CDIM;
    for (int k = 0; k < CDIM; k++) acc += q[k] * kr[k];
#pragma unroll
    for (int sel = 0; sel < TOPK; sel++) {
        lv[m] = acc; li[m] = m; __syncthreads();
#pragma unroll
        for (int s = 128; s > 0; s >>= 1) {
            if (m < s) {
                if (lv[m + s] > lv[m] || (lv[m + s] == lv[m] && li[m + s] < li[m])) {
                    lv[m] = lv[m + s]; li[m] = li[m + s];
                }
            }
            __syncthreads();
        }
        int best = li[0]; __syncthreads();
        if (m == best) acc = -1e30f;
        if (m == 0) tidx[wid * TOPK + sel] = best;
    }
}

// K5: build LN(sc) [B,NW,96,C]. grid B*NW*W3, block 128.
__global__ void k_build_lnsc(const float* __restrict__ x_in, const float* __restrict__ xg4,
                             const int* __restrict__ tidx,
                             const float* __restrict__ ln_g, const float* __restrict__ ln_b,
                             float* __restrict__ lnsc) {
    int blk = blockIdx.x;
    int t = blk % W3; int wn = blk / W3;
    int b = wn / NW, n = wn % NW;
    int c = threadIdx.x;
    int i1 = n / (P2 * P3), i2 = (n / P3) % P2, i3 = n % P3;
    float v;
    if (t < W3L) {
        int ds = t >> 4, dh = (t >> 2) & 3, dw = t & 3;
        int s = i1 * 4 + ds, hh = i2 * 4 + dh, ww = i3 * 4 + dw;
        v = x_in[(((size_t)(b * CDIM + c) * SS + s) * HH_ + hh) * WW_ + ww];
    } else {
        int k = (t - W3L) / W3G, j = (t - W3L) % W3G;
        int g = tidx[wn * TOPK + k];
        int gi1 = g / (P2 * P3), gi2 = (g / P3) % P2, gi3 = g % P3;
        int ds = j >> 2, dh = (j >> 1) & 1, dw = j & 1;
        int s = gi1 * 2 + ds, hh = gi2 * 2 + dh, ww = gi3 * 2 + dw;
        int gi = (s * GH + hh) * GW + ww;
        v = xg4[((size_t)(b * GN + gi)) * CDIM + c];
    }
    __shared__ float red[CDIM];
    float mu = block_sum_128(v, red, c) * (1.0f / CDIM);
    float d = v - mu;
    float var = block_sum_128(d * d, red, c) * (1.0f / CDIM);
    lnsc[(size_t)blk * CDIM + c] = d * rsqrtf(var + LN_EPS) * ln_g[c] + ln_b[c];
}

// K6: local attention, one (window, head) per 64-thread block. grid B*NW*HEADS.
__global__ __launch_bounds__(64) void k_local_attn(const float* __restrict__ lnsc,
                                                   const float* __restrict__ gqkv_w,
                                                   const float* __restrict__ gqkv_b,
                                                   float* __restrict__ aout) {
    int blk = blockIdx.x;
    int h = blk % HEADS; int wn = blk / HEADS;
    int tid = threadIdx.x;
    __shared__ float X[W3][CDIM + 1];    // +1 pad: avoid 64-way bank conflict on X[q][k]
    __shared__ float Ks[W3][DH];
    __shared__ float Vs[W3][DH];
    const float* src = lnsc + (size_t)wn * W3 * CDIM;
    for (int i = tid; i < W3 * CDIM; i += 64) X[i / CDIM][i % CDIM] = src[i];
    __syncthreads();
    int ck0 = CDIM + h * DH;       // k columns
    int cv0 = 2 * CDIM + h * DH;   // v columns
    for (int i = tid; i < W3 * DH; i += 64) {
        int r = i / DH, d = i % DH;
        float ak = gqkv_b[ck0 + d], av = gqkv_b[cv0 + d];
        for (int k = 0; k < CDIM; k++) {
            float x = X[r][k];
            ak += x * gqkv_w[k * (3 * CDIM) + ck0 + d];
            av += x * gqkv_w[k * (3 * CDIM) + cv0 + d];
        }
        Ks[r][d] = ak; Vs[r][d] = av;
    }
    __syncthreads();
    // queries 0..63 only (out[:, :, :w3l] is all that's consumed)
    int q = tid;
    int cq0 = h * DH;
    float qv[DH];
#pragma unroll
    for (int d = 0; d < DH; d++) {
        float a = gqkv_b[cq0 + d];
        for (int k = 0; k < CDIM; k++) a += X[q][k] * gqkv_w[k * (3 * CDIM) + cq0 + d];
        qv[d] = a * ROUTE_SCALE;
    }
    float sc[W3];
    float mx = -1e30f;
    for (int r = 0; r < W3; r++) {
        float s = 0.f;
#pragma unroll
        for (int d = 0; d < DH; d++) s += qv[d] * Ks[r][d];
        sc[r] = s; mx = fmaxf(mx, s);
    }
    float sum = 0.f;
    for (int r = 0; r < W3; r++) { float p = __expf(sc[r] - mx); sc[r] = p; sum += p; }
    float inv = 1.f / sum;
    float o[DH];
#pragma unroll
    for (int d = 0; d < DH; d++) o[d] = 0.f;
    for (int r = 0; r < W3; r++) {
        float p = sc[r];
#pragma unroll
        for (int d = 0; d < DH; d++) o[d] += p * Vs[r][d];
    }
    float* dst = aout + ((size_t)wn * W3L + q) * CDIM + h * DH;
#pragma unroll
    for (int d = 0; d < DH; d++) dst[d] = o[d] * inv;
}

// K7: wo proj + residual(shortcut from x_in) -> lpre [B, sp, C]. grid B*NW*64, block 128.
__global__ void k_wo(const float* __restrict__ aout, const float* __restrict__ wo_w,
                     const float* __restrict__ wo_b, const float* __restrict__ x_in,
                     float* __restrict__ lpre) {
    int blk = blockIdx.x;
    int t = blk % W3L; int wn = blk / W3L;
    int b = wn / NW, n = wn % NW;
    int c = threadIdx.x;
    __shared__ float row[CDIM];
    row[c] = aout[(size_t)blk * CDIM + c];
    __syncthreads();
    float a = wo_b[c];
    for (int k = 0; k < CDIM; k++) a += row[k] * wo_w[k * CDIM + c];
    int i1 = n / (P2 * P3), i2 = (n / P3) % P2, i3 = n % P3;
    int ds = t >> 4, dh = (t >> 2) & 3, dw = t & 3;
    int s = i1 * 4 + ds, hh = i2 * 4 + dh, ww = i3 * 4 + dw;
    float shortcut = x_in[(((size_t)(b * CDIM + c) * SS + s) * HH_ + hh) * WW_ + ww];
    lpre[(((size_t)(b * SS + s) * HH_ + hh) * WW_ + ww) * CDIM + c] = a + shortcut;
}

// K8: LN + MLP2 + residual, write l_out transposed. grid B*NSP, block 128.
__global__ void k_mlp2(const float* __restrict__ lpre,
                       const float* __restrict__ ln_g, const float* __restrict__ ln_b,
                       const float* __restrict__ w1, const float* __restrict__ b1,
                       const float* __restrict__ w2, const float* __restrict__ b2,
                       float* __restrict__ lout) {
    int t = blockIdx.x;
    int b = t / NSP, sp = t % NSP;
    int c = threadIdx.x;
    __shared__ float h[CDIM];
    __shared__ float h1[4 * CDIM];
    __shared__ float red[CDIM];
    float xv = lpre[(size_t)t * CDIM + c];
    float mu = block_sum_128(xv, red, c) * (1.0f / CDIM);
    float d = xv - mu;
    float var = block_sum_128(d * d, red, c) * (1.0f / CDIM);
    h[c] = d * rsqrtf(var + LN_EPS) * ln_g[c] + ln_b[c];
    __syncthreads();
#pragma unroll
    for (int part = 0; part < 4; part++) {
        int j = part * CDIM + c;
        float a = b1[j];
        for (int k = 0; k < CDIM; k++) a += h[k] * w1[k * (4 * CDIM) + j];
        h1[j] = gelu_exact(a);
    }
    __syncthreads();
    float a2 = b2[c];
    for (int k = 0; k < 4 * CDIM; k++) a2 += h1[k] * w2[k * CDIM + c];
    lout[((size_t)(b * CDIM + c)) * NSP + sp] = xv + a2;
}

extern "C" void kernel_launch(void* const* d_in, const int* in_sizes, int n_in,
                              void* d_out, int out_size, void* d_ws, size_t ws_size,
                              hipStream_t stream) {
    const float* x_in   = (const float*)d_in[0];
    const float* xg_in  = (const float*)d_in[1];
    const float* qkv_w  = (const float*)d_in[2];
    const float* qkv_b  = (const float*)d_in[3];
    const float* proj_w = (const float*)d_in[4];
    const float* proj_b = (const float*)d_in[5];
    const float* ln_g   = (const float*)d_in[6];
    const float* ln_b   = (const float*)d_in[7];
    const float* mlp_w1 = (const float*)d_in[8];
    const float* mlp_b1 = (const float*)d_in[9];
    const float* mlp_w2 = (const float*)d_in[10];
    const float* mlp_b2 = (const float*)d_in[11];
    const float* rq_w   = (const float*)d_in[12];
    const float* rq_b   = (const float*)d_in[13];
    const float* rk_w   = (const float*)d_in[14];
    const float* rk_b   = (const float*)d_in[15];
    const float* gqkv_w = (const float*)d_in[16];
    const float* gqkv_b = (const float*)d_in[17];
    const float* wo_w   = (const float*)d_in[18];
    const float* wo_b   = (const float*)d_in[19];
    const float* m2_w1  = (const float*)d_in[20];
    const float* m2_b1  = (const float*)d_in[21];
    const float* m2_w2  = (const float*)d_in[22];
    const float* m2_b2  = (const float*)d_in[23];

    float* out = (float*)d_out;
    float* ws  = (float*)d_ws;

    // workspace arena (float offsets), lifetime-based reuse:
    const size_t SZ_TOK = (size_t)BATCH * GN * CDIM;      // 524288
    float* xg4  = ws;                                     // [0, 524288)      K3..K5
    float* xg   = ws + SZ_TOK;                            // [524288, ...)    K1..K3
    float* qg   = ws + 2 * SZ_TOK;
    float* kg   = ws + 3 * SZ_TOK;
    float* vg   = ws + 4 * SZ_TOK;
    float* og   = ws + 5 * SZ_TOK;                        // K2..K3
    float* qh   = ws + SZ_TOK;                            // reuse xg region after K3
    float* kh   = ws + SZ_TOK + (size_t)BATCH * NW * CDIM;
    int*   tidx = (int*)(ws + SZ_TOK + 2 * (size_t)BATCH * NW * CDIM);
    float* lnsc = ws + 2 * SZ_TOK;                        // reuse qg..og after K3: 6291456 floats
    float* aout = ws + 2 * SZ_TOK + (size_t)BATCH * NW * W3 * CDIM;   // 4194304 floats
    float* lpre = aout + (size_t)BATCH * NW * W3L * CDIM;

    const size_t L_OUT = (size_t)BATCH * CDIM * NSP;      // 4194304
    float* gout = out + L_OUT;

    hipLaunchKernelGGL(k_global_qkv, dim3(BATCH * GN), dim3(128), 0, stream,
                       xg_in, qkv_w, qkv_b, ln_g, ln_b, xg, qg, kg, vg);
    hipLaunchKernelGGL(k_global_attn, dim3(BATCH * HEADS * (GN / 256)), dim3(256), 0, stream,
                       qg, kg, vg, og);
    hipLaunchKernelGGL(k_global_mlp, dim3(BATCH * GN), dim3(128), 0, stream,
                       og, xg, proj_w, proj_b, ln_g, ln_b, mlp_w1, mlp_b1, mlp_w2, mlp_b2,
                       xg4, gout);
    hipLaunchKernelGGL(k_routing_qk, dim3(BATCH * NW), dim3(128), 0, stream,
                       xg4, rq_w, rq_b, rk_w, rk_b, qh, kh);
    hipLaunchKernelGGL(k_topk, dim3(BATCH * NW), dim3(256), 0, stream,
                       qh, kh, tidx);
    hipLaunchKernelGGL(k_build_lnsc, dim3(BATCH * NW * W3), dim3(128), 0, stream,
                       x_in, xg4, tidx, ln_g, ln_b, lnsc);
    hipLaunchKernelGGL(k_local_attn, dim3(BATCH * NW * HEADS), dim3(64), 0, stream,
                       lnsc, gqkv_w, gqkv_b, aout);
    hipLaunchKernelGGL(k_wo, dim3(BATCH * NW * W3L), dim3(128), 0, stream,
                       aout, wo_w, wo_b, x_in, lpre);
    hipLaunchKernelGGL(k_mlp2, dim3(BATCH * NSP), dim3(128), 0, stream,
                       lpre, ln_g, ln_b, m2_w1, m2_b1, m2_w2, m2_b2, out);
}

// Round 2
// 953.743 us; speedup vs baseline: 2.7054x; 2.7054x over previous
//
#include <hip/hip_runtime.h>
#include <hip/hip_bf16.h>
#include <math.h>

#define BATCH 2
#define CDIM 128
#define SS 16
#define HH_ 32
#define WW_ 32
#define NSP (SS*HH_*WW_)
#define GS 8
#define GH 16
#define GW 16
#define GN (GS*GH*GW)
#define HEADS 8
#define DH 16
#define NW 256
#define W3L 64
#define W3G 8
#define TOPK 4
#define W3 (W3L + TOPK*W3G)
#define LN_EPS 1e-6f
#define ROUTE_SCALE 0.08838834764831845f
#define GATTN_SCALE 0.25f

__device__ __forceinline__ unsigned short f2bf(float f) {
    unsigned int u = __float_as_uint(f);
    unsigned int r = (u + 0x7fffu + ((u >> 16) & 1u)) >> 16;
    return (unsigned short)r;
}
__device__ __forceinline__ float bf2f_lo(unsigned int u) { return __uint_as_float(u << 16); }
__device__ __forceinline__ float bf2f_hi(unsigned int u) { return __uint_as_float(u & 0xffff0000u); }

__device__ __forceinline__ float gelu_exact(float x) {
    return 0.5f * x * (1.0f + erff(x * 0.70710678118654752f));
}

__device__ __forceinline__ float shfl_sum32(float v) {
#pragma unroll
    for (int m = 16; m > 0; m >>= 1) v += __shfl_xor(v, m);
    return v;
}
__device__ __forceinline__ float shfl_sum16(float v) {
#pragma unroll
    for (int m = 8; m > 0; m >>= 1) v += __shfl_xor(v, m);
    return v;
}

// ---------------- K1: global branch qkv (T=8 tokens/block) ----------------
__global__ __launch_bounds__(256) void k_gqkv2(const float* __restrict__ xg_in,
        const float* __restrict__ qkv_w, const float* __restrict__ qkv_b,
        const float* __restrict__ ln_g, const float* __restrict__ ln_b,
        float* __restrict__ xg, float* __restrict__ qg, float* __restrict__ kg,
        float* __restrict__ vg) {
    int blk = blockIdx.x; int b = blk >> 8; int n0 = (blk & 255) * 8;
    int t = threadIdx.x;
    __shared__ float xs[8][128];
    __shared__ float h[8][128];
    {   // transpose-stage: thread t -> channel c=t/2, token-quad (t&1)*4
        int c = t >> 1, q4 = (t & 1) * 4;
        float4 v = *(const float4*)(xg_in + ((size_t)(b * 128 + c)) * GN + n0 + q4);
        xs[q4 + 0][c] = v.x; xs[q4 + 1][c] = v.y; xs[q4 + 2][c] = v.z; xs[q4 + 3][c] = v.w;
    }
    __syncthreads();
    int j = t >> 5, c4 = (t & 31) * 4;
    float4 v = *(float4*)&xs[j][c4];
    *(float4*)(xg + ((size_t)(b * GN) + n0 + j) * 128 + c4) = v;
    float s1 = shfl_sum32(v.x + v.y + v.z + v.w);
    float mu = s1 * (1.0f / 128.0f);
    float d0 = v.x - mu, d1 = v.y - mu, d2 = v.z - mu, d3 = v.w - mu;
    float s2 = shfl_sum32(d0 * d0 + d1 * d1 + d2 * d2 + d3 * d3);
    float rs = rsqrtf(s2 * (1.0f / 128.0f) + LN_EPS);
    float4 g4 = *(const float4*)(ln_g + c4);
    float4 b4 = *(const float4*)(ln_b + c4);
    float4 hn = { d0 * rs * g4.x + b4.x, d1 * rs * g4.y + b4.y,
                  d2 * rs * g4.z + b4.z, d3 * rs * g4.w + b4.w };
    *(float4*)&h[j][c4] = hn;
    __syncthreads();
    for (int c = t; c < 384; c += 256) {
        float acc[8];
        float bias = qkv_b[c];
#pragma unroll
        for (int jj = 0; jj < 8; jj++) acc[jj] = bias;
        for (int k = 0; k < 128; k++) {
            float w = qkv_w[k * 384 + c];
#pragma unroll
            for (int jj = 0; jj < 8; jj++) acc[jj] = fmaf(h[jj][k], w, acc[jj]);
        }
        int part = c >> 7, head = (c >> 4) & 7, d = c & 15;
        float* dst = (part == 0) ? qg : (part == 1) ? kg : vg;
        size_t base = ((size_t)(b * HEADS + head) * GN + n0) * DH + d;
#pragma unroll
        for (int jj = 0; jj < 8; jj++) dst[base + jj * DH] = acc[jj];
    }
}

// ---------------- K2: global attention, split-K flash ----------------
__global__ __launch_bounds__(256) void k_gattn2(const float* __restrict__ qg,
        const float* __restrict__ kg, const float* __restrict__ vg, float* __restrict__ og) {
    int blk = blockIdx.x; int bh = blk >> 5; int qb = blk & 31;
    int b = bh >> 3, hh = bh & 7;
    int t = threadIdx.x; int l = t & 63, p = t >> 6;
    int q = qb * 64 + l;
    const float* qp = qg + ((size_t)bh * GN + q) * DH;
    const float* kp = kg + (size_t)bh * GN * DH;
    const float* vp = vg + (size_t)bh * GN * DH;
    float qv[16];
#pragma unroll
    for (int d4 = 0; d4 < 4; d4++) {
        float4 vv = *(const float4*)(qp + d4 * 4);
        qv[d4 * 4 + 0] = vv.x * GATTN_SCALE; qv[d4 * 4 + 1] = vv.y * GATTN_SCALE;
        qv[d4 * 4 + 2] = vv.z * GATTN_SCALE; qv[d4 * 4 + 3] = vv.w * GATTN_SCALE;
    }
    float m = -1e30f, ll = 0.f, o[16];
#pragma unroll
    for (int d = 0; d < 16; d++) o[d] = 0.f;
    int k0 = p * 512;
    for (int key = k0; key < k0 + 512; key++) {
        const float* kr = kp + (size_t)key * DH;
        float4 a0 = *(const float4*)(kr + 0);
        float4 a1 = *(const float4*)(kr + 4);
        float4 a2 = *(const float4*)(kr + 8);
        float4 a3 = *(const float4*)(kr + 12);
        float s = qv[0] * a0.x + qv[1] * a0.y + qv[2] * a0.z + qv[3] * a0.w
                + qv[4] * a1.x + qv[5] * a1.y + qv[6] * a1.z + qv[7] * a1.w
                + qv[8] * a2.x + qv[9] * a2.y + qv[10] * a2.z + qv[11] * a2.w
                + qv[12] * a3.x + qv[13] * a3.y + qv[14] * a3.z + qv[15] * a3.w;
        float mn = fmaxf(m, s);
        float corr = __expf(m - mn);
        float pe = __expf(s - mn);
        ll = ll * corr + pe;
        const float* vr = vp + (size_t)key * DH;
        float4 v0 = *(const float4*)(vr + 0);
        float4 v1 = *(const float4*)(vr + 4);
        float4 v2 = *(const float4*)(vr + 8);
        float4 v3 = *(const float4*)(vr + 12);
        o[0] = o[0] * corr + pe * v0.x; o[1] = o[1] * corr + pe * v0.y;
        o[2] = o[2] * corr + pe * v0.z; o[3] = o[3] * corr + pe * v0.w;
        o[4] = o[4] * corr + pe * v1.x; o[5] = o[5] * corr + pe * v1.y;
        o[6] = o[6] * corr + pe * v1.z; o[7] = o[7] * corr + pe * v1.w;
        o[8] = o[8] * corr + pe * v2.x; o[9] = o[9] * corr + pe * v2.y;
        o[10] = o[10] * corr + pe * v2.z; o[11] = o[11] * corr + pe * v2.w;
        o[12] = o[12] * corr + pe * v3.x; o[13] = o[13] * corr + pe * v3.y;
        o[14] = o[14] * corr + pe * v3.z; o[15] = o[15] * corr + pe * v3.w;
        m = mn;
    }
    __shared__ float pm[4][64];
    __shared__ float pl[4][64];
    __shared__ float po[4][64][17];
    pm[p][l] = m; pl[p][l] = ll;
#pragma unroll
    for (int d = 0; d < 16; d++) po[p][l][d] = o[d];
    __syncthreads();
    if (t < 64) {
        float M = pm[0][t];
#pragma unroll
        for (int p2 = 1; p2 < 4; p2++) M = fmaxf(M, pm[p2][t]);
        float L = 0.f; float O[16];
#pragma unroll
        for (int d = 0; d < 16; d++) O[d] = 0.f;
#pragma unroll
        for (int p2 = 0; p2 < 4; p2++) {
            float e = __expf(pm[p2][t] - M);
            L += pl[p2][t] * e;
#pragma unroll
            for (int d = 0; d < 16; d++) O[d] += po[p2][t][d] * e;
        }
        float inv = 1.f / L;
        float* dst = og + ((size_t)(b * GN) + qb * 64 + t) * 128 + hh * 16;
#pragma unroll
        for (int d4 = 0; d4 < 4; d4++) {
            float4 vv = { O[d4 * 4] * inv, O[d4 * 4 + 1] * inv, O[d4 * 4 + 2] * inv, O[d4 * 4 + 3] * inv };
            *(float4*)(dst + d4 * 4) = vv;
        }
    }
}

// ---------------- K3: global proj+residual+LN+MLP (T=8) ----------------
__global__ __launch_bounds__(256) void k_gmlp2(const float* __restrict__ og,
        const float* __restrict__ xg,
        const float* __restrict__ proj_w, const float* __restrict__ proj_b,
        const float* __restrict__ ln_g, const float* __restrict__ ln_b,
        const float* __restrict__ w1, const float* __restrict__ b1,
        const float* __restrict__ w2, const float* __restrict__ b2,
        float* __restrict__ xg4, float* __restrict__ gout) {
    int blk = blockIdx.x; int b = blk >> 8; int n0 = (blk & 255) * 8;
    int t = threadIdx.x;
    __shared__ float xs[8][128];
    __shared__ float h[8][128];
    __shared__ float h1[8][512];
    int j = t >> 5, c4 = (t & 31) * 4;
    size_t rbase = ((size_t)(b * GN) + n0 + j) * 128 + c4;
    *(float4*)&h[j][c4] = *(const float4*)(og + rbase);   // h temporarily holds attention-out
    *(float4*)&xs[j][c4] = *(const float4*)(xg + rbase);
    __syncthreads();
    int c = t & 127, g = t >> 7;
    {
        float acc[4];
        float bias = proj_b[c];
#pragma unroll
        for (int jj = 0; jj < 4; jj++) acc[jj] = bias;
        for (int k = 0; k < 128; k++) {
            float w = proj_w[k * 128 + c];
#pragma unroll
            for (int jj = 0; jj < 4; jj++) acc[jj] = fmaf(h[g * 4 + jj][k], w, acc[jj]);
        }
#pragma unroll
        for (int jj = 0; jj < 4; jj++) xs[g * 4 + jj][c] += acc[jj];
    }
    __syncthreads();
    {   // LN -> h (overwrite; og-stage dead)
        float4 v = *(float4*)&xs[j][c4];
        float s1 = shfl_sum32(v.x + v.y + v.z + v.w);
        float mu = s1 * (1.0f / 128.0f);
        float d0 = v.x - mu, d1 = v.y - mu, d2 = v.z - mu, d3 = v.w - mu;
        float s2 = shfl_sum32(d0 * d0 + d1 * d1 + d2 * d2 + d3 * d3);
        float rs = rsqrtf(s2 * (1.0f / 128.0f) + LN_EPS);
        float4 g4 = *(const float4*)(ln_g + c4);
        float4 b4 = *(const float4*)(ln_b + c4);
        float4 hn = { d0 * rs * g4.x + b4.x, d1 * rs * g4.y + b4.y,
                      d2 * rs * g4.z + b4.z, d3 * rs * g4.w + b4.w };
        *(float4*)&h[j][c4] = hn;
    }
    __syncthreads();
    {   // w1 + gelu -> h1 (cols t and t+256)
        float acc0[8], acc1[8];
        float bi0 = b1[t], bi1 = b1[t + 256];
#pragma unroll
        for (int jj = 0; jj < 8; jj++) { acc0[jj] = bi0; acc1[jj] = bi1; }
        for (int k = 0; k < 128; k++) {
            float wa = w1[k * 512 + t];
            float wb = w1[k * 512 + t + 256];
#pragma unroll
            for (int jj = 0; jj < 8; jj++) {
                float hv = h[jj][k];
                acc0[jj] = fmaf(hv, wa, acc0[jj]);
                acc1[jj] = fmaf(hv, wb, acc1[jj]);
            }
        }
#pragma unroll
        for (int jj = 0; jj < 8; jj++) {
            h1[jj][t] = gelu_exact(acc0[jj]);
            h1[jj][t + 256] = gelu_exact(acc1[jj]);
        }
    }
    __syncthreads();
    {   // w2 + residual
        float acc[4];
        float bias = b2[c];
#pragma unroll
        for (int jj = 0; jj < 4; jj++) acc[jj] = bias;
        for (int k = 0; k < 512; k++) {
            float w = w2[k * 128 + c];
#pragma unroll
            for (int jj = 0; jj < 4; jj++) acc[jj] = fmaf(h1[g * 4 + jj][k], w, acc[jj]);
        }
#pragma unroll
        for (int jj = 0; jj < 4; jj++) {
            float ov = xs[g * 4 + jj][c] + acc[jj];
            xg4[((size_t)(b * GN) + n0 + g * 4 + jj) * 128 + c] = ov;
            h[g * 4 + jj][c] = ov;
        }
    }
    __syncthreads();
    {   // transposed g_out write
        int cw = t >> 1, hf = t & 1, j0 = hf * 4;
        float4 ov = { h[j0 + 0][cw], h[j0 + 1][cw], h[j0 + 2][cw], h[j0 + 3][cw] };
        *(float4*)(gout + ((size_t)(b * 128 + cw)) * GN + n0 + j0) = ov;
    }
}

// ---------------- K4a: routing q/k (unchanged) ----------------
__global__ void k_routing_qk(const float* __restrict__ xg4,
                             const float* __restrict__ rq_w, const float* __restrict__ rq_b,
                             const float* __restrict__ rk_w, const float* __restrict__ rk_b,
                             float* __restrict__ qh, float* __restrict__ kh) {
    int wid = blockIdx.x; int b = wid / NW, n = wid % NW;
    int c = threadIdx.x;
    int i1 = n / 64, i2 = (n / 8) % 8, i3 = n % 8;
    __shared__ float g[CDIM];
    float s = 0.f;
#pragma unroll
    for (int j = 0; j < W3G; j++) {
        int ds = j >> 2, dh = (j >> 1) & 1, dw = j & 1;
        int gi = ((i1 * 2 + ds) * GH + (i2 * 2 + dh)) * GW + (i3 * 2 + dw);
        s += xg4[((size_t)(b * GN + gi)) * CDIM + c];
    }
    g[c] = s * (1.0f / W3G);
    __syncthreads();
    float aq = rq_b[c], ak = rk_b[c];
    for (int k = 0; k < CDIM; k++) { float gv = g[k]; aq = fmaf(gv, rq_w[k * CDIM + c], aq); ak = fmaf(gv, rk_w[k * CDIM + c], ak); }
    qh[(size_t)wid * CDIM + c] = aq;
    kh[(size_t)wid * CDIM + c] = ak;
}

// ---------------- K4b: top-k (unchanged) ----------------
__global__ void k_topk(const float* __restrict__ qh, const float* __restrict__ kh,
                       int* __restrict__ tidx) {
    int wid = blockIdx.x; int b = wid / NW;
    int m = threadIdx.x;
    __shared__ float q[CDIM];
    __shared__ float lv[NW];
    __shared__ int li[NW];
    if (m < CDIM) q[m] = qh[(size_t)wid * CDIM + m] * ROUTE_SCALE;
    __syncthreads();
    float acc = 0.f;
    const float* kr = kh + ((size_t)b * NW + m) * CDIM;
    for (int k = 0; k < CDIM; k++) acc = fmaf(q[k], kr[k], acc);
#pragma unroll
    for (int sel = 0; sel < TOPK; sel++) {
        lv[m] = acc; li[m] = m; __syncthreads();
#pragma unroll
        for (int s = 128; s > 0; s >>= 1) {
            if (m < s) {
                if (lv[m + s] > lv[m] || (lv[m + s] == lv[m] && li[m + s] < li[m])) {
                    lv[m] = lv[m + s]; li[m] = li[m + s];
                }
            }
            __syncthreads();
        }
        int best = li[0]; __syncthreads();
        if (m == best) acc = -1e30f;
        if (m == 0) tidx[wid * TOPK + sel] = best;
    }
}

// ---------------- K5a: LN of local tokens -> lnsc bf16 (slots 0..63) ----------------
__global__ __launch_bounds__(256) void k_lnsc_local(const float* __restrict__ x_in,
        const float* __restrict__ ln_g, const float* __restrict__ ln_b,
        unsigned short* __restrict__ lnsc) {
    int blk = blockIdx.x;
    int wt = blk & 1; int hh = (blk >> 1) & 31; int s = (blk >> 6) & 15; int b = blk >> 10;
    int w0 = wt * 16;
    int t = threadIdx.x;
    __shared__ float tile[16][132];
    {
        int c = t >> 1; int wq = (t & 1) * 8;
        const float* src = x_in + (((size_t)(b * 128 + c) * SS + s)) * 1024 + hh * 32 + w0 + wq;
        float4 v0 = *(const float4*)src;
        float4 v1 = *(const float4*)(src + 4);
        tile[wq + 0][c] = v0.x; tile[wq + 1][c] = v0.y; tile[wq + 2][c] = v0.z; tile[wq + 3][c] = v0.w;
        tile[wq + 4][c] = v1.x; tile[wq + 5][c] = v1.y; tile[wq + 6][c] = v1.z; tile[wq + 7][c] = v1.w;
    }
    __syncthreads();
    int w = t >> 4; int j = t & 15;
    float vals[8];
    float s1 = 0.f;
#pragma unroll
    for (int i = 0; i < 8; i++) { vals[i] = tile[w][j * 8 + i]; s1 += vals[i]; }
    s1 = shfl_sum16(s1);
    float mu = s1 * (1.0f / 128.0f);
    float s2 = 0.f;
#pragma unroll
    for (int i = 0; i < 8; i++) { float d = vals[i] - mu; s2 += d * d; }
    s2 = shfl_sum16(s2);
    float rs = rsqrtf(s2 * (1.0f / 128.0f) + LN_EPS);
    float4 g0 = *(const float4*)(ln_g + j * 8);
    float4 g1 = *(const float4*)(ln_g + j * 8 + 4);
    float4 b0 = *(const float4*)(ln_b + j * 8);
    float4 b1 = *(const float4*)(ln_b + j * 8 + 4);
    float gv[8] = { g0.x, g0.y, g0.z, g0.w, g1.x, g1.y, g1.z, g1.w };
    float bv[8] = { b0.x, b0.y, b0.z, b0.w, b1.x, b1.y, b1.z, b1.w };
    int ww = w0 + w;
    int n = (s >> 2) * 64 + (hh >> 2) * 8 + (ww >> 2);
    int slot = (s & 3) * 16 + (hh & 3) * 4 + (ww & 3);
    unsigned short* dst = lnsc + ((size_t)(b * NW + n) * W3 + slot) * 128 + j * 8;
    ushort4 u0, u1;
    u0.x = f2bf((vals[0] - mu) * rs * gv[0] + bv[0]);
    u0.y = f2bf((vals[1] - mu) * rs * gv[1] + bv[1]);
    u0.z = f2bf((vals[2] - mu) * rs * gv[2] + bv[2]);
    u0.w = f2bf((vals[3] - mu) * rs * gv[3] + bv[3]);
    u1.x = f2bf((vals[4] - mu) * rs * gv[4] + bv[4]);
    u1.y = f2bf((vals[5] - mu) * rs * gv[5] + bv[5]);
    u1.z = f2bf((vals[6] - mu) * rs * gv[6] + bv[6]);
    u1.w = f2bf((vals[7] - mu) * rs * gv[7] + bv[7]);
    *(ushort4*)dst = u0;
    *(ushort4*)(dst + 4) = u1;
}

// ---------------- K5b: LN of gathered global tokens -> lnsc bf16 (slots 64..95) ----------------
__global__ __launch_bounds__(256) void k_lnsc_gath(const float* __restrict__ xg4,
        const int* __restrict__ tidx,
        const float* __restrict__ ln_g, const float* __restrict__ ln_b,
        unsigned short* __restrict__ lnsc) {
    int blk = blockIdx.x;
    int kk = blk & 3; int wn = blk >> 2;
    int b = wn >> 8;
    int g = tidx[wn * TOPK + kk];
    int gi1 = g >> 6, gi2 = (g >> 3) & 7, gi3 = g & 7;
    int t = threadIdx.x; int j = t >> 5, lj = t & 31;
    int ds = j >> 2, dh = (j >> 1) & 1, dw = j & 1;
    int gi = ((gi1 * 2 + ds) * GH + (gi2 * 2 + dh)) * GW + (gi3 * 2 + dw);
    float4 v = *(const float4*)(xg4 + ((size_t)(b * GN + gi)) * 128 + lj * 4);
    float s1 = shfl_sum32(v.x + v.y + v.z + v.w);
    float mu = s1 * (1.0f / 128.0f);
    float d0 = v.x - mu, d1 = v.y - mu, d2 = v.z - mu, d3 = v.w - mu;
    float s2 = shfl_sum32(d0 * d0 + d1 * d1 + d2 * d2 + d3 * d3);
    float rs = rsqrtf(s2 * (1.0f / 128.0f) + LN_EPS);
    float4 g4 = *(const float4*)(ln_g + lj * 4);
    float4 b4 = *(const float4*)(ln_b + lj * 4);
    ushort4 u;
    u.x = f2bf(d0 * rs * g4.x + b4.x);
    u.y = f2bf(d1 * rs * g4.y + b4.y);
    u.z = f2bf(d2 * rs * g4.z + b4.z);
    u.w = f2bf(d3 * rs * g4.w + b4.w);
    *(ushort4*)(lnsc + ((size_t)wn * W3 + 64 + kk * 8 + j) * 128 + lj * 4) = u;
}

// ---------------- K6: local attention, one window per 256-thread block ----------------
__global__ __launch_bounds__(256) void k_local_attn2(const unsigned short* __restrict__ lnsc,
        const float* __restrict__ gqkv_w, const float* __restrict__ gqkv_b,
        float* __restrict__ aout) {
    int wn = blockIdx.x; int t = threadIdx.x;
    __shared__ unsigned short X[96 * 132];   // padded stride 132
    __shared__ unsigned short Ks[96 * 128];
    __shared__ unsigned short Vs[96 * 128];
    const unsigned short* src = lnsc + (size_t)wn * W3 * 128;
#pragma unroll
    for (int i = 0; i < 12; i++) {
        int e = t + 256 * i; int r = e >> 5; int c4 = (e & 31) << 2;
        *(ushort4*)&X[r * 132 + c4] = *(const ushort4*)&src[r * 128 + c4];
    }
    __syncthreads();
    {   // K/V projection: thread t owns gqkv column 128+t
        int wcol = 128 + t;
        float bias = gqkv_b[wcol];
        unsigned short* dst = (t < 128) ? Ks : Vs;
        int cc = t & 127;
        for (int r0 = 0; r0 < 96; r0 += 8) {
            float acc[8];
#pragma unroll
            for (int jj = 0; jj < 8; jj++) acc[jj] = 0.f;
            for (int k = 0; k < 128; k += 2) {
                float w0 = gqkv_w[k * 384 + wcol];
                float w1 = gqkv_w[(k + 1) * 384 + wcol];
#pragma unroll
                for (int jj = 0; jj < 8; jj++) {
                    unsigned int u = *(const unsigned int*)&X[(r0 + jj) * 132 + k];
                    acc[jj] = fmaf(bf2f_lo(u), w0, acc[jj]);
                    acc[jj] = fmaf(bf2f_hi(u), w1, acc[jj]);
                }
            }
#pragma unroll
            for (int jj = 0; jj < 8; jj++) dst[(r0 + jj) * 128 + cc] = f2bf(acc[jj] + bias);
        }
    }
    // Q projection: wave wv covers heads 2wv,2wv+1 (cols 32wv..32wv+31); lane = query
    int wv = t >> 6, l = t & 63;
    int c0 = wv * 32;
    float q[32];
#pragma unroll
    for (int jj = 0; jj < 32; jj++) q[jj] = gqkv_b[c0 + jj];
    for (int k = 0; k < 128; k += 2) {
        unsigned int u = *(const unsigned int*)&X[l * 132 + k];
        float f0 = bf2f_lo(u), f1 = bf2f_hi(u);
        const float* wr0 = gqkv_w + k * 384 + c0;
        const float* wr1 = wr0 + 384;
#pragma unroll
        for (int j4 = 0; j4 < 8; j4++) {
            float4 a = *(const float4*)(wr0 + j4 * 4);
            float4 bb = *(const float4*)(wr1 + j4 * 4);
            q[j4 * 4 + 0] = fmaf(f0, a.x, fmaf(f1, bb.x, q[j4 * 4 + 0]));
            q[j4 * 4 + 1] = fmaf(f0, a.y, fmaf(f1, bb.y, q[j4 * 4 + 1]));
            q[j4 * 4 + 2] = fmaf(f0, a.z, fmaf(f1, bb.z, q[j4 * 4 + 2]));
            q[j4 * 4 + 3] = fmaf(f0, a.w, fmaf(f1, bb.w, q[j4 * 4 + 3]));
        }
    }
#pragma unroll
    for (int jj = 0; jj < 32; jj++) q[jj] *= ROUTE_SCALE;
    __syncthreads();
    float* outp = aout + ((size_t)wn * W3L + l) * 128;
    for (int hh2 = 0; hh2 < 2; hh2++) {
        int hh = wv * 2 + hh2; int qo = hh2 * 16;
        float sc[96]; float mx = -1e30f;
#pragma unroll
        for (int r = 0; r < 96; r++) {
            const unsigned short* kr = &Ks[r * 128 + hh * 16];
            float s = 0.f;
#pragma unroll
            for (int d2 = 0; d2 < 8; d2++) {
                unsigned int u = *(const unsigned int*)&kr[d2 * 2];
                s = fmaf(bf2f_lo(u), q[qo + d2 * 2], s);
                s = fmaf(bf2f_hi(u), q[qo + d2 * 2 + 1], s);
            }
            sc[r] = s; mx = fmaxf(mx, s);
        }
        float sum = 0.f; float o[16];
#pragma unroll
        for (int d = 0; d < 16; d++) o[d] = 0.f;
#pragma unroll
        for (int r = 0; r < 96; r++) {
            float p = __expf(sc[r] - mx); sum += p;
            const unsigned short* vr = &Vs[r * 128 + hh * 16];
#pragma unroll
            for (int d2 = 0; d2 < 8; d2++) {
                unsigned int u = *(const unsigned int*)&vr[d2 * 2];
                o[d2 * 2] = fmaf(p, bf2f_lo(u), o[d2 * 2]);
                o[d2 * 2 + 1] = fmaf(p, bf2f_hi(u), o[d2 * 2 + 1]);
            }
        }
        float inv = 1.f / sum;
#pragma unroll
        for (int d4 = 0; d4 < 4; d4++) {
            float4 vv = { o[d4 * 4] * inv, o[d4 * 4 + 1] * inv, o[d4 * 4 + 2] * inv, o[d4 * 4 + 3] * inv };
            *(float4*)(outp + hh * 16 + d4 * 4) = vv;
        }
    }
}

// ---------------- K7: wo projection + shortcut (T=8) ----------------
__global__ __launch_bounds__(256) void k_wo2(const float* __restrict__ aout,
        const float* __restrict__ wo_w, const float* __restrict__ wo_b,
        const float* __restrict__ x_in, float* __restrict__ lpre) {
    int blk = blockIdx.x; int wn = blk >> 3; int g8 = blk & 7;
    int b = wn >> 8; int n = wn & 255;
    int t = threadIdx.x;
    __shared__ float as[8][128];
    {
        int j = t >> 5, c4 = (t & 31) << 2;
        *(float4*)&as[j][c4] = *(const float4*)(aout + ((size_t)wn * W3L + g8 * 8 + j) * 128 + c4);
    }
    __syncthreads();
    int c = t & 127, g = t >> 7;
    float acc[4];
    float bias = wo_b[c];
#pragma unroll
    for (int jj = 0; jj < 4; jj++) acc[jj] = bias;
    for (int k = 0; k < 128; k++) {
        float w = wo_w[k * 128 + c];
#pragma unroll
        for (int jj = 0; jj < 4; jj++) acc[jj] = fmaf(as[g * 4 + jj][k], w, acc[jj]);
    }
    int i1 = n >> 6, i2 = (n >> 3) & 7, i3 = n & 7;
    int s0 = g8 * 8 + g * 4;            // first of this thread's 4 slots (dw = 0..3)
    int dsl = s0 >> 4, dh = (s0 >> 2) & 3;
    int s = i1 * 4 + dsl, hh = i2 * 4 + dh, ww0 = i3 * 4;
    float4 sc4 = *(const float4*)(x_in + (((size_t)(b * 128 + c) * SS + s)) * 1024 + hh * 32 + ww0);
    float ov[4] = { acc[0] + sc4.x, acc[1] + sc4.y, acc[2] + sc4.z, acc[3] + sc4.w };
    size_t obase = ((((size_t)(b * SS + s)) * HH_ + hh) * WW_ + ww0) * 128 + c;
#pragma unroll
    for (int jj = 0; jj < 4; jj++) lpre[obase + (size_t)jj * 128] = ov[jj];
}

// ---------------- K8: LN + MLP2 + residual, transposed out (T=8) ----------------
__global__ __launch_bounds__(256) void k_mlp22(const float* __restrict__ lpre,
        const float* __restrict__ ln_g, const float* __restrict__ ln_b,
        const float* __restrict__ w1, const float* __restrict__ b1,
        const float* __restrict__ w2, const float* __restrict__ b2,
        float* __restrict__ lout) {
    int blk = blockIdx.x;
    int b = blk >> 11; int sp0 = (blk & 2047) * 8;
    int t = threadIdx.x;
    __shared__ float xs[8][128];
    __shared__ float h[8][128];
    __shared__ float h1[8][512];
    int j = t >> 5, c4 = (t & 31) * 4;
    float4 v = *(const float4*)(lpre + ((size_t)(b * NSP) + sp0 + j) * 128 + c4);
    *(float4*)&xs[j][c4] = v;
    float s1 = shfl_sum32(v.x + v.y + v.z + v.w);
    float mu = s1 * (1.0f / 128.0f);
    float d0 = v.x - mu, d1 = v.y - mu, d2 = v.z - mu, d3 = v.w - mu;
    float s2 = shfl_sum32(d0 * d0 + d1 * d1 + d2 * d2 + d3 * d3);
    float rs = rsqrtf(s2 * (1.0f / 128.0f) + LN_EPS);
    float4 g4 = *(const float4*)(ln_g + c4);
    float4 b4 = *(const float4*)(ln_b + c4);
    float4 hn = { d0 * rs * g4.x + b4.x, d1 * rs * g4.y + b4.y,
                  d2 * rs * g4.z + b4.z, d3 * rs * g4.w + b4.w };
    *(float4*)&h[j][c4] = hn;
    __syncthreads();
    {
        float acc0[8], acc1[8];
        float bi0 = b1[t], bi1 = b1[t + 256];
#pragma unroll
        for (int jj = 0; jj < 8; jj++) { acc0[jj] = bi0; acc1[jj] = bi1; }
        for (int k = 0; k < 128; k++) {
            float wa = w1[k * 512 + t];
            float wb = w1[k * 512 + t + 256];
#pragma unroll
            for (int jj = 0; jj < 8; jj++) {
                float hv = h[jj][k];
                acc0[jj] = fmaf(hv, wa, acc0[jj]);
                acc1[jj] = fmaf(hv, wb, acc1[jj]);
            }
        }
#pragma unroll
        for (int jj = 0; jj < 8; jj++) {
            h1[jj][t] = gelu_exact(acc0[jj]);
            h1[jj][t + 256] = gelu_exact(acc1[jj]);
        }
    }
    __syncthreads();
    int c = t & 127, g = t >> 7;
    {
        float acc[4];
        float bias = b2[c];
#pragma unroll
        for (int jj = 0; jj < 4; jj++) acc[jj] = bias;
        for (int k = 0; k < 512; k++) {
            float w = w2[k * 128 + c];
#pragma unroll
            for (int jj = 0; jj < 4; jj++) acc[jj] = fmaf(h1[g * 4 + jj][k], w, acc[jj]);
        }
#pragma unroll
        for (int jj = 0; jj < 4; jj++) h[g * 4 + jj][c] = xs[g * 4 + jj][c] + acc[jj];
    }
    __syncthreads();
    {
        int cw = t >> 1, hf = t & 1, j0 = hf * 4;
        float4 ov = { h[j0 + 0][cw], h[j0 + 1][cw], h[j0 + 2][cw], h[j0 + 3][cw] };
        *(float4*)(lout + ((size_t)(b * 128 + cw)) * NSP + sp0 + j0) = ov;
    }
}

extern "C" void kernel_launch(void* const* d_in, const int* in_sizes, int n_in,
                              void* d_out, int out_size, void* d_ws, size_t ws_size,
                              hipStream_t stream) {
    const float* x_in   = (const float*)d_in[0];
    const float* xg_in  = (const float*)d_in[1];
    const float* qkv_w  = (const float*)d_in[2];
    const float* qkv_b  = (const float*)d_in[3];
    const float* proj_w = (const float*)d_in[4];
    const float* proj_b = (const float*)d_in[5];
    const float* ln_g   = (const float*)d_in[6];
    const float* ln_b   = (const float*)d_in[7];
    const float* mlp_w1 = (const float*)d_in[8];
    const float* mlp_b1 = (const float*)d_in[9];
    const float* mlp_w2 = (const float*)d_in[10];
    const float* mlp_b2 = (const float*)d_in[11];
    const float* rq_w   = (const float*)d_in[12];
    const float* rq_b   = (const float*)d_in[13];
    const float* rk_w   = (const float*)d_in[14];
    const float* rk_b   = (const float*)d_in[15];
    const float* gqkv_w = (const float*)d_in[16];
    const float* gqkv_b = (const float*)d_in[17];
    const float* wo_w   = (const float*)d_in[18];
    const float* wo_b   = (const float*)d_in[19];
    const float* m2_w1  = (const float*)d_in[20];
    const float* m2_b1  = (const float*)d_in[21];
    const float* m2_w2  = (const float*)d_in[22];
    const float* m2_b2  = (const float*)d_in[23];

    float* out = (float*)d_out;
    float* ws  = (float*)d_ws;

    float* xg4 = ws;                       // 524288
    float* xg  = ws + 524288;
    float* qg  = ws + 1048576;
    float* kg  = ws + 1572864;
    float* vg  = ws + 2097152;
    float* og  = ws + 2621440;
    float* qh  = ws + 3145728;             // 65536
    float* kh  = ws + 3211264;             // 65536
    int*   tidx = (int*)(ws + 3276800);    // 2048
    unsigned short* lnsc = (unsigned short*)(ws + 3280896);  // 6291456 bf16
    float* aout = ws + 3280896 + 3145728;  // 4194304
    float* lpre = aout + 4194304;          // 4194304

    const size_t L_OUT = (size_t)BATCH * CDIM * NSP;
    float* gout = out + L_OUT;

    hipLaunchKernelGGL(k_gqkv2, dim3(512), dim3(256), 0, stream,
                       xg_in, qkv_w, qkv_b, ln_g, ln_b, xg, qg, kg, vg);
    hipLaunchKernelGGL(k_gattn2, dim3(512), dim3(256), 0, stream, qg, kg, vg, og);
    hipLaunchKernelGGL(k_gmlp2, dim3(512), dim3(256), 0, stream,
                       og, xg, proj_w, proj_b, ln_g, ln_b, mlp_w1, mlp_b1, mlp_w2, mlp_b2,
                       xg4, gout);
    hipLaunchKernelGGL(k_routing_qk, dim3(512), dim3(128), 0, stream,
                       xg4, rq_w, rq_b, rk_w, rk_b, qh, kh);
    hipLaunchKernelGGL(k_topk, dim3(512), dim3(256), 0, stream, qh, kh, tidx);
    hipLaunchKernelGGL(k_lnsc_local, dim3(2048), dim3(256), 0, stream,
                       x_in, ln_g, ln_b, lnsc);
    hipLaunchKernelGGL(k_lnsc_gath, dim3(2048), dim3(256), 0, stream,
                       xg4, tidx, ln_g, ln_b, lnsc);
    hipLaunchKernelGGL(k_local_attn2, dim3(512), dim3(256), 0, stream,
                       lnsc, gqkv_w, gqkv_b, aout);
    hipLaunchKernelGGL(k_wo2, dim3(4096), dim3(256), 0, stream,
                       aout, wo_w, wo_b, x_in, lpre);
    hipLaunchKernelGGL(k_mlp22, dim3(4096), dim3(256), 0, stream,
                       lpre, ln_g, ln_b, m2_w1, m2_b1, m2_w2, m2_b2, out);
}

// Round 3
// 696.560 us; speedup vs baseline: 3.7042x; 1.3692x over previous
//
#include <hip/hip_runtime.h>
#include <hip/hip_bf16.h>
#include <math.h>

#define BATCH 2
#define CDIM 128
#define SS 16
#define HH_ 32
#define WW_ 32
#define NSP (SS*HH_*WW_)
#define GS 8
#define GH 16
#define GW 16
#define GN (GS*GH*GW)
#define HEADS 8
#define DH 16
#define NW 256
#define W3L 64
#define W3G 8
#define TOPK 4
#define W3 (W3L + TOPK*W3G)
#define LN_EPS 1e-6f
#define ROUTE_SCALE 0.08838834764831845f
#define GATTN_SCALE 0.25f

typedef short bshort8 __attribute__((ext_vector_type(8)));
typedef float f32x4 __attribute__((ext_vector_type(4)));

__device__ __forceinline__ unsigned short f2bf(float f) {
    unsigned int u = __float_as_uint(f);
    unsigned int r = (u + 0x7fffu + ((u >> 16) & 1u)) >> 16;
    return (unsigned short)r;
}
__device__ __forceinline__ float bf2f_lo(unsigned int u) { return __uint_as_float(u << 16); }
__device__ __forceinline__ float bf2f_hi(unsigned int u) { return __uint_as_float(u & 0xffff0000u); }

__device__ __forceinline__ float gelu_exact(float x) {
    return 0.5f * x * (1.0f + erff(x * 0.70710678118654752f));
}

__device__ __forceinline__ float shfl_sum32(float v) {
#pragma unroll
    for (int m = 16; m > 0; m >>= 1) v += __shfl_xor(v, m);
    return v;
}
__device__ __forceinline__ float shfl_sum16(float v) {
#pragma unroll
    for (int m = 8; m > 0; m >>= 1) v += __shfl_xor(v, m);
    return v;
}

// ---------------- K1: global branch qkv (T=8 tokens/block), bf16 q/k/v^T out ----------------
__global__ __launch_bounds__(256) void k_gqkv2(const float* __restrict__ xg_in,
        const float* __restrict__ qkv_w, const float* __restrict__ qkv_b,
        const float* __restrict__ ln_g, const float* __restrict__ ln_b,
        float* __restrict__ xg, unsigned short* __restrict__ qgb,
        unsigned short* __restrict__ kgb, unsigned short* __restrict__ vgtb) {
    int blk = blockIdx.x; int b = blk >> 8; int n0 = (blk & 255) * 8;
    int t = threadIdx.x;
    __shared__ float xs[8][128];
    __shared__ float h[8][128];
    {   // transpose-stage
        int c = t >> 1, q4 = (t & 1) * 4;
        float4 v = *(const float4*)(xg_in + ((size_t)(b * 128 + c)) * GN + n0 + q4);
        xs[q4 + 0][c] = v.x; xs[q4 + 1][c] = v.y; xs[q4 + 2][c] = v.z; xs[q4 + 3][c] = v.w;
    }
    __syncthreads();
    int j = t >> 5, c4 = (t & 31) * 4;
    float4 v = *(float4*)&xs[j][c4];
    *(float4*)(xg + ((size_t)(b * GN) + n0 + j) * 128 + c4) = v;
    float s1 = shfl_sum32(v.x + v.y + v.z + v.w);
    float mu = s1 * (1.0f / 128.0f);
    float d0 = v.x - mu, d1 = v.y - mu, d2 = v.z - mu, d3 = v.w - mu;
    float s2 = shfl_sum32(d0 * d0 + d1 * d1 + d2 * d2 + d3 * d3);
    float rs = rsqrtf(s2 * (1.0f / 128.0f) + LN_EPS);
    float4 g4 = *(const float4*)(ln_g + c4);
    float4 b4 = *(const float4*)(ln_b + c4);
    float4 hn = { d0 * rs * g4.x + b4.x, d1 * rs * g4.y + b4.y,
                  d2 * rs * g4.z + b4.z, d3 * rs * g4.w + b4.w };
    *(float4*)&h[j][c4] = hn;
    __syncthreads();
    for (int c = t; c < 384; c += 256) {
        float acc[8];
        float bias = qkv_b[c];
#pragma unroll
        for (int jj = 0; jj < 8; jj++) acc[jj] = bias;
        for (int k = 0; k < 128; k++) {
            float w = qkv_w[k * 384 + c];
#pragma unroll
            for (int jj = 0; jj < 8; jj++) acc[jj] = fmaf(h[jj][k], w, acc[jj]);
        }
        int part = c >> 7, head = (c >> 4) & 7, d = c & 15;
        int bh = b * HEADS + head;
        if (part == 0) {
#pragma unroll
            for (int jj = 0; jj < 8; jj++)
                qgb[((size_t)bh * GN + n0 + jj) * DH + d] = f2bf(acc[jj] * GATTN_SCALE);
        } else if (part == 1) {
#pragma unroll
            for (int jj = 0; jj < 8; jj++)
                kgb[((size_t)bh * GN + n0 + jj) * DH + d] = f2bf(acc[jj]);
        } else {
            ushort4 u0, u1;
            u0.x = f2bf(acc[0]); u0.y = f2bf(acc[1]); u0.z = f2bf(acc[2]); u0.w = f2bf(acc[3]);
            u1.x = f2bf(acc[4]); u1.y = f2bf(acc[5]); u1.z = f2bf(acc[6]); u1.w = f2bf(acc[7]);
            unsigned short* dst = vgtb + ((size_t)bh * DH + d) * GN + n0;
            *(ushort4*)dst = u0; *(ushort4*)(dst + 4) = u1;
        }
    }
}

// ---------------- K2: global attention via MFMA bf16 ----------------
// grid = 16 bh * 128 qtiles(16) = 2048 blocks, 256 threads = 4 waves (key-split).
__global__ __launch_bounds__(256) void k_gattn_mfma(const unsigned short* __restrict__ qgb,
        const unsigned short* __restrict__ kgb, const unsigned short* __restrict__ vgtb,
        float* __restrict__ og) {
    int blk = blockIdx.x;
    int bh = blk >> 7; int qt = (blk & 127) << 4;
    int b = bh >> 3, hh = bh & 7;
    int t = threadIdx.x; int w = t >> 6; int lane = t & 63;
    int col = lane & 15, quad = lane >> 4;
    __shared__ __align__(16) unsigned short Pbuf[4 * 16 * 40];   // per-wave 16x(32+8) bf16
    __shared__ float po[4][64][4];
    __shared__ float pl[4][64][4];

    // A fragment: Q tile [16q x 32k], k = dh (0..15 real, 16..31 zero)
    bshort8 aq = {0, 0, 0, 0, 0, 0, 0, 0};
    if (quad < 2)
        aq = *(const bshort8*)(qgb + ((size_t)bh * GN + qt + col) * DH + quad * 8);

    f32x4 o = {0.f, 0.f, 0.f, 0.f};
    float lsum[4] = {0.f, 0.f, 0.f, 0.f};
    const unsigned short* kb = kgb + (size_t)bh * GN * DH;
    const unsigned short* vb = vgtb + (size_t)bh * DH * GN;
    unsigned short* pb = Pbuf + w * (16 * 40);
    int row0 = quad * 4;
    int kbeg = w * 512;
    for (int kc = kbeg; kc < kbeg + 512; kc += 32) {
        bshort8 bk0 = {0, 0, 0, 0, 0, 0, 0, 0};
        bshort8 bk1 = {0, 0, 0, 0, 0, 0, 0, 0};
        if (quad < 2) {
            bk0 = *(const bshort8*)(kb + (size_t)(kc + col) * DH + quad * 8);
            bk1 = *(const bshort8*)(kb + (size_t)(kc + 16 + col) * DH + quad * 8);
        }
        f32x4 z = {0.f, 0.f, 0.f, 0.f};
        f32x4 s0 = __builtin_amdgcn_mfma_f32_16x16x32_bf16(aq, bk0, z, 0, 0, 0);
        f32x4 s1 = __builtin_amdgcn_mfma_f32_16x16x32_bf16(aq, bk1, z, 0, 0, 0);
        // p = exp(s) -- scores are tiny (|s| << 1): no max subtraction needed
        float p0[4], p1[4];
#pragma unroll
        for (int r = 0; r < 4; r++) {
            p0[r] = __expf(s0[r]); p1[r] = __expf(s1[r]);
            lsum[r] += p0[r] + p1[r];
        }
        // C-layout -> A-layout via LDS (row stride 40 shorts: 16B-aligned reads, 2-way max)
#pragma unroll
        for (int r = 0; r < 4; r++) {
            pb[(row0 + r) * 40 + col] = f2bf(p0[r]);
            pb[(row0 + r) * 40 + 16 + col] = f2bf(p1[r]);
        }
        bshort8 pA = *(const bshort8*)(pb + col * 40 + quad * 8);
        // V fragment: B[k=key][n=d] read from V^T rows
        bshort8 bv = *(const bshort8*)(vb + (size_t)col * GN + kc + quad * 8);
        o = __builtin_amdgcn_mfma_f32_16x16x32_bf16(pA, bv, o, 0, 0, 0);
    }
    // row-sum of l over the 16 key-lanes
#pragma unroll
    for (int r = 0; r < 4; r++) {
        float v = lsum[r];
        v += __shfl_xor(v, 1); v += __shfl_xor(v, 2);
        v += __shfl_xor(v, 4); v += __shfl_xor(v, 8);
        lsum[r] = v;
    }
#pragma unroll
    for (int r = 0; r < 4; r++) { po[w][lane][r] = o[r]; pl[w][lane][r] = lsum[r]; }
    __syncthreads();
    if (w == 0) {
#pragma unroll
        for (int r = 0; r < 4; r++) {
            float os = po[0][lane][r] + po[1][lane][r] + po[2][lane][r] + po[3][lane][r];
            float ls = pl[0][lane][r] + pl[1][lane][r] + pl[2][lane][r] + pl[3][lane][r];
            og[((size_t)(b * GN) + qt + quad * 4 + r) * 128 + hh * 16 + col] = os / ls;
        }
    }
}

// ---------------- K3: global proj+residual+LN+MLP (T=8) ----------------
__global__ __launch_bounds__(256) void k_gmlp2(const float* __restrict__ og,
        const float* __restrict__ xg,
        const float* __restrict__ proj_w, const float* __restrict__ proj_b,
        const float* __restrict__ ln_g, const float* __restrict__ ln_b,
        const float* __restrict__ w1, const float* __restrict__ b1,
        const float* __restrict__ w2, const float* __restrict__ b2,
        float* __restrict__ xg4, float* __restrict__ gout) {
    int blk = blockIdx.x; int b = blk >> 8; int n0 = (blk & 255) * 8;
    int t = threadIdx.x;
    __shared__ float xs[8][128];
    __shared__ float h[8][128];
    __shared__ float h1[8][512];
    int j = t >> 5, c4 = (t & 31) * 4;
    size_t rbase = ((size_t)(b * GN) + n0 + j) * 128 + c4;
    *(float4*)&h[j][c4] = *(const float4*)(og + rbase);
    *(float4*)&xs[j][c4] = *(const float4*)(xg + rbase);
    __syncthreads();
    int c = t & 127, g = t >> 7;
    {
        float acc[4];
        float bias = proj_b[c];
#pragma unroll
        for (int jj = 0; jj < 4; jj++) acc[jj] = bias;
        for (int k = 0; k < 128; k++) {
            float w = proj_w[k * 128 + c];
#pragma unroll
            for (int jj = 0; jj < 4; jj++) acc[jj] = fmaf(h[g * 4 + jj][k], w, acc[jj]);
        }
#pragma unroll
        for (int jj = 0; jj < 4; jj++) xs[g * 4 + jj][c] += acc[jj];
    }
    __syncthreads();
    {
        float4 v = *(float4*)&xs[j][c4];
        float s1 = shfl_sum32(v.x + v.y + v.z + v.w);
        float mu = s1 * (1.0f / 128.0f);
        float d0 = v.x - mu, d1 = v.y - mu, d2 = v.z - mu, d3 = v.w - mu;
        float s2 = shfl_sum32(d0 * d0 + d1 * d1 + d2 * d2 + d3 * d3);
        float rs = rsqrtf(s2 * (1.0f / 128.0f) + LN_EPS);
        float4 g4 = *(const float4*)(ln_g + c4);
        float4 b4 = *(const float4*)(ln_b + c4);
        float4 hn = { d0 * rs * g4.x + b4.x, d1 * rs * g4.y + b4.y,
                      d2 * rs * g4.z + b4.z, d3 * rs * g4.w + b4.w };
        *(float4*)&h[j][c4] = hn;
    }
    __syncthreads();
    {
        float acc0[8], acc1[8];
        float bi0 = b1[t], bi1 = b1[t + 256];
#pragma unroll
        for (int jj = 0; jj < 8; jj++) { acc0[jj] = bi0; acc1[jj] = bi1; }
        for (int k = 0; k < 128; k++) {
            float wa = w1[k * 512 + t];
            float wb = w1[k * 512 + t + 256];
#pragma unroll
            for (int jj = 0; jj < 8; jj++) {
                float hv = h[jj][k];
                acc0[jj] = fmaf(hv, wa, acc0[jj]);
                acc1[jj] = fmaf(hv, wb, acc1[jj]);
            }
        }
#pragma unroll
        for (int jj = 0; jj < 8; jj++) {
            h1[jj][t] = gelu_exact(acc0[jj]);
            h1[jj][t + 256] = gelu_exact(acc1[jj]);
        }
    }
    __syncthreads();
    {
        float acc[4];
        float bias = b2[c];
#pragma unroll
        for (int jj = 0; jj < 4; jj++) acc[jj] = bias;
        for (int k = 0; k < 512; k++) {
            float w = w2[k * 128 + c];
#pragma unroll
            for (int jj = 0; jj < 4; jj++) acc[jj] = fmaf(h1[g * 4 + jj][k], w, acc[jj]);
        }
#pragma unroll
        for (int jj = 0; jj < 4; jj++) {
            float ov = xs[g * 4 + jj][c] + acc[jj];
            xg4[((size_t)(b * GN) + n0 + g * 4 + jj) * 128 + c] = ov;
            h[g * 4 + jj][c] = ov;
        }
    }
    __syncthreads();
    {
        int cw = t >> 1, hf = t & 1, j0 = hf * 4;
        float4 ov = { h[j0 + 0][cw], h[j0 + 1][cw], h[j0 + 2][cw], h[j0 + 3][cw] };
        *(float4*)(gout + ((size_t)(b * 128 + cw)) * GN + n0 + j0) = ov;
    }
}

// ---------------- K4a: routing q/k ----------------
__global__ void k_routing_qk(const float* __restrict__ xg4,
                             const float* __restrict__ rq_w, const float* __restrict__ rq_b,
                             const float* __restrict__ rk_w, const float* __restrict__ rk_b,
                             float* __restrict__ qh, float* __restrict__ kh) {
    int wid = blockIdx.x; int b = wid / NW, n = wid % NW;
    int c = threadIdx.x;
    int i1 = n / 64, i2 = (n / 8) % 8, i3 = n % 8;
    __shared__ float g[CDIM];
    float s = 0.f;
#pragma unroll
    for (int j = 0; j < W3G; j++) {
        int ds = j >> 2, dh = (j >> 1) & 1, dw = j & 1;
        int gi = ((i1 * 2 + ds) * GH + (i2 * 2 + dh)) * GW + (i3 * 2 + dw);
        s += xg4[((size_t)(b * GN + gi)) * CDIM + c];
    }
    g[c] = s * (1.0f / W3G);
    __syncthreads();
    float aq = rq_b[c], ak = rk_b[c];
    for (int k = 0; k < CDIM; k++) { float gv = g[k]; aq = fmaf(gv, rq_w[k * CDIM + c], aq); ak = fmaf(gv, rk_w[k * CDIM + c], ak); }
    qh[(size_t)wid * CDIM + c] = aq;
    kh[(size_t)wid * CDIM + c] = ak;
}

// ---------------- K4b: top-k ----------------
__global__ void k_topk(const float* __restrict__ qh, const float* __restrict__ kh,
                       int* __restrict__ tidx) {
    int wid = blockIdx.x; int b = wid / NW;
    int m = threadIdx.x;
    __shared__ float q[CDIM];
    __shared__ float lv[NW];
    __shared__ int li[NW];
    if (m < CDIM) q[m] = qh[(size_t)wid * CDIM + m] * ROUTE_SCALE;
    __syncthreads();
    float acc = 0.f;
    const float* kr = kh + ((size_t)b * NW + m) * CDIM;
    for (int k = 0; k < CDIM; k++) acc = fmaf(q[k], kr[k], acc);
#pragma unroll
    for (int sel = 0; sel < TOPK; sel++) {
        lv[m] = acc; li[m] = m; __syncthreads();
#pragma unroll
        for (int s = 128; s > 0; s >>= 1) {
            if (m < s) {
                if (lv[m + s] > lv[m] || (lv[m + s] == lv[m] && li[m + s] < li[m])) {
                    lv[m] = lv[m + s]; li[m] = li[m + s];
                }
            }
            __syncthreads();
        }
        int best = li[0]; __syncthreads();
        if (m == best) acc = -1e30f;
        if (m == 0) tidx[wid * TOPK + sel] = best;
    }
}

// ---------------- K5a: LN local tokens -> lnsc bf16 ----------------
__global__ __launch_bounds__(256) void k_lnsc_local(const float* __restrict__ x_in,
        const float* __restrict__ ln_g, const float* __restrict__ ln_b,
        unsigned short* __restrict__ lnsc) {
    int blk = blockIdx.x;
    int wt = blk & 1; int hh = (blk >> 1) & 31; int s = (blk >> 6) & 15; int b = blk >> 10;
    int w0 = wt * 16;
    int t = threadIdx.x;
    __shared__ float tile[16][132];
    {
        int c = t >> 1; int wq = (t & 1) * 8;
        const float* src = x_in + (((size_t)(b * 128 + c) * SS + s)) * 1024 + hh * 32 + w0 + wq;
        float4 v0 = *(const float4*)src;
        float4 v1 = *(const float4*)(src + 4);
        tile[wq + 0][c] = v0.x; tile[wq + 1][c] = v0.y; tile[wq + 2][c] = v0.z; tile[wq + 3][c] = v0.w;
        tile[wq + 4][c] = v1.x; tile[wq + 5][c] = v1.y; tile[wq + 6][c] = v1.z; tile[wq + 7][c] = v1.w;
    }
    __syncthreads();
    int w = t >> 4; int j = t & 15;
    float vals[8];
    float s1 = 0.f;
#pragma unroll
    for (int i = 0; i < 8; i++) { vals[i] = tile[w][j * 8 + i]; s1 += vals[i]; }
    s1 = shfl_sum16(s1);
    float mu = s1 * (1.0f / 128.0f);
    float s2 = 0.f;
#pragma unroll
    for (int i = 0; i < 8; i++) { float d = vals[i] - mu; s2 += d * d; }
    s2 = shfl_sum16(s2);
    float rs = rsqrtf(s2 * (1.0f / 128.0f) + LN_EPS);
    float4 g0 = *(const float4*)(ln_g + j * 8);
    float4 g1 = *(const float4*)(ln_g + j * 8 + 4);
    float4 b0 = *(const float4*)(ln_b + j * 8);
    float4 b1 = *(const float4*)(ln_b + j * 8 + 4);
    float gv[8] = { g0.x, g0.y, g0.z, g0.w, g1.x, g1.y, g1.z, g1.w };
    float bv[8] = { b0.x, b0.y, b0.z, b0.w, b1.x, b1.y, b1.z, b1.w };
    int ww = w0 + w;
    int n = (s >> 2) * 64 + (hh >> 2) * 8 + (ww >> 2);
    int slot = (s & 3) * 16 + (hh & 3) * 4 + (ww & 3);
    unsigned short* dst = lnsc + ((size_t)(b * NW + n) * W3 + slot) * 128 + j * 8;
    ushort4 u0, u1;
    u0.x = f2bf((vals[0] - mu) * rs * gv[0] + bv[0]);
    u0.y = f2bf((vals[1] - mu) * rs * gv[1] + bv[1]);
    u0.z = f2bf((vals[2] - mu) * rs * gv[2] + bv[2]);
    u0.w = f2bf((vals[3] - mu) * rs * gv[3] + bv[3]);
    u1.x = f2bf((vals[4] - mu) * rs * gv[4] + bv[4]);
    u1.y = f2bf((vals[5] - mu) * rs * gv[5] + bv[5]);
    u1.z = f2bf((vals[6] - mu) * rs * gv[6] + bv[6]);
    u1.w = f2bf((vals[7] - mu) * rs * gv[7] + bv[7]);
    *(ushort4*)dst = u0;
    *(ushort4*)(dst + 4) = u1;
}

// ---------------- K5b: LN gathered global tokens -> lnsc bf16 ----------------
__global__ __launch_bounds__(256) void k_lnsc_gath(const float* __restrict__ xg4,
        const int* __restrict__ tidx,
        const float* __restrict__ ln_g, const float* __restrict__ ln_b,
        unsigned short* __restrict__ lnsc) {
    int blk = blockIdx.x;
    int kk = blk & 3; int wn = blk >> 2;
    int b = wn >> 8;
    int g = tidx[wn * TOPK + kk];
    int gi1 = g >> 6, gi2 = (g >> 3) & 7, gi3 = g & 7;
    int t = threadIdx.x; int j = t >> 5, lj = t & 31;
    int ds = j >> 2, dh = (j >> 1) & 1, dw = j & 1;
    int gi = ((gi1 * 2 + ds) * GH + (gi2 * 2 + dh)) * GW + (gi3 * 2 + dw);
    float4 v = *(const float4*)(xg4 + ((size_t)(b * GN + gi)) * 128 + lj * 4);
    float s1 = shfl_sum32(v.x + v.y + v.z + v.w);
    float mu = s1 * (1.0f / 128.0f);
    float d0 = v.x - mu, d1 = v.y - mu, d2 = v.z - mu, d3 = v.w - mu;
    float s2 = shfl_sum32(d0 * d0 + d1 * d1 + d2 * d2 + d3 * d3);
    float rs = rsqrtf(s2 * (1.0f / 128.0f) + LN_EPS);
    float4 g4 = *(const float4*)(ln_g + lj * 4);
    float4 b4 = *(const float4*)(ln_b + lj * 4);
    ushort4 u;
    u.x = f2bf(d0 * rs * g4.x + b4.x);
    u.y = f2bf(d1 * rs * g4.y + b4.y);
    u.z = f2bf(d2 * rs * g4.z + b4.z);
    u.w = f2bf(d3 * rs * g4.w + b4.w);
    *(ushort4*)(lnsc + ((size_t)wn * W3 + 64 + kk * 8 + j) * 128 + lj * 4) = u;
}

// ---------------- K6: local attention ----------------
__global__ __launch_bounds__(256) void k_local_attn2(const unsigned short* __restrict__ lnsc,
        const float* __restrict__ gqkv_w, const float* __restrict__ gqkv_b,
        float* __restrict__ aout) {
    int wn = blockIdx.x; int t = threadIdx.x;
    __shared__ unsigned short X[96 * 132];
    __shared__ unsigned short Ks[96 * 128];
    __shared__ unsigned short Vs[96 * 128];
    const unsigned short* src = lnsc + (size_t)wn * W3 * 128;
#pragma unroll
    for (int i = 0; i < 12; i++) {
        int e = t + 256 * i; int r = e >> 5; int c4 = (e & 31) << 2;
        *(ushort4*)&X[r * 132 + c4] = *(const ushort4*)&src[r * 128 + c4];
    }
    __syncthreads();
    {
        int wcol = 128 + t;
        float bias = gqkv_b[wcol];
        unsigned short* dst = (t < 128) ? Ks : Vs;
        int cc = t & 127;
        for (int r0 = 0; r0 < 96; r0 += 8) {
            float acc[8];
#pragma unroll
            for (int jj = 0; jj < 8; jj++) acc[jj] = 0.f;
            for (int k = 0; k < 128; k += 2) {
                float w0 = gqkv_w[k * 384 + wcol];
                float w1 = gqkv_w[(k + 1) * 384 + wcol];
#pragma unroll
                for (int jj = 0; jj < 8; jj++) {
                    unsigned int u = *(const unsigned int*)&X[(r0 + jj) * 132 + k];
                    acc[jj] = fmaf(bf2f_lo(u), w0, acc[jj]);
                    acc[jj] = fmaf(bf2f_hi(u), w1, acc[jj]);
                }
            }
#pragma unroll
            for (int jj = 0; jj < 8; jj++) dst[(r0 + jj) * 128 + cc] = f2bf(acc[jj] + bias);
        }
    }
    int wv = t >> 6, l = t & 63;
    int c0 = wv * 32;
    float q[32];
#pragma unroll
    for (int jj = 0; jj < 32; jj++) q[jj] = gqkv_b[c0 + jj];
    for (int k = 0; k < 128; k += 2) {
        unsigned int u = *(const unsigned int*)&X[l * 132 + k];
        float f0 = bf2f_lo(u), f1 = bf2f_hi(u);
        const float* wr0 = gqkv_w + k * 384 + c0;
        const float* wr1 = wr0 + 384;
#pragma unroll
        for (int j4 = 0; j4 < 8; j4++) {
            float4 a = *(const float4*)(wr0 + j4 * 4);
            float4 bb = *(const float4*)(wr1 + j4 * 4);
            q[j4 * 4 + 0] = fmaf(f0, a.x, fmaf(f1, bb.x, q[j4 * 4 + 0]));
            q[j4 * 4 + 1] = fmaf(f0, a.y, fmaf(f1, bb.y, q[j4 * 4 + 1]));
            q[j4 * 4 + 2] = fmaf(f0, a.z, fmaf(f1, bb.z, q[j4 * 4 + 2]));
            q[j4 * 4 + 3] = fmaf(f0, a.w, fmaf(f1, bb.w, q[j4 * 4 + 3]));
        }
    }
#pragma unroll
    for (int jj = 0; jj < 32; jj++) q[jj] *= ROUTE_SCALE;
    __syncthreads();
    float* outp = aout + ((size_t)wn * W3L + l) * 128;
    for (int hh2 = 0; hh2 < 2; hh2++) {
        int hh = wv * 2 + hh2; int qo = hh2 * 16;
        float sc[96]; float mx = -1e30f;
#pragma unroll
        for (int r = 0; r < 96; r++) {
            const unsigned short* kr = &Ks[r * 128 + hh * 16];
            float s = 0.f;
#pragma unroll
            for (int d2 = 0; d2 < 8; d2++) {
                unsigned int u = *(const unsigned int*)&kr[d2 * 2];
                s = fmaf(bf2f_lo(u), q[qo + d2 * 2], s);
                s = fmaf(bf2f_hi(u), q[qo + d2 * 2 + 1], s);
            }
            sc[r] = s; mx = fmaxf(mx, s);
        }
        float sum = 0.f; float o[16];
#pragma unroll
        for (int d = 0; d < 16; d++) o[d] = 0.f;
#pragma unroll
        for (int r = 0; r < 96; r++) {
            float p = __expf(sc[r] - mx); sum += p;
            const unsigned short* vr = &Vs[r * 128 + hh * 16];
#pragma unroll
            for (int d2 = 0; d2 < 8; d2++) {
                unsigned int u = *(const unsigned int*)&vr[d2 * 2];
                o[d2 * 2] = fmaf(p, bf2f_lo(u), o[d2 * 2]);
                o[d2 * 2 + 1] = fmaf(p, bf2f_hi(u), o[d2 * 2 + 1]);
            }
        }
        float inv = 1.f / sum;
#pragma unroll
        for (int d4 = 0; d4 < 4; d4++) {
            float4 vv = { o[d4 * 4] * inv, o[d4 * 4 + 1] * inv, o[d4 * 4 + 2] * inv, o[d4 * 4 + 3] * inv };
            *(float4*)(outp + hh * 16 + d4 * 4) = vv;
        }
    }
}

// ---------------- K7: wo projection + shortcut (T=8) ----------------
__global__ __launch_bounds__(256) void k_wo2(const float* __restrict__ aout,
        const float* __restrict__ wo_w, const float* __restrict__ wo_b,
        const float* __restrict__ x_in, float* __restrict__ lpre) {
    int blk = blockIdx.x; int wn = blk >> 3; int g8 = blk & 7;
    int b = wn >> 8; int n = wn & 255;
    int t = threadIdx.x;
    __shared__ float as[8][128];
    {
        int j = t >> 5, c4 = (t & 31) << 2;
        *(float4*)&as[j][c4] = *(const float4*)(aout + ((size_t)wn * W3L + g8 * 8 + j) * 128 + c4);
    }
    __syncthreads();
    int c = t & 127, g = t >> 7;
    float acc[4];
    float bias = wo_b[c];
#pragma unroll
    for (int jj = 0; jj < 4; jj++) acc[jj] = bias;
    for (int k = 0; k < 128; k++) {
        float w = wo_w[k * 128 + c];
#pragma unroll
        for (int jj = 0; jj < 4; jj++) acc[jj] = fmaf(as[g * 4 + jj][k], w, acc[jj]);
    }
    int i1 = n >> 6, i2 = (n >> 3) & 7, i3 = n & 7;
    int s0 = g8 * 8 + g * 4;
    int dsl = s0 >> 4, dh = (s0 >> 2) & 3;
    int s = i1 * 4 + dsl, hh = i2 * 4 + dh, ww0 = i3 * 4;
    float4 sc4 = *(const float4*)(x_in + (((size_t)(b * 128 + c) * SS + s)) * 1024 + hh * 32 + ww0);
    float ov[4] = { acc[0] + sc4.x, acc[1] + sc4.y, acc[2] + sc4.z, acc[3] + sc4.w };
    size_t obase = ((((size_t)(b * SS + s)) * HH_ + hh) * WW_ + ww0) * 128 + c;
#pragma unroll
    for (int jj = 0; jj < 4; jj++) lpre[obase + (size_t)jj * 128] = ov[jj];
}

// ---------------- K8: LN + MLP2 + residual, transposed out (T=8) ----------------
__global__ __launch_bounds__(256) void k_mlp22(const float* __restrict__ lpre,
        const float* __restrict__ ln_g, const float* __restrict__ ln_b,
        const float* __restrict__ w1, const float* __restrict__ b1,
        const float* __restrict__ w2, const float* __restrict__ b2,
        float* __restrict__ lout) {
    int blk = blockIdx.x;
    int b = blk >> 11; int sp0 = (blk & 2047) * 8;
    int t = threadIdx.x;
    __shared__ float xs[8][128];
    __shared__ float h[8][128];
    __shared__ float h1[8][512];
    int j = t >> 5, c4 = (t & 31) * 4;
    float4 v = *(const float4*)(lpre + ((size_t)(b * NSP) + sp0 + j) * 128 + c4);
    *(float4*)&xs[j][c4] = v;
    float s1 = shfl_sum32(v.x + v.y + v.z + v.w);
    float mu = s1 * (1.0f / 128.0f);
    float d0 = v.x - mu, d1 = v.y - mu, d2 = v.z - mu, d3 = v.w - mu;
    float s2 = shfl_sum32(d0 * d0 + d1 * d1 + d2 * d2 + d3 * d3);
    float rs = rsqrtf(s2 * (1.0f / 128.0f) + LN_EPS);
    float4 g4 = *(const float4*)(ln_g + c4);
    float4 b4 = *(const float4*)(ln_b + c4);
    float4 hn = { d0 * rs * g4.x + b4.x, d1 * rs * g4.y + b4.y,
                  d2 * rs * g4.z + b4.z, d3 * rs * g4.w + b4.w };
    *(float4*)&h[j][c4] = hn;
    __syncthreads();
    {
        float acc0[8], acc1[8];
        float bi0 = b1[t], bi1 = b1[t + 256];
#pragma unroll
        for (int jj = 0; jj < 8; jj++) { acc0[jj] = bi0; acc1[jj] = bi1; }
        for (int k = 0; k < 128; k++) {
            float wa = w1[k * 512 + t];
            float wb = w1[k * 512 + t + 256];
#pragma unroll
            for (int jj = 0; jj < 8; jj++) {
                float hv = h[jj][k];
                acc0[jj] = fmaf(hv, wa, acc0[jj]);
                acc1[jj] = fmaf(hv, wb, acc1[jj]);
            }
        }
#pragma unroll
        for (int jj = 0; jj < 8; jj++) {
            h1[jj][t] = gelu_exact(acc0[jj]);
            h1[jj][t + 256] = gelu_exact(acc1[jj]);
        }
    }
    __syncthreads();
    int c = t & 127, g = t >> 7;
    {
        float acc[4];
        float bias = b2[c];
#pragma unroll
        for (int jj = 0; jj < 4; jj++) acc[jj] = bias;
        for (int k = 0; k < 512; k++) {
            float w = w2[k * 128 + c];
#pragma unroll
            for (int jj = 0; jj < 4; jj++) acc[jj] = fmaf(h1[g * 4 + jj][k], w, acc[jj]);
        }
#pragma unroll
        for (int jj = 0; jj < 4; jj++) h[g * 4 + jj][c] = xs[g * 4 + jj][c] + acc[jj];
    }
    __syncthreads();
    {
        int cw = t >> 1, hf = t & 1, j0 = hf * 4;
        float4 ov = { h[j0 + 0][cw], h[j0 + 1][cw], h[j0 + 2][cw], h[j0 + 3][cw] };
        *(float4*)(lout + ((size_t)(b * 128 + cw)) * NSP + sp0 + j0) = ov;
    }
}

extern "C" void kernel_launch(void* const* d_in, const int* in_sizes, int n_in,
                              void* d_out, int out_size, void* d_ws, size_t ws_size,
                              hipStream_t stream) {
    const float* x_in   = (const float*)d_in[0];
    const float* xg_in  = (const float*)d_in[1];
    const float* qkv_w  = (const float*)d_in[2];
    const float* qkv_b  = (const float*)d_in[3];
    const float* proj_w = (const float*)d_in[4];
    const float* proj_b = (const float*)d_in[5];
    const float* ln_g   = (const float*)d_in[6];
    const float* ln_b   = (const float*)d_in[7];
    const float* mlp_w1 = (const float*)d_in[8];
    const float* mlp_b1 = (const float*)d_in[9];
    const float* mlp_w2 = (const float*)d_in[10];
    const float* mlp_b2 = (const float*)d_in[11];
    const float* rq_w   = (const float*)d_in[12];
    const float* rq_b   = (const float*)d_in[13];
    const float* rk_w   = (const float*)d_in[14];
    const float* rk_b   = (const float*)d_in[15];
    const float* gqkv_w = (const float*)d_in[16];
    const float* gqkv_b = (const float*)d_in[17];
    const float* wo_w   = (const float*)d_in[18];
    const float* wo_b   = (const float*)d_in[19];
    const float* m2_w1  = (const float*)d_in[20];
    const float* m2_b1  = (const float*)d_in[21];
    const float* m2_w2  = (const float*)d_in[22];
    const float* m2_b2  = (const float*)d_in[23];

    float* out = (float*)d_out;
    float* ws  = (float*)d_ws;

    float* xg4 = ws;                                         // 524288
    float* xg  = ws + 524288;                                // 524288
    unsigned short* qgb  = (unsigned short*)(ws + 1048576);  // 524288 bf16
    unsigned short* kgb  = (unsigned short*)(ws + 1310720);  // 524288 bf16
    unsigned short* vgtb = (unsigned short*)(ws + 1572864);  // 524288 bf16 (V^T)
    float* og  = ws + 1835008;                               // 524288
    float* qh  = ws + 2359296;                               // 65536
    float* kh  = ws + 2424832;                               // 65536
    int*   tidx = (int*)(ws + 2490368);                      // 2048
    unsigned short* lnsc = (unsigned short*)(ws + 2492416);  // 6291456 bf16
    float* aout = ws + 2492416 + 3145728;                    // 4194304
    float* lpre = ws + 9832448;                              // 4194304

    const size_t L_OUT = (size_t)BATCH * CDIM * NSP;
    float* gout = out + L_OUT;

    hipLaunchKernelGGL(k_gqkv2, dim3(512), dim3(256), 0, stream,
                       xg_in, qkv_w, qkv_b, ln_g, ln_b, xg, qgb, kgb, vgtb);
    hipLaunchKernelGGL(k_gattn_mfma, dim3(2048), dim3(256), 0, stream, qgb, kgb, vgtb, og);
    hipLaunchKernelGGL(k_gmlp2, dim3(512), dim3(256), 0, stream,
                       og, xg, proj_w, proj_b, ln_g, ln_b, mlp_w1, mlp_b1, mlp_w2, mlp_b2,
                       xg4, gout);
    hipLaunchKernelGGL(k_routing_qk, dim3(512), dim3(128), 0, stream,
                       xg4, rq_w, rq_b, rk_w, rk_b, qh, kh);
    hipLaunchKernelGGL(k_topk, dim3(512), dim3(256), 0, stream, qh, kh, tidx);
    hipLaunchKernelGGL(k_lnsc_local, dim3(2048), dim3(256), 0, stream,
                       x_in, ln_g, ln_b, lnsc);
    hipLaunchKernelGGL(k_lnsc_gath, dim3(2048), dim3(256), 0, stream,
                       xg4, tidx, ln_g, ln_b, lnsc);
    hipLaunchKernelGGL(k_local_attn2, dim3(512), dim3(256), 0, stream,
                       lnsc, gqkv_w, gqkv_b, aout);
    hipLaunchKernelGGL(k_wo2, dim3(4096), dim3(256), 0, stream,
                       aout, wo_w, wo_b, x_in, lpre);
    hipLaunchKernelGGL(k_mlp22, dim3(4096), dim3(256), 0, stream,
                       lpre, ln_g, ln_b, m2_w1, m2_b1, m2_w2, m2_b2, out);
}

// Round 4
// 470.915 us; speedup vs baseline: 5.4792x; 1.4792x over previous
//
#include <hip/hip_runtime.h>
#include <hip/hip_bf16.h>
#include <math.h>

#define BATCH 2
#define CDIM 128
#define SS 16
#define HH_ 32
#define WW_ 32
#define NSP (SS*HH_*WW_)
#define GS 8
#define GH 16
#define GW 16
#define GN (GS*GH*GW)
#define HEADS 8
#define DH 16
#define NW 256
#define W3L 64
#define W3G 8
#define TOPK 4
#define W3 (W3L + TOPK*W3G)
#define LN_EPS 1e-6f
#define ROUTE_SCALE 0.08838834764831845f
#define GATTN_SCALE 0.25f

typedef short bshort8 __attribute__((ext_vector_type(8)));
typedef float f32x4 __attribute__((ext_vector_type(4)));

__device__ __forceinline__ unsigned short f2bf(float f) {
    unsigned int u = __float_as_uint(f);
    unsigned int r = (u + 0x7fffu + ((u >> 16) & 1u)) >> 16;
    return (unsigned short)r;
}
__device__ __forceinline__ float bf2f_lo(unsigned int u) { return __uint_as_float(u << 16); }
__device__ __forceinline__ float bf2f_hi(unsigned int u) { return __uint_as_float(u & 0xffff0000u); }

__device__ __forceinline__ float gelu_exact(float x) {
    return 0.5f * x * (1.0f + erff(x * 0.70710678118654752f));
}

__device__ __forceinline__ float shfl_sum32(float v) {
#pragma unroll
    for (int m = 16; m > 0; m >>= 1) v += __shfl_xor(v, m);
    return v;
}
__device__ __forceinline__ float shfl_sum16(float v) {
#pragma unroll
    for (int m = 8; m > 0; m >>= 1) v += __shfl_xor(v, m);
    return v;
}

// ---------------- K0: transpose gqkv_w -> bf16 W^T[384][128], scale folded for Q ----------------
__global__ __launch_bounds__(256) void k_wtrans(const float* __restrict__ gqkv_w,
                                                unsigned short* __restrict__ wt) {
    int id = blockIdx.x * 256 + threadIdx.x;   // 0..49151
    int n = id >> 7, k = id & 127;
    float v = gqkv_w[k * 384 + n];
    if (n < 128) v *= ROUTE_SCALE;
    wt[id] = f2bf(v);
}

// ---------------- K1: global branch qkv (T=8 tokens/block), bf16 q/k/v^T out ----------------
__global__ __launch_bounds__(256) void k_gqkv2(const float* __restrict__ xg_in,
        const float* __restrict__ qkv_w, const float* __restrict__ qkv_b,
        const float* __restrict__ ln_g, const float* __restrict__ ln_b,
        float* __restrict__ xg, unsigned short* __restrict__ qgb,
        unsigned short* __restrict__ kgb, unsigned short* __restrict__ vgtb) {
    int blk = blockIdx.x; int b = blk >> 8; int n0 = (blk & 255) * 8;
    int t = threadIdx.x;
    __shared__ float xs[8][128];
    __shared__ float h[8][128];
    {
        int c = t >> 1, q4 = (t & 1) * 4;
        float4 v = *(const float4*)(xg_in + ((size_t)(b * 128 + c)) * GN + n0 + q4);
        xs[q4 + 0][c] = v.x; xs[q4 + 1][c] = v.y; xs[q4 + 2][c] = v.z; xs[q4 + 3][c] = v.w;
    }
    __syncthreads();
    int j = t >> 5, c4 = (t & 31) * 4;
    float4 v = *(float4*)&xs[j][c4];
    *(float4*)(xg + ((size_t)(b * GN) + n0 + j) * 128 + c4) = v;
    float s1 = shfl_sum32(v.x + v.y + v.z + v.w);
    float mu = s1 * (1.0f / 128.0f);
    float d0 = v.x - mu, d1 = v.y - mu, d2 = v.z - mu, d3 = v.w - mu;
    float s2 = shfl_sum32(d0 * d0 + d1 * d1 + d2 * d2 + d3 * d3);
    float rs = rsqrtf(s2 * (1.0f / 128.0f) + LN_EPS);
    float4 g4 = *(const float4*)(ln_g + c4);
    float4 b4 = *(const float4*)(ln_b + c4);
    float4 hn = { d0 * rs * g4.x + b4.x, d1 * rs * g4.y + b4.y,
                  d2 * rs * g4.z + b4.z, d3 * rs * g4.w + b4.w };
    *(float4*)&h[j][c4] = hn;
    __syncthreads();
    for (int c = t; c < 384; c += 256) {
        float acc[8];
        float bias = qkv_b[c];
#pragma unroll
        for (int jj = 0; jj < 8; jj++) acc[jj] = bias;
        for (int k = 0; k < 128; k++) {
            float w = qkv_w[k * 384 + c];
#pragma unroll
            for (int jj = 0; jj < 8; jj++) acc[jj] = fmaf(h[jj][k], w, acc[jj]);
        }
        int part = c >> 7, head = (c >> 4) & 7, d = c & 15;
        int bh = b * HEADS + head;
        if (part == 0) {
#pragma unroll
            for (int jj = 0; jj < 8; jj++)
                qgb[((size_t)bh * GN + n0 + jj) * DH + d] = f2bf(acc[jj] * GATTN_SCALE);
        } else if (part == 1) {
#pragma unroll
            for (int jj = 0; jj < 8; jj++)
                kgb[((size_t)bh * GN + n0 + jj) * DH + d] = f2bf(acc[jj]);
        } else {
            ushort4 u0, u1;
            u0.x = f2bf(acc[0]); u0.y = f2bf(acc[1]); u0.z = f2bf(acc[2]); u0.w = f2bf(acc[3]);
            u1.x = f2bf(acc[4]); u1.y = f2bf(acc[5]); u1.z = f2bf(acc[6]); u1.w = f2bf(acc[7]);
            unsigned short* dst = vgtb + ((size_t)bh * DH + d) * GN + n0;
            *(ushort4*)dst = u0; *(ushort4*)(dst + 4) = u1;
        }
    }
}

// ---------------- K2: global attention via MFMA bf16 ----------------
__global__ __launch_bounds__(256) void k_gattn_mfma(const unsigned short* __restrict__ qgb,
        const unsigned short* __restrict__ kgb, const unsigned short* __restrict__ vgtb,
        float* __restrict__ og) {
    int blk = blockIdx.x;
    int bh = blk >> 7; int qt = (blk & 127) << 4;
    int b = bh >> 3, hh = bh & 7;
    int t = threadIdx.x; int w = t >> 6; int lane = t & 63;
    int col = lane & 15, quad = lane >> 4;
    __shared__ __align__(16) unsigned short Pbuf[4 * 16 * 40];
    __shared__ float po[4][64][4];
    __shared__ float pl[4][64][4];

    bshort8 aq = {0, 0, 0, 0, 0, 0, 0, 0};
    if (quad < 2)
        aq = *(const bshort8*)(qgb + ((size_t)bh * GN + qt + col) * DH + quad * 8);

    f32x4 o = {0.f, 0.f, 0.f, 0.f};
    float lsum[4] = {0.f, 0.f, 0.f, 0.f};
    const unsigned short* kb = kgb + (size_t)bh * GN * DH;
    const unsigned short* vb = vgtb + (size_t)bh * DH * GN;
    unsigned short* pb = Pbuf + w * (16 * 40);
    int row0 = quad * 4;
    int kbeg = w * 512;
    for (int kc = kbeg; kc < kbeg + 512; kc += 32) {
        bshort8 bk0 = {0, 0, 0, 0, 0, 0, 0, 0};
        bshort8 bk1 = {0, 0, 0, 0, 0, 0, 0, 0};
        if (quad < 2) {
            bk0 = *(const bshort8*)(kb + (size_t)(kc + col) * DH + quad * 8);
            bk1 = *(const bshort8*)(kb + (size_t)(kc + 16 + col) * DH + quad * 8);
        }
        f32x4 z = {0.f, 0.f, 0.f, 0.f};
        f32x4 s0 = __builtin_amdgcn_mfma_f32_16x16x32_bf16(aq, bk0, z, 0, 0, 0);
        f32x4 s1 = __builtin_amdgcn_mfma_f32_16x16x32_bf16(aq, bk1, z, 0, 0, 0);
        float p0[4], p1[4];
#pragma unroll
        for (int r = 0; r < 4; r++) {
            p0[r] = __expf(s0[r]); p1[r] = __expf(s1[r]);
            lsum[r] += p0[r] + p1[r];
        }
#pragma unroll
        for (int r = 0; r < 4; r++) {
            pb[(row0 + r) * 40 + col] = f2bf(p0[r]);
            pb[(row0 + r) * 40 + 16 + col] = f2bf(p1[r]);
        }
        bshort8 pA = *(const bshort8*)(pb + col * 40 + quad * 8);
        bshort8 bv = *(const bshort8*)(vb + (size_t)col * GN + kc + quad * 8);
        o = __builtin_amdgcn_mfma_f32_16x16x32_bf16(pA, bv, o, 0, 0, 0);
    }
#pragma unroll
    for (int r = 0; r < 4; r++) {
        float v = lsum[r];
        v += __shfl_xor(v, 1); v += __shfl_xor(v, 2);
        v += __shfl_xor(v, 4); v += __shfl_xor(v, 8);
        lsum[r] = v;
    }
#pragma unroll
    for (int r = 0; r < 4; r++) { po[w][lane][r] = o[r]; pl[w][lane][r] = lsum[r]; }
    __syncthreads();
    if (w == 0) {
#pragma unroll
        for (int r = 0; r < 4; r++) {
            float os = po[0][lane][r] + po[1][lane][r] + po[2][lane][r] + po[3][lane][r];
            float ls = pl[0][lane][r] + pl[1][lane][r] + pl[2][lane][r] + pl[3][lane][r];
            og[((size_t)(b * GN) + qt + quad * 4 + r) * 128 + hh * 16 + col] = os / ls;
        }
    }
}

// ---------------- K3: global proj+residual+LN+MLP (T=8) ----------------
__global__ __launch_bounds__(256) void k_gmlp2(const float* __restrict__ og,
        const float* __restrict__ xg,
        const float* __restrict__ proj_w, const float* __restrict__ proj_b,
        const float* __restrict__ ln_g, const float* __restrict__ ln_b,
        const float* __restrict__ w1, const float* __restrict__ b1,
        const float* __restrict__ w2, const float* __restrict__ b2,
        float* __restrict__ xg4, float* __restrict__ gout) {
    int blk = blockIdx.x; int b = blk >> 8; int n0 = (blk & 255) * 8;
    int t = threadIdx.x;
    __shared__ float xs[8][128];
    __shared__ float h[8][128];
    __shared__ float h1[8][512];
    int j = t >> 5, c4 = (t & 31) * 4;
    size_t rbase = ((size_t)(b * GN) + n0 + j) * 128 + c4;
    *(float4*)&h[j][c4] = *(const float4*)(og + rbase);
    *(float4*)&xs[j][c4] = *(const float4*)(xg + rbase);
    __syncthreads();
    int c = t & 127, g = t >> 7;
    {
        float acc[4];
        float bias = proj_b[c];
#pragma unroll
        for (int jj = 0; jj < 4; jj++) acc[jj] = bias;
        for (int k = 0; k < 128; k++) {
            float w = proj_w[k * 128 + c];
#pragma unroll
            for (int jj = 0; jj < 4; jj++) acc[jj] = fmaf(h[g * 4 + jj][k], w, acc[jj]);
        }
#pragma unroll
        for (int jj = 0; jj < 4; jj++) xs[g * 4 + jj][c] += acc[jj];
    }
    __syncthreads();
    {
        float4 v = *(float4*)&xs[j][c4];
        float s1 = shfl_sum32(v.x + v.y + v.z + v.w);
        float mu = s1 * (1.0f / 128.0f);
        float d0 = v.x - mu, d1 = v.y - mu, d2 = v.z - mu, d3 = v.w - mu;
        float s2 = shfl_sum32(d0 * d0 + d1 * d1 + d2 * d2 + d3 * d3);
        float rs = rsqrtf(s2 * (1.0f / 128.0f) + LN_EPS);
        float4 g4 = *(const float4*)(ln_g + c4);
        float4 b4 = *(const float4*)(ln_b + c4);
        float4 hn = { d0 * rs * g4.x + b4.x, d1 * rs * g4.y + b4.y,
                      d2 * rs * g4.z + b4.z, d3 * rs * g4.w + b4.w };
        *(float4*)&h[j][c4] = hn;
    }
    __syncthreads();
    {
        float acc0[8], acc1[8];
        float bi0 = b1[t], bi1 = b1[t + 256];
#pragma unroll
        for (int jj = 0; jj < 8; jj++) { acc0[jj] = bi0; acc1[jj] = bi1; }
        for (int k = 0; k < 128; k++) {
            float wa = w1[k * 512 + t];
            float wb = w1[k * 512 + t + 256];
#pragma unroll
            for (int jj = 0; jj < 8; jj++) {
                float hv = h[jj][k];
                acc0[jj] = fmaf(hv, wa, acc0[jj]);
                acc1[jj] = fmaf(hv, wb, acc1[jj]);
            }
        }
#pragma unroll
        for (int jj = 0; jj < 8; jj++) {
            h1[jj][t] = gelu_exact(acc0[jj]);
            h1[jj][t + 256] = gelu_exact(acc1[jj]);
        }
    }
    __syncthreads();
    {
        float acc[4];
        float bias = b2[c];
#pragma unroll
        for (int jj = 0; jj < 4; jj++) acc[jj] = bias;
        for (int k = 0; k < 512; k++) {
            float w = w2[k * 128 + c];
#pragma unroll
            for (int jj = 0; jj < 4; jj++) acc[jj] = fmaf(h1[g * 4 + jj][k], w, acc[jj]);
        }
#pragma unroll
        for (int jj = 0; jj < 4; jj++) {
            float ov = xs[g * 4 + jj][c] + acc[jj];
            xg4[((size_t)(b * GN) + n0 + g * 4 + jj) * 128 + c] = ov;
            h[g * 4 + jj][c] = ov;
        }
    }
    __syncthreads();
    {
        int cw = t >> 1, hf = t & 1, j0 = hf * 4;
        float4 ov = { h[j0 + 0][cw], h[j0 + 1][cw], h[j0 + 2][cw], h[j0 + 3][cw] };
        *(float4*)(gout + ((size_t)(b * 128 + cw)) * GN + n0 + j0) = ov;
    }
}

// ---------------- K4a: routing q/k ----------------
__global__ void k_routing_qk(const float* __restrict__ xg4,
                             const float* __restrict__ rq_w, const float* __restrict__ rq_b,
                             const float* __restrict__ rk_w, const float* __restrict__ rk_b,
                             float* __restrict__ qh, float* __restrict__ kh) {
    int wid = blockIdx.x; int b = wid / NW, n = wid % NW;
    int c = threadIdx.x;
    int i1 = n / 64, i2 = (n / 8) % 8, i3 = n % 8;
    __shared__ float g[CDIM];
    float s = 0.f;
#pragma unroll
    for (int j = 0; j < W3G; j++) {
        int ds = j >> 2, dh = (j >> 1) & 1, dw = j & 1;
        int gi = ((i1 * 2 + ds) * GH + (i2 * 2 + dh)) * GW + (i3 * 2 + dw);
        s += xg4[((size_t)(b * GN + gi)) * CDIM + c];
    }
    g[c] = s * (1.0f / W3G);
    __syncthreads();
    float aq = rq_b[c], ak = rk_b[c];
    for (int k = 0; k < CDIM; k++) { float gv = g[k]; aq = fmaf(gv, rq_w[k * CDIM + c], aq); ak = fmaf(gv, rk_w[k * CDIM + c], ak); }
    qh[(size_t)wid * CDIM + c] = aq;
    kh[(size_t)wid * CDIM + c] = ak;
}

// ---------------- K4b: top-k ----------------
__global__ void k_topk(const float* __restrict__ qh, const float* __restrict__ kh,
                       int* __restrict__ tidx) {
    int wid = blockIdx.x; int b = wid / NW;
    int m = threadIdx.x;
    __shared__ float q[CDIM];
    __shared__ float lv[NW];
    __shared__ int li[NW];
    if (m < CDIM) q[m] = qh[(size_t)wid * CDIM + m] * ROUTE_SCALE;
    __syncthreads();
    float acc = 0.f;
    const float* kr = kh + ((size_t)b * NW + m) * CDIM;
    for (int k = 0; k < CDIM; k++) acc = fmaf(q[k], kr[k], acc);
#pragma unroll
    for (int sel = 0; sel < TOPK; sel++) {
        lv[m] = acc; li[m] = m; __syncthreads();
#pragma unroll
        for (int s = 128; s > 0; s >>= 1) {
            if (m < s) {
                if (lv[m + s] > lv[m] || (lv[m + s] == lv[m] && li[m + s] < li[m])) {
                    lv[m] = lv[m + s]; li[m] = li[m + s];
                }
            }
            __syncthreads();
        }
        int best = li[0]; __syncthreads();
        if (m == best) acc = -1e30f;
        if (m == 0) tidx[wid * TOPK + sel] = best;
    }
}

// ---------------- K5a: LN local tokens -> lnsc bf16 ----------------
__global__ __launch_bounds__(256) void k_lnsc_local(const float* __restrict__ x_in,
        const float* __restrict__ ln_g, const float* __restrict__ ln_b,
        unsigned short* __restrict__ lnsc) {
    int blk = blockIdx.x;
    int wt = blk & 1; int hh = (blk >> 1) & 31; int s = (blk >> 6) & 15; int b = blk >> 10;
    int w0 = wt * 16;
    int t = threadIdx.x;
    __shared__ float tile[16][132];
    {
        int c = t >> 1; int wq = (t & 1) * 8;
        const float* src = x_in + (((size_t)(b * 128 + c) * SS + s)) * 1024 + hh * 32 + w0 + wq;
        float4 v0 = *(const float4*)src;
        float4 v1 = *(const float4*)(src + 4);
        tile[wq + 0][c] = v0.x; tile[wq + 1][c] = v0.y; tile[wq + 2][c] = v0.z; tile[wq + 3][c] = v0.w;
        tile[wq + 4][c] = v1.x; tile[wq + 5][c] = v1.y; tile[wq + 6][c] = v1.z; tile[wq + 7][c] = v1.w;
    }
    __syncthreads();
    int w = t >> 4; int j = t & 15;
    float vals[8];
    float s1 = 0.f;
#pragma unroll
    for (int i = 0; i < 8; i++) { vals[i] = tile[w][j * 8 + i]; s1 += vals[i]; }
    s1 = shfl_sum16(s1);
    float mu = s1 * (1.0f / 128.0f);
    float s2 = 0.f;
#pragma unroll
    for (int i = 0; i < 8; i++) { float d = vals[i] - mu; s2 += d * d; }
    s2 = shfl_sum16(s2);
    float rs = rsqrtf(s2 * (1.0f / 128.0f) + LN_EPS);
    float4 g0 = *(const float4*)(ln_g + j * 8);
    float4 g1 = *(const float4*)(ln_g + j * 8 + 4);
    float4 b0 = *(const float4*)(ln_b + j * 8);
    float4 b1 = *(const float4*)(ln_b + j * 8 + 4);
    float gv[8] = { g0.x, g0.y, g0.z, g0.w, g1.x, g1.y, g1.z, g1.w };
    float bv[8] = { b0.x, b0.y, b0.z, b0.w, b1.x, b1.y, b1.z, b1.w };
    int ww = w0 + w;
    int n = (s >> 2) * 64 + (hh >> 2) * 8 + (ww >> 2);
    int slot = (s & 3) * 16 + (hh & 3) * 4 + (ww & 3);
    unsigned short* dst = lnsc + ((size_t)(b * NW + n) * W3 + slot) * 128 + j * 8;
    ushort4 u0, u1;
    u0.x = f2bf((vals[0] - mu) * rs * gv[0] + bv[0]);
    u0.y = f2bf((vals[1] - mu) * rs * gv[1] + bv[1]);
    u0.z = f2bf((vals[2] - mu) * rs * gv[2] + bv[2]);
    u0.w = f2bf((vals[3] - mu) * rs * gv[3] + bv[3]);
    u1.x = f2bf((vals[4] - mu) * rs * gv[4] + bv[4]);
    u1.y = f2bf((vals[5] - mu) * rs * gv[5] + bv[5]);
    u1.z = f2bf((vals[6] - mu) * rs * gv[6] + bv[6]);
    u1.w = f2bf((vals[7] - mu) * rs * gv[7] + bv[7]);
    *(ushort4*)dst = u0;
    *(ushort4*)(dst + 4) = u1;
}

// ---------------- K5b: LN gathered global tokens -> lnsc bf16 ----------------
__global__ __launch_bounds__(256) void k_lnsc_gath(const float* __restrict__ xg4,
        const int* __restrict__ tidx,
        const float* __restrict__ ln_g, const float* __restrict__ ln_b,
        unsigned short* __restrict__ lnsc) {
    int blk = blockIdx.x;
    int kk = blk & 3; int wn = blk >> 2;
    int b = wn >> 8;
    int g = tidx[wn * TOPK + kk];
    int gi1 = g >> 6, gi2 = (g >> 3) & 7, gi3 = g & 7;
    int t = threadIdx.x; int j = t >> 5, lj = t & 31;
    int ds = j >> 2, dh = (j >> 1) & 1, dw = j & 1;
    int gi = ((gi1 * 2 + ds) * GH + (gi2 * 2 + dh)) * GW + (gi3 * 2 + dw);
    float4 v = *(const float4*)(xg4 + ((size_t)(b * GN + gi)) * 128 + lj * 4);
    float s1 = shfl_sum32(v.x + v.y + v.z + v.w);
    float mu = s1 * (1.0f / 128.0f);
    float d0 = v.x - mu, d1 = v.y - mu, d2 = v.z - mu, d3 = v.w - mu;
    float s2 = shfl_sum32(d0 * d0 + d1 * d1 + d2 * d2 + d3 * d3);
    float rs = rsqrtf(s2 * (1.0f / 128.0f) + LN_EPS);
    float4 g4 = *(const float4*)(ln_g + lj * 4);
    float4 b4 = *(const float4*)(ln_b + lj * 4);
    ushort4 u;
    u.x = f2bf(d0 * rs * g4.x + b4.x);
    u.y = f2bf(d1 * rs * g4.y + b4.y);
    u.z = f2bf(d2 * rs * g4.z + b4.z);
    u.w = f2bf(d3 * rs * g4.w + b4.w);
    *(ushort4*)(lnsc + ((size_t)wn * W3 + 64 + kk * 8 + j) * 128 + lj * 4) = u;
}

// ---------------- K6: local attention via MFMA. one window / 256-thread block ----------------
// LDS: Q[64][136], K[96][136], Vt[128][104], P[4][16][40]  = 75264 B
__global__ __launch_bounds__(256) void k_local_mfma(const unsigned short* __restrict__ lnsc,
        const unsigned short* __restrict__ wt, const float* __restrict__ gqkv_b,
        float* __restrict__ aout) {
    int wn = blockIdx.x;
    int t = threadIdx.x; int w = t >> 6; int lane = t & 63;
    int l15 = lane & 15, quad = lane >> 4;
    __shared__ __align__(16) unsigned short Qs[64 * 136];
    __shared__ __align__(16) unsigned short Ks2[96 * 136];
    __shared__ __align__(16) unsigned short Vts[128 * 104];
    __shared__ __align__(16) unsigned short Ps[4][16 * 40];

    const unsigned short* Xb = lnsc + (size_t)wn * W3 * 128;
    f32x4 zero4 = {0.f, 0.f, 0.f, 0.f};

    // ---- projection phase ----
    // Q tiles: mt 0..3, nt in {w, w+4}
    for (int mt = 0; mt < 4; mt++) {
        bshort8 a[4];
#pragma unroll
        for (int ks = 0; ks < 4; ks++)
            a[ks] = *(const bshort8*)(Xb + (mt * 16 + l15) * 128 + ks * 32 + quad * 8);
#pragma unroll
        for (int which = 0; which < 2; which++) {
            int n0 = (w + which * 4) * 16;
            f32x4 acc = zero4;
#pragma unroll
            for (int ks = 0; ks < 4; ks++) {
                bshort8 bfr = *(const bshort8*)(wt + (n0 + l15) * 128 + ks * 32 + quad * 8);
                acc = __builtin_amdgcn_mfma_f32_16x16x32_bf16(a[ks], bfr, acc, 0, 0, 0);
            }
            float bias = gqkv_b[n0 + l15] * ROUTE_SCALE;
#pragma unroll
            for (int r = 0; r < 4; r++)
                Qs[(mt * 16 + quad * 4 + r) * 136 + n0 + l15] = f2bf(acc[r] + bias);
        }
    }
    // K tiles: mt 0..5, nt8 in {w, w+4}
    for (int mt = 0; mt < 6; mt++) {
        bshort8 a[4];
#pragma unroll
        for (int ks = 0; ks < 4; ks++)
            a[ks] = *(const bshort8*)(Xb + (mt * 16 + l15) * 128 + ks * 32 + quad * 8);
#pragma unroll
        for (int which = 0; which < 2; which++) {
            int nt8 = w + which * 4;
            int n0g = 128 + nt8 * 16;
            f32x4 acc = zero4;
#pragma unroll
            for (int ks = 0; ks < 4; ks++) {
                bshort8 bfr = *(const bshort8*)(wt + (n0g + l15) * 128 + ks * 32 + quad * 8);
                acc = __builtin_amdgcn_mfma_f32_16x16x32_bf16(a[ks], bfr, acc, 0, 0, 0);
            }
            float bias = gqkv_b[n0g + l15];
#pragma unroll
            for (int r = 0; r < 4; r++)
                Ks2[(mt * 16 + quad * 4 + r) * 136 + nt8 * 16 + l15] = f2bf(acc[r] + bias);
        }
    }
    // Vt tiles (V computed transposed): mtv in {2w, 2w+1}, ntv 0..5
    for (int which = 0; which < 2; which++) {
        int mtv = 2 * w + which;
        bshort8 a[4];
#pragma unroll
        for (int ks = 0; ks < 4; ks++)
            a[ks] = *(const bshort8*)(wt + (256 + mtv * 16 + l15) * 128 + ks * 32 + quad * 8);
        float biasr[4];
#pragma unroll
        for (int r = 0; r < 4; r++) biasr[r] = gqkv_b[256 + mtv * 16 + quad * 4 + r];
        for (int ntv = 0; ntv < 6; ntv++) {
            f32x4 acc = zero4;
#pragma unroll
            for (int ks = 0; ks < 4; ks++) {
                bshort8 bfr = *(const bshort8*)(Xb + (ntv * 16 + l15) * 128 + ks * 32 + quad * 8);
                acc = __builtin_amdgcn_mfma_f32_16x16x32_bf16(a[ks], bfr, acc, 0, 0, 0);
            }
#pragma unroll
            for (int r = 0; r < 4; r++)
                Vts[(mtv * 16 + quad * 4 + r) * 104 + ntv * 16 + l15] = f2bf(acc[r] + biasr[r]);
        }
    }
    __syncthreads();

    // ---- attention phase: wave w -> heads 2w, 2w+1 ----
    unsigned short* Pw = &Ps[w][0];
    bshort8 zfrag = {0, 0, 0, 0, 0, 0, 0, 0};
#pragma unroll
    for (int hh2 = 0; hh2 < 2; hh2++) {
        int h = 2 * w + hh2;
        for (int mt = 0; mt < 4; mt++) {
            bshort8 aq = zfrag;
            if (quad < 2)
                aq = *(const bshort8*)(Qs + (mt * 16 + l15) * 136 + h * 16 + quad * 8);
            float rsum[4] = {0.f, 0.f, 0.f, 0.f};
            f32x4 oacc = zero4;
#pragma unroll
            for (int kc = 0; kc < 96; kc += 32) {
#pragma unroll
                for (int sub = 0; sub < 2; sub++) {
                    int nt = (kc >> 4) + sub;
                    bshort8 bk = zfrag;
                    if (quad < 2)
                        bk = *(const bshort8*)(Ks2 + (nt * 16 + l15) * 136 + h * 16 + quad * 8);
                    f32x4 s = __builtin_amdgcn_mfma_f32_16x16x32_bf16(aq, bk, zero4, 0, 0, 0);
#pragma unroll
                    for (int r = 0; r < 4; r++) {
                        float p = __expf(s[r]);
                        rsum[r] += p;
                        Pw[(quad * 4 + r) * 40 + sub * 16 + l15] = f2bf(p);
                    }
                }
                bshort8 ap = *(const bshort8*)(Pw + l15 * 40 + quad * 8);
                bshort8 bv = *(const bshort8*)(Vts + (h * 16 + l15) * 104 + kc + quad * 8);
                oacc = __builtin_amdgcn_mfma_f32_16x16x32_bf16(ap, bv, oacc, 0, 0, 0);
            }
#pragma unroll
            for (int r = 0; r < 4; r++) {
                float v = rsum[r];
                v += __shfl_xor(v, 1); v += __shfl_xor(v, 2);
                v += __shfl_xor(v, 4); v += __shfl_xor(v, 8);
                rsum[r] = v;
            }
#pragma unroll
            for (int r = 0; r < 4; r++)
                aout[((size_t)wn * W3L + mt * 16 + quad * 4 + r) * 128 + h * 16 + l15]
                    = oacc[r] / rsum[r];
        }
    }
}

// ---------------- K7: wo projection + shortcut (T=8) ----------------
__global__ __launch_bounds__(256) void k_wo2(const float* __restrict__ aout,
        const float* __restrict__ wo_w, const float* __restrict__ wo_b,
        const float* __restrict__ x_in, float* __restrict__ lpre) {
    int blk = blockIdx.x; int wn = blk >> 3; int g8 = blk & 7;
    int b = wn >> 8; int n = wn & 255;
    int t = threadIdx.x;
    __shared__ float as[8][128];
    {
        int j = t >> 5, c4 = (t & 31) << 2;
        *(float4*)&as[j][c4] = *(const float4*)(aout + ((size_t)wn * W3L + g8 * 8 + j) * 128 + c4);
    }
    __syncthreads();
    int c = t & 127, g = t >> 7;
    float acc[4];
    float bias = wo_b[c];
#pragma unroll
    for (int jj = 0; jj < 4; jj++) acc[jj] = bias;
    for (int k = 0; k < 128; k++) {
        float w = wo_w[k * 128 + c];
#pragma unroll
        for (int jj = 0; jj < 4; jj++) acc[jj] = fmaf(as[g * 4 + jj][k], w, acc[jj]);
    }
    int i1 = n >> 6, i2 = (n >> 3) & 7, i3 = n & 7;
    int s0 = g8 * 8 + g * 4;
    int dsl = s0 >> 4, dh = (s0 >> 2) & 3;
    int s = i1 * 4 + dsl, hh = i2 * 4 + dh, ww0 = i3 * 4;
    float4 sc4 = *(const float4*)(x_in + (((size_t)(b * 128 + c) * SS + s)) * 1024 + hh * 32 + ww0);
    float ov[4] = { acc[0] + sc4.x, acc[1] + sc4.y, acc[2] + sc4.z, acc[3] + sc4.w };
    size_t obase = ((((size_t)(b * SS + s)) * HH_ + hh) * WW_ + ww0) * 128 + c;
#pragma unroll
    for (int jj = 0; jj < 4; jj++) lpre[obase + (size_t)jj * 128] = ov[jj];
}

// ---------------- K8: LN + MLP2 + residual, transposed out (T=8) ----------------
__global__ __launch_bounds__(256) void k_mlp22(const float* __restrict__ lpre,
        const float* __restrict__ ln_g, const float* __restrict__ ln_b,
        const float* __restrict__ w1, const float* __restrict__ b1,
        const float* __restrict__ w2, const float* __restrict__ b2,
        float* __restrict__ lout) {
    int blk = blockIdx.x;
    int b = blk >> 11; int sp0 = (blk & 2047) * 8;
    int t = threadIdx.x;
    __shared__ float xs[8][128];
    __shared__ float h[8][128];
    __shared__ float h1[8][512];
    int j = t >> 5, c4 = (t & 31) * 4;
    float4 v = *(const float4*)(lpre + ((size_t)(b * NSP) + sp0 + j) * 128 + c4);
    *(float4*)&xs[j][c4] = v;
    float s1 = shfl_sum32(v.x + v.y + v.z + v.w);
    float mu = s1 * (1.0f / 128.0f);
    float d0 = v.x - mu, d1 = v.y - mu, d2 = v.z - mu, d3 = v.w - mu;
    float s2 = shfl_sum32(d0 * d0 + d1 * d1 + d2 * d2 + d3 * d3);
    float rs = rsqrtf(s2 * (1.0f / 128.0f) + LN_EPS);
    float4 g4 = *(const float4*)(ln_g + c4);
    float4 b4 = *(const float4*)(ln_b + c4);
    float4 hn = { d0 * rs * g4.x + b4.x, d1 * rs * g4.y + b4.y,
                  d2 * rs * g4.z + b4.z, d3 * rs * g4.w + b4.w };
    *(float4*)&h[j][c4] = hn;
    __syncthreads();
    {
        float acc0[8], acc1[8];
        float bi0 = b1[t], bi1 = b1[t + 256];
#pragma unroll
        for (int jj = 0; jj < 8; jj++) { acc0[jj] = bi0; acc1[jj] = bi1; }
        for (int k = 0; k < 128; k++) {
            float wa = w1[k * 512 + t];
            float wb = w1[k * 512 + t + 256];
#pragma unroll
            for (int jj = 0; jj < 8; jj++) {
                float hv = h[jj][k];
                acc0[jj] = fmaf(hv, wa, acc0[jj]);
                acc1[jj] = fmaf(hv, wb, acc1[jj]);
            }
        }
#pragma unroll
        for (int jj = 0; jj < 8; jj++) {
            h1[jj][t] = gelu_exact(acc0[jj]);
            h1[jj][t + 256] = gelu_exact(acc1[jj]);
        }
    }
    __syncthreads();
    int c = t & 127, g = t >> 7;
    {
        float acc[4];
        float bias = b2[c];
#pragma unroll
        for (int jj = 0; jj < 4; jj++) acc[jj] = bias;
        for (int k = 0; k < 512; k++) {
            float w = w2[k * 128 + c];
#pragma unroll
            for (int jj = 0; jj < 4; jj++) acc[jj] = fmaf(h1[g * 4 + jj][k], w, acc[jj]);
        }
#pragma unroll
        for (int jj = 0; jj < 4; jj++) h[g * 4 + jj][c] = xs[g * 4 + jj][c] + acc[jj];
    }
    __syncthreads();
    {
        int cw = t >> 1, hf = t & 1, j0 = hf * 4;
        float4 ov = { h[j0 + 0][cw], h[j0 + 1][cw], h[j0 + 2][cw], h[j0 + 3][cw] };
        *(float4*)(lout + ((size_t)(b * 128 + cw)) * NSP + sp0 + j0) = ov;
    }
}

extern "C" void kernel_launch(void* const* d_in, const int* in_sizes, int n_in,
                              void* d_out, int out_size, void* d_ws, size_t ws_size,
                              hipStream_t stream) {
    const float* x_in   = (const float*)d_in[0];
    const float* xg_in  = (const float*)d_in[1];
    const float* qkv_w  = (const float*)d_in[2];
    const float* qkv_b  = (const float*)d_in[3];
    const float* proj_w = (const float*)d_in[4];
    const float* proj_b = (const float*)d_in[5];
    const float* ln_g   = (const float*)d_in[6];
    const float* ln_b   = (const float*)d_in[7];
    const float* mlp_w1 = (const float*)d_in[8];
    const float* mlp_b1 = (const float*)d_in[9];
    const float* mlp_w2 = (const float*)d_in[10];
    const float* mlp_b2 = (const float*)d_in[11];
    const float* rq_w   = (const float*)d_in[12];
    const float* rq_b   = (const float*)d_in[13];
    const float* rk_w   = (const float*)d_in[14];
    const float* rk_b   = (const float*)d_in[15];
    const float* gqkv_w = (const float*)d_in[16];
    const float* gqkv_b = (const float*)d_in[17];
    const float* wo_w   = (const float*)d_in[18];
    const float* wo_b   = (const float*)d_in[19];
    const float* m2_w1  = (const float*)d_in[20];
    const float* m2_b1  = (const float*)d_in[21];
    const float* m2_w2  = (const float*)d_in[22];
    const float* m2_b2  = (const float*)d_in[23];

    float* out = (float*)d_out;
    float* ws  = (float*)d_ws;

    float* xg4 = ws;                                         // 524288
    float* xg  = ws + 524288;                                // 524288
    unsigned short* qgb  = (unsigned short*)(ws + 1048576);  // 524288 bf16
    unsigned short* kgb  = (unsigned short*)(ws + 1310720);  // 524288 bf16
    unsigned short* vgtb = (unsigned short*)(ws + 1572864);  // 524288 bf16 (V^T)
    float* og  = ws + 1835008;                               // 524288
    float* qh  = ws + 2359296;                               // 65536
    float* kh  = ws + 2424832;                               // 65536
    int*   tidx = (int*)(ws + 2490368);                      // 2048
    unsigned short* lnsc = (unsigned short*)(ws + 2492416);  // 6291456 bf16
    float* aout = ws + 2492416 + 3145728;                    // 4194304
    float* lpre = ws + 9832448;                              // 4194304
    unsigned short* wt   = (unsigned short*)(ws + 14026752); // 49152 bf16 (gqkv_w^T)

    const size_t L_OUT = (size_t)BATCH * CDIM * NSP;
    float* gout = out + L_OUT;

    hipLaunchKernelGGL(k_wtrans, dim3(192), dim3(256), 0, stream, gqkv_w, wt);
    hipLaunchKernelGGL(k_gqkv2, dim3(512), dim3(256), 0, stream,
                       xg_in, qkv_w, qkv_b, ln_g, ln_b, xg, qgb, kgb, vgtb);
    hipLaunchKernelGGL(k_gattn_mfma, dim3(2048), dim3(256), 0, stream, qgb, kgb, vgtb, og);
    hipLaunchKernelGGL(k_gmlp2, dim3(512), dim3(256), 0, stream,
                       og, xg, proj_w, proj_b, ln_g, ln_b, mlp_w1, mlp_b1, mlp_w2, mlp_b2,
                       xg4, gout);
    hipLaunchKernelGGL(k_routing_qk, dim3(512), dim3(128), 0, stream,
                       xg4, rq_w, rq_b, rk_w, rk_b, qh, kh);
    hipLaunchKernelGGL(k_topk, dim3(512), dim3(256), 0, stream, qh, kh, tidx);
    hipLaunchKernelGGL(k_lnsc_local, dim3(2048), dim3(256), 0, stream,
                       x_in, ln_g, ln_b, lnsc);
    hipLaunchKernelGGL(k_lnsc_gath, dim3(2048), dim3(256), 0, stream,
                       xg4, tidx, ln_g, ln_b, lnsc);
    hipLaunchKernelGGL(k_local_mfma, dim3(512), dim3(256), 0, stream,
                       lnsc, wt, gqkv_b, aout);
    hipLaunchKernelGGL(k_wo2, dim3(4096), dim3(256), 0, stream,
                       aout, wo_w, wo_b, x_in, lpre);
    hipLaunchKernelGGL(k_mlp22, dim3(4096), dim3(256), 0, stream,
                       lpre, ln_g, ln_b, m2_w1, m2_b1, m2_w2, m2_b2, out);
}

// Round 5
// 351.750 us; speedup vs baseline: 7.3354x; 1.3388x over previous
//
#include <hip/hip_runtime.h>
#include <hip/hip_bf16.h>
#include <math.h>

#define BATCH 2
#define CDIM 128
#define SS 16
#define HH_ 32
#define WW_ 32
#define NSP (SS*HH_*WW_)
#define GS 8
#define GH 16
#define GW 16
#define GN (GS*GH*GW)
#define HEADS 8
#define DH 16
#define NW 256
#define W3L 64
#define W3G 8
#define TOPK 4
#define W3 (W3L + TOPK*W3G)
#define LN_EPS 1e-6f
#define ROUTE_SCALE 0.08838834764831845f
#define GATTN_SCALE 0.25f

typedef short bshort8 __attribute__((ext_vector_type(8)));
typedef float f32x4 __attribute__((ext_vector_type(4)));

__device__ __forceinline__ unsigned short f2bf(float f) {
    unsigned int u = __float_as_uint(f);
    unsigned int r = (u + 0x7fffu + ((u >> 16) & 1u)) >> 16;
    return (unsigned short)r;
}
__device__ __forceinline__ float bf2f_lo(unsigned int u) { return __uint_as_float(u << 16); }
__device__ __forceinline__ float bf2f_hi(unsigned int u) { return __uint_as_float(u & 0xffff0000u); }

__device__ __forceinline__ float gelu_exact(float x) {
    return 0.5f * x * (1.0f + erff(x * 0.70710678118654752f));
}

__device__ __forceinline__ float shfl_sum32(float v) {
#pragma unroll
    for (int m = 16; m > 0; m >>= 1) v += __shfl_xor(v, m);
    return v;
}
__device__ __forceinline__ float shfl_sum16(float v) {
#pragma unroll
    for (int m = 8; m > 0; m >>= 1) v += __shfl_xor(v, m);
    return v;
}
__device__ __forceinline__ float shfl_sum8(float v) {
#pragma unroll
    for (int m = 4; m > 0; m >>= 1) v += __shfl_xor(v, m);
    return v;
}

// ---------------- K0a: transpose gqkv_w -> bf16 W^T[384][128], scale folded for Q ----------------
__global__ __launch_bounds__(256) void k_wtrans(const float* __restrict__ gqkv_w,
                                                unsigned short* __restrict__ wt) {
    int id = blockIdx.x * 256 + threadIdx.x;   // 0..49151
    int n = id >> 7, k = id & 127;
    float v = gqkv_w[k * 384 + n];
    if (n < 128) v *= ROUTE_SCALE;
    wt[id] = f2bf(v);
}

// ---------------- K0b: mlp2 weights -> bf16 transposed ----------------
// w1 [128][512] -> w1t [512][128];  w2 [512][128] -> w2t [128][512]
__global__ __launch_bounds__(256) void k_wprep_mlp2(const float* __restrict__ w1,
        const float* __restrict__ w2, unsigned short* __restrict__ w1t,
        unsigned short* __restrict__ w2t) {
    int id = blockIdx.x * 256 + threadIdx.x;   // 0..131071
    if (id < 65536) {
        int n = id >> 7, k = id & 127;
        w1t[id] = f2bf(w1[k * 512 + n]);
    } else {
        int id2 = id - 65536;
        int n = id2 >> 9, k = id2 & 511;
        w2t[id2] = f2bf(w2[k * 128 + n]);
    }
}

// ---------------- K1: global branch qkv (T=8 tokens/block), bf16 q/k/v^T out ----------------
__global__ __launch_bounds__(256) void k_gqkv2(const float* __restrict__ xg_in,
        const float* __restrict__ qkv_w, const float* __restrict__ qkv_b,
        const float* __restrict__ ln_g, const float* __restrict__ ln_b,
        float* __restrict__ xg, unsigned short* __restrict__ qgb,
        unsigned short* __restrict__ kgb, unsigned short* __restrict__ vgtb) {
    int blk = blockIdx.x; int b = blk >> 8; int n0 = (blk & 255) * 8;
    int t = threadIdx.x;
    __shared__ float xs[8][128];
    __shared__ float h[8][128];
    {
        int c = t >> 1, q4 = (t & 1) * 4;
        float4 v = *(const float4*)(xg_in + ((size_t)(b * 128 + c)) * GN + n0 + q4);
        xs[q4 + 0][c] = v.x; xs[q4 + 1][c] = v.y; xs[q4 + 2][c] = v.z; xs[q4 + 3][c] = v.w;
    }
    __syncthreads();
    int j = t >> 5, c4 = (t & 31) * 4;
    float4 v = *(float4*)&xs[j][c4];
    *(float4*)(xg + ((size_t)(b * GN) + n0 + j) * 128 + c4) = v;
    float s1 = shfl_sum32(v.x + v.y + v.z + v.w);
    float mu = s1 * (1.0f / 128.0f);
    float d0 = v.x - mu, d1 = v.y - mu, d2 = v.z - mu, d3 = v.w - mu;
    float s2 = shfl_sum32(d0 * d0 + d1 * d1 + d2 * d2 + d3 * d3);
    float rs = rsqrtf(s2 * (1.0f / 128.0f) + LN_EPS);
    float4 g4 = *(const float4*)(ln_g + c4);
    float4 b4 = *(const float4*)(ln_b + c4);
    float4 hn = { d0 * rs * g4.x + b4.x, d1 * rs * g4.y + b4.y,
                  d2 * rs * g4.z + b4.z, d3 * rs * g4.w + b4.w };
    *(float4*)&h[j][c4] = hn;
    __syncthreads();
    for (int c = t; c < 384; c += 256) {
        float acc[8];
        float bias = qkv_b[c];
#pragma unroll
        for (int jj = 0; jj < 8; jj++) acc[jj] = bias;
        for (int k = 0; k < 128; k++) {
            float w = qkv_w[k * 384 + c];
#pragma unroll
            for (int jj = 0; jj < 8; jj++) acc[jj] = fmaf(h[jj][k], w, acc[jj]);
        }
        int part = c >> 7, head = (c >> 4) & 7, d = c & 15;
        int bh = b * HEADS + head;
        if (part == 0) {
#pragma unroll
            for (int jj = 0; jj < 8; jj++)
                qgb[((size_t)bh * GN + n0 + jj) * DH + d] = f2bf(acc[jj] * GATTN_SCALE);
        } else if (part == 1) {
#pragma unroll
            for (int jj = 0; jj < 8; jj++)
                kgb[((size_t)bh * GN + n0 + jj) * DH + d] = f2bf(acc[jj]);
        } else {
            ushort4 u0, u1;
            u0.x = f2bf(acc[0]); u0.y = f2bf(acc[1]); u0.z = f2bf(acc[2]); u0.w = f2bf(acc[3]);
            u1.x = f2bf(acc[4]); u1.y = f2bf(acc[5]); u1.z = f2bf(acc[6]); u1.w = f2bf(acc[7]);
            unsigned short* dst = vgtb + ((size_t)bh * DH + d) * GN + n0;
            *(ushort4*)dst = u0; *(ushort4*)(dst + 4) = u1;
        }
    }
}

// ---------------- K2: global attention via MFMA bf16 ----------------
__global__ __launch_bounds__(256) void k_gattn_mfma(const unsigned short* __restrict__ qgb,
        const unsigned short* __restrict__ kgb, const unsigned short* __restrict__ vgtb,
        float* __restrict__ og) {
    int blk = blockIdx.x;
    int bh = blk >> 7; int qt = (blk & 127) << 4;
    int b = bh >> 3, hh = bh & 7;
    int t = threadIdx.x; int w = t >> 6; int lane = t & 63;
    int col = lane & 15, quad = lane >> 4;
    __shared__ __align__(16) unsigned short Pbuf[4 * 16 * 40];
    __shared__ float po[4][64][4];
    __shared__ float pl[4][64][4];

    bshort8 aq = {0, 0, 0, 0, 0, 0, 0, 0};
    if (quad < 2)
        aq = *(const bshort8*)(qgb + ((size_t)bh * GN + qt + col) * DH + quad * 8);

    f32x4 o = {0.f, 0.f, 0.f, 0.f};
    float lsum[4] = {0.f, 0.f, 0.f, 0.f};
    const unsigned short* kb = kgb + (size_t)bh * GN * DH;
    const unsigned short* vb = vgtb + (size_t)bh * DH * GN;
    unsigned short* pb = Pbuf + w * (16 * 40);
    int row0 = quad * 4;
    int kbeg = w * 512;
    for (int kc = kbeg; kc < kbeg + 512; kc += 32) {
        bshort8 bk0 = {0, 0, 0, 0, 0, 0, 0, 0};
        bshort8 bk1 = {0, 0, 0, 0, 0, 0, 0, 0};
        if (quad < 2) {
            bk0 = *(const bshort8*)(kb + (size_t)(kc + col) * DH + quad * 8);
            bk1 = *(const bshort8*)(kb + (size_t)(kc + 16 + col) * DH + quad * 8);
        }
        f32x4 z = {0.f, 0.f, 0.f, 0.f};
        f32x4 s0 = __builtin_amdgcn_mfma_f32_16x16x32_bf16(aq, bk0, z, 0, 0, 0);
        f32x4 s1 = __builtin_amdgcn_mfma_f32_16x16x32_bf16(aq, bk1, z, 0, 0, 0);
        float p0[4], p1[4];
#pragma unroll
        for (int r = 0; r < 4; r++) {
            p0[r] = __expf(s0[r]); p1[r] = __expf(s1[r]);
            lsum[r] += p0[r] + p1[r];
        }
#pragma unroll
        for (int r = 0; r < 4; r++) {
            pb[(row0 + r) * 40 + col] = f2bf(p0[r]);
            pb[(row0 + r) * 40 + 16 + col] = f2bf(p1[r]);
        }
        bshort8 pA = *(const bshort8*)(pb + col * 40 + quad * 8);
        bshort8 bv = *(const bshort8*)(vb + (size_t)col * GN + kc + quad * 8);
        o = __builtin_amdgcn_mfma_f32_16x16x32_bf16(pA, bv, o, 0, 0, 0);
    }
#pragma unroll
    for (int r = 0; r < 4; r++) {
        float v = lsum[r];
        v += __shfl_xor(v, 1); v += __shfl_xor(v, 2);
        v += __shfl_xor(v, 4); v += __shfl_xor(v, 8);
        lsum[r] = v;
    }
#pragma unroll
    for (int r = 0; r < 4; r++) { po[w][lane][r] = o[r]; pl[w][lane][r] = lsum[r]; }
    __syncthreads();
    if (w == 0) {
#pragma unroll
        for (int r = 0; r < 4; r++) {
            float os = po[0][lane][r] + po[1][lane][r] + po[2][lane][r] + po[3][lane][r];
            float ls = pl[0][lane][r] + pl[1][lane][r] + pl[2][lane][r] + pl[3][lane][r];
            og[((size_t)(b * GN) + qt + quad * 4 + r) * 128 + hh * 16 + col] = os / ls;
        }
    }
}

// ---------------- K3: global proj+residual+LN+MLP (T=8) ----------------
__global__ __launch_bounds__(256) void k_gmlp2(const float* __restrict__ og,
        const float* __restrict__ xg,
        const float* __restrict__ proj_w, const float* __restrict__ proj_b,
        const float* __restrict__ ln_g, const float* __restrict__ ln_b,
        const float* __restrict__ w1, const float* __restrict__ b1,
        const float* __restrict__ w2, const float* __restrict__ b2,
        float* __restrict__ xg4, float* __restrict__ gout) {
    int blk = blockIdx.x; int b = blk >> 8; int n0 = (blk & 255) * 8;
    int t = threadIdx.x;
    __shared__ float xs[8][128];
    __shared__ float h[8][128];
    __shared__ float h1[8][512];
    int j = t >> 5, c4 = (t & 31) * 4;
    size_t rbase = ((size_t)(b * GN) + n0 + j) * 128 + c4;
    *(float4*)&h[j][c4] = *(const float4*)(og + rbase);
    *(float4*)&xs[j][c4] = *(const float4*)(xg + rbase);
    __syncthreads();
    int c = t & 127, g = t >> 7;
    {
        float acc[4];
        float bias = proj_b[c];
#pragma unroll
        for (int jj = 0; jj < 4; jj++) acc[jj] = bias;
        for (int k = 0; k < 128; k++) {
            float w = proj_w[k * 128 + c];
#pragma unroll
            for (int jj = 0; jj < 4; jj++) acc[jj] = fmaf(h[g * 4 + jj][k], w, acc[jj]);
        }
#pragma unroll
        for (int jj = 0; jj < 4; jj++) xs[g * 4 + jj][c] += acc[jj];
    }
    __syncthreads();
    {
        float4 v = *(float4*)&xs[j][c4];
        float s1 = shfl_sum32(v.x + v.y + v.z + v.w);
        float mu = s1 * (1.0f / 128.0f);
        float d0 = v.x - mu, d1 = v.y - mu, d2 = v.z - mu, d3 = v.w - mu;
        float s2 = shfl_sum32(d0 * d0 + d1 * d1 + d2 * d2 + d3 * d3);
        float rs = rsqrtf(s2 * (1.0f / 128.0f) + LN_EPS);
        float4 g4 = *(const float4*)(ln_g + c4);
        float4 b4 = *(const float4*)(ln_b + c4);
        float4 hn = { d0 * rs * g4.x + b4.x, d1 * rs * g4.y + b4.y,
                      d2 * rs * g4.z + b4.z, d3 * rs * g4.w + b4.w };
        *(float4*)&h[j][c4] = hn;
    }
    __syncthreads();
    {
        float acc0[8], acc1[8];
        float bi0 = b1[t], bi1 = b1[t + 256];
#pragma unroll
        for (int jj = 0; jj < 8; jj++) { acc0[jj] = bi0; acc1[jj] = bi1; }
        for (int k = 0; k < 128; k++) {
            float wa = w1[k * 512 + t];
            float wb = w1[k * 512 + t + 256];
#pragma unroll
            for (int jj = 0; jj < 8; jj++) {
                float hv = h[jj][k];
                acc0[jj] = fmaf(hv, wa, acc0[jj]);
                acc1[jj] = fmaf(hv, wb, acc1[jj]);
            }
        }
#pragma unroll
        for (int jj = 0; jj < 8; jj++) {
            h1[jj][t] = gelu_exact(acc0[jj]);
            h1[jj][t + 256] = gelu_exact(acc1[jj]);
        }
    }
    __syncthreads();
    {
        float acc[4];
        float bias = b2[c];
#pragma unroll
        for (int jj = 0; jj < 4; jj++) acc[jj] = bias;
        for (int k = 0; k < 512; k++) {
            float w = w2[k * 128 + c];
#pragma unroll
            for (int jj = 0; jj < 4; jj++) acc[jj] = fmaf(h1[g * 4 + jj][k], w, acc[jj]);
        }
#pragma unroll
        for (int jj = 0; jj < 4; jj++) {
            float ov = xs[g * 4 + jj][c] + acc[jj];
            xg4[((size_t)(b * GN) + n0 + g * 4 + jj) * 128 + c] = ov;
            h[g * 4 + jj][c] = ov;
        }
    }
    __syncthreads();
    {
        int cw = t >> 1, hf = t & 1, j0 = hf * 4;
        float4 ov = { h[j0 + 0][cw], h[j0 + 1][cw], h[j0 + 2][cw], h[j0 + 3][cw] };
        *(float4*)(gout + ((size_t)(b * 128 + cw)) * GN + n0 + j0) = ov;
    }
}

// ---------------- K4a: routing q/k ----------------
__global__ void k_routing_qk(const float* __restrict__ xg4,
                             const float* __restrict__ rq_w, const float* __restrict__ rq_b,
                             const float* __restrict__ rk_w, const float* __restrict__ rk_b,
                             float* __restrict__ qh, float* __restrict__ kh) {
    int wid = blockIdx.x; int b = wid / NW, n = wid % NW;
    int c = threadIdx.x;
    int i1 = n / 64, i2 = (n / 8) % 8, i3 = n % 8;
    __shared__ float g[CDIM];
    float s = 0.f;
#pragma unroll
    for (int j = 0; j < W3G; j++) {
        int ds = j >> 2, dh = (j >> 1) & 1, dw = j & 1;
        int gi = ((i1 * 2 + ds) * GH + (i2 * 2 + dh)) * GW + (i3 * 2 + dw);
        s += xg4[((size_t)(b * GN + gi)) * CDIM + c];
    }
    g[c] = s * (1.0f / W3G);
    __syncthreads();
    float aq = rq_b[c], ak = rk_b[c];
    for (int k = 0; k < CDIM; k++) { float gv = g[k]; aq = fmaf(gv, rq_w[k * CDIM + c], aq); ak = fmaf(gv, rk_w[k * CDIM + c], ak); }
    qh[(size_t)wid * CDIM + c] = aq;
    kh[(size_t)wid * CDIM + c] = ak;
}

// ---------------- K4b: top-k ----------------
__global__ void k_topk(const float* __restrict__ qh, const float* __restrict__ kh,
                       int* __restrict__ tidx) {
    int wid = blockIdx.x; int b = wid / NW;
    int m = threadIdx.x;
    __shared__ float q[CDIM];
    __shared__ float lv[NW];
    __shared__ int li[NW];
    if (m < CDIM) q[m] = qh[(size_t)wid * CDIM + m] * ROUTE_SCALE;
    __syncthreads();
    float acc = 0.f;
    const float* kr = kh + ((size_t)b * NW + m) * CDIM;
    for (int k = 0; k < CDIM; k++) acc = fmaf(q[k], kr[k], acc);
#pragma unroll
    for (int sel = 0; sel < TOPK; sel++) {
        lv[m] = acc; li[m] = m; __syncthreads();
#pragma unroll
        for (int s = 128; s > 0; s >>= 1) {
            if (m < s) {
                if (lv[m + s] > lv[m] || (lv[m + s] == lv[m] && li[m + s] < li[m])) {
                    lv[m] = lv[m + s]; li[m] = li[m + s];
                }
            }
            __syncthreads();
        }
        int best = li[0]; __syncthreads();
        if (m == best) acc = -1e30f;
        if (m == 0) tidx[wid * TOPK + sel] = best;
    }
}

// ---------------- K5a: LN local tokens -> lnsc bf16 ----------------
__global__ __launch_bounds__(256) void k_lnsc_local(const float* __restrict__ x_in,
        const float* __restrict__ ln_g, const float* __restrict__ ln_b,
        unsigned short* __restrict__ lnsc) {
    int blk = blockIdx.x;
    int wt = blk & 1; int hh = (blk >> 1) & 31; int s = (blk >> 6) & 15; int b = blk >> 10;
    int w0 = wt * 16;
    int t = threadIdx.x;
    __shared__ float tile[16][132];
    {
        int c = t >> 1; int wq = (t & 1) * 8;
        const float* src = x_in + (((size_t)(b * 128 + c) * SS + s)) * 1024 + hh * 32 + w0 + wq;
        float4 v0 = *(const float4*)src;
        float4 v1 = *(const float4*)(src + 4);
        tile[wq + 0][c] = v0.x; tile[wq + 1][c] = v0.y; tile[wq + 2][c] = v0.z; tile[wq + 3][c] = v0.w;
        tile[wq + 4][c] = v1.x; tile[wq + 5][c] = v1.y; tile[wq + 6][c] = v1.z; tile[wq + 7][c] = v1.w;
    }
    __syncthreads();
    int w = t >> 4; int j = t & 15;
    float vals[8];
    float s1 = 0.f;
#pragma unroll
    for (int i = 0; i < 8; i++) { vals[i] = tile[w][j * 8 + i]; s1 += vals[i]; }
    s1 = shfl_sum16(s1);
    float mu = s1 * (1.0f / 128.0f);
    float s2 = 0.f;
#pragma unroll
    for (int i = 0; i < 8; i++) { float d = vals[i] - mu; s2 += d * d; }
    s2 = shfl_sum16(s2);
    float rs = rsqrtf(s2 * (1.0f / 128.0f) + LN_EPS);
    float4 g0 = *(const float4*)(ln_g + j * 8);
    float4 g1 = *(const float4*)(ln_g + j * 8 + 4);
    float4 b0 = *(const float4*)(ln_b + j * 8);
    float4 b1 = *(const float4*)(ln_b + j * 8 + 4);
    float gv[8] = { g0.x, g0.y, g0.z, g0.w, g1.x, g1.y, g1.z, g1.w };
    float bv[8] = { b0.x, b0.y, b0.z, b0.w, b1.x, b1.y, b1.z, b1.w };
    int ww = w0 + w;
    int n = (s >> 2) * 64 + (hh >> 2) * 8 + (ww >> 2);
    int slot = (s & 3) * 16 + (hh & 3) * 4 + (ww & 3);
    unsigned short* dst = lnsc + ((size_t)(b * NW + n) * W3 + slot) * 128 + j * 8;
    ushort4 u0, u1;
    u0.x = f2bf((vals[0] - mu) * rs * gv[0] + bv[0]);
    u0.y = f2bf((vals[1] - mu) * rs * gv[1] + bv[1]);
    u0.z = f2bf((vals[2] - mu) * rs * gv[2] + bv[2]);
    u0.w = f2bf((vals[3] - mu) * rs * gv[3] + bv[3]);
    u1.x = f2bf((vals[4] - mu) * rs * gv[4] + bv[4]);
    u1.y = f2bf((vals[5] - mu) * rs * gv[5] + bv[5]);
    u1.z = f2bf((vals[6] - mu) * rs * gv[6] + bv[6]);
    u1.w = f2bf((vals[7] - mu) * rs * gv[7] + bv[7]);
    *(ushort4*)dst = u0;
    *(ushort4*)(dst + 4) = u1;
}

// ---------------- K5b: LN gathered global tokens -> lnsc bf16 ----------------
__global__ __launch_bounds__(256) void k_lnsc_gath(const float* __restrict__ xg4,
        const int* __restrict__ tidx,
        const float* __restrict__ ln_g, const float* __restrict__ ln_b,
        unsigned short* __restrict__ lnsc) {
    int blk = blockIdx.x;
    int kk = blk & 3; int wn = blk >> 2;
    int b = wn >> 8;
    int g = tidx[wn * TOPK + kk];
    int gi1 = g >> 6, gi2 = (g >> 3) & 7, gi3 = g & 7;
    int t = threadIdx.x; int j = t >> 5, lj = t & 31;
    int ds = j >> 2, dh = (j >> 1) & 1, dw = j & 1;
    int gi = ((gi1 * 2 + ds) * GH + (gi2 * 2 + dh)) * GW + (gi3 * 2 + dw);
    float4 v = *(const float4*)(xg4 + ((size_t)(b * GN + gi)) * 128 + lj * 4);
    float s1 = shfl_sum32(v.x + v.y + v.z + v.w);
    float mu = s1 * (1.0f / 128.0f);
    float d0 = v.x - mu, d1 = v.y - mu, d2 = v.z - mu, d3 = v.w - mu;
    float s2 = shfl_sum32(d0 * d0 + d1 * d1 + d2 * d2 + d3 * d3);
    float rs = rsqrtf(s2 * (1.0f / 128.0f) + LN_EPS);
    float4 g4 = *(const float4*)(ln_g + lj * 4);
    float4 b4 = *(const float4*)(ln_b + lj * 4);
    ushort4 u;
    u.x = f2bf(d0 * rs * g4.x + b4.x);
    u.y = f2bf(d1 * rs * g4.y + b4.y);
    u.z = f2bf(d2 * rs * g4.z + b4.z);
    u.w = f2bf(d3 * rs * g4.w + b4.w);
    *(ushort4*)(lnsc + ((size_t)wn * W3 + 64 + kk * 8 + j) * 128 + lj * 4) = u;
}

// ---------------- K6: local attention via MFMA ----------------
__global__ __launch_bounds__(256) void k_local_mfma(const unsigned short* __restrict__ lnsc,
        const unsigned short* __restrict__ wt, const float* __restrict__ gqkv_b,
        float* __restrict__ aout) {
    int wn = blockIdx.x;
    int t = threadIdx.x; int w = t >> 6; int lane = t & 63;
    int l15 = lane & 15, quad = lane >> 4;
    __shared__ __align__(16) unsigned short Qs[64 * 136];
    __shared__ __align__(16) unsigned short Ks2[96 * 136];
    __shared__ __align__(16) unsigned short Vts[128 * 104];
    __shared__ __align__(16) unsigned short Ps[4][16 * 40];

    const unsigned short* Xb = lnsc + (size_t)wn * W3 * 128;
    f32x4 zero4 = {0.f, 0.f, 0.f, 0.f};

    for (int mt = 0; mt < 4; mt++) {
        bshort8 a[4];
#pragma unroll
        for (int ks = 0; ks < 4; ks++)
            a[ks] = *(const bshort8*)(Xb + (mt * 16 + l15) * 128 + ks * 32 + quad * 8);
#pragma unroll
        for (int which = 0; which < 2; which++) {
            int n0 = (w + which * 4) * 16;
            f32x4 acc = zero4;
#pragma unroll
            for (int ks = 0; ks < 4; ks++) {
                bshort8 bfr = *(const bshort8*)(wt + (n0 + l15) * 128 + ks * 32 + quad * 8);
                acc = __builtin_amdgcn_mfma_f32_16x16x32_bf16(a[ks], bfr, acc, 0, 0, 0);
            }
            float bias = gqkv_b[n0 + l15] * ROUTE_SCALE;
#pragma unroll
            for (int r = 0; r < 4; r++)
                Qs[(mt * 16 + quad * 4 + r) * 136 + n0 + l15] = f2bf(acc[r] + bias);
        }
    }
    for (int mt = 0; mt < 6; mt++) {
        bshort8 a[4];
#pragma unroll
        for (int ks = 0; ks < 4; ks++)
            a[ks] = *(const bshort8*)(Xb + (mt * 16 + l15) * 128 + ks * 32 + quad * 8);
#pragma unroll
        for (int which = 0; which < 2; which++) {
            int nt8 = w + which * 4;
            int n0g = 128 + nt8 * 16;
            f32x4 acc = zero4;
#pragma unroll
            for (int ks = 0; ks < 4; ks++) {
                bshort8 bfr = *(const bshort8*)(wt + (n0g + l15) * 128 + ks * 32 + quad * 8);
                acc = __builtin_amdgcn_mfma_f32_16x16x32_bf16(a[ks], bfr, acc, 0, 0, 0);
            }
            float bias = gqkv_b[n0g + l15];
#pragma unroll
            for (int r = 0; r < 4; r++)
                Ks2[(mt * 16 + quad * 4 + r) * 136 + nt8 * 16 + l15] = f2bf(acc[r] + bias);
        }
    }
    for (int which = 0; which < 2; which++) {
        int mtv = 2 * w + which;
        bshort8 a[4];
#pragma unroll
        for (int ks = 0; ks < 4; ks++)
            a[ks] = *(const bshort8*)(wt + (256 + mtv * 16 + l15) * 128 + ks * 32 + quad * 8);
        float biasr[4];
#pragma unroll
        for (int r = 0; r < 4; r++) biasr[r] = gqkv_b[256 + mtv * 16 + quad * 4 + r];
        for (int ntv = 0; ntv < 6; ntv++) {
            f32x4 acc = zero4;
#pragma unroll
            for (int ks = 0; ks < 4; ks++) {
                bshort8 bfr = *(const bshort8*)(Xb + (ntv * 16 + l15) * 128 + ks * 32 + quad * 8);
                acc = __builtin_amdgcn_mfma_f32_16x16x32_bf16(a[ks], bfr, acc, 0, 0, 0);
            }
#pragma unroll
            for (int r = 0; r < 4; r++)
                Vts[(mtv * 16 + quad * 4 + r) * 104 + ntv * 16 + l15] = f2bf(acc[r] + biasr[r]);
        }
    }
    __syncthreads();

    unsigned short* Pw = &Ps[w][0];
    bshort8 zfrag = {0, 0, 0, 0, 0, 0, 0, 0};
#pragma unroll
    for (int hh2 = 0; hh2 < 2; hh2++) {
        int h = 2 * w + hh2;
        for (int mt = 0; mt < 4; mt++) {
            bshort8 aq = zfrag;
            if (quad < 2)
                aq = *(const bshort8*)(Qs + (mt * 16 + l15) * 136 + h * 16 + quad * 8);
            float rsum[4] = {0.f, 0.f, 0.f, 0.f};
            f32x4 oacc = zero4;
#pragma unroll
            for (int kc = 0; kc < 96; kc += 32) {
#pragma unroll
                for (int sub = 0; sub < 2; sub++) {
                    int nt = (kc >> 4) + sub;
                    bshort8 bk = zfrag;
                    if (quad < 2)
                        bk = *(const bshort8*)(Ks2 + (nt * 16 + l15) * 136 + h * 16 + quad * 8);
                    f32x4 s = __builtin_amdgcn_mfma_f32_16x16x32_bf16(aq, bk, zero4, 0, 0, 0);
#pragma unroll
                    for (int r = 0; r < 4; r++) {
                        float p = __expf(s[r]);
                        rsum[r] += p;
                        Pw[(quad * 4 + r) * 40 + sub * 16 + l15] = f2bf(p);
                    }
                }
                bshort8 ap = *(const bshort8*)(Pw + l15 * 40 + quad * 8);
                bshort8 bv = *(const bshort8*)(Vts + (h * 16 + l15) * 104 + kc + quad * 8);
                oacc = __builtin_amdgcn_mfma_f32_16x16x32_bf16(ap, bv, oacc, 0, 0, 0);
            }
#pragma unroll
            for (int r = 0; r < 4; r++) {
                float v = rsum[r];
                v += __shfl_xor(v, 1); v += __shfl_xor(v, 2);
                v += __shfl_xor(v, 4); v += __shfl_xor(v, 8);
                rsum[r] = v;
            }
#pragma unroll
            for (int r = 0; r < 4; r++)
                aout[((size_t)wn * W3L + mt * 16 + quad * 4 + r) * 128 + h * 16 + l15]
                    = oacc[r] / rsum[r];
        }
    }
}

// ---------------- K7: wo projection + shortcut (T=8) ----------------
__global__ __launch_bounds__(256) void k_wo2(const float* __restrict__ aout,
        const float* __restrict__ wo_w, const float* __restrict__ wo_b,
        const float* __restrict__ x_in, float* __restrict__ lpre) {
    int blk = blockIdx.x; int wn = blk >> 3; int g8 = blk & 7;
    int b = wn >> 8; int n = wn & 255;
    int t = threadIdx.x;
    __shared__ float as[8][128];
    {
        int j = t >> 5, c4 = (t & 31) << 2;
        *(float4*)&as[j][c4] = *(const float4*)(aout + ((size_t)wn * W3L + g8 * 8 + j) * 128 + c4);
    }
    __syncthreads();
    int c = t & 127, g = t >> 7;
    float acc[4];
    float bias = wo_b[c];
#pragma unroll
    for (int jj = 0; jj < 4; jj++) acc[jj] = bias;
    for (int k = 0; k < 128; k++) {
        float w = wo_w[k * 128 + c];
#pragma unroll
        for (int jj = 0; jj < 4; jj++) acc[jj] = fmaf(as[g * 4 + jj][k], w, acc[jj]);
    }
    int i1 = n >> 6, i2 = (n >> 3) & 7, i3 = n & 7;
    int s0 = g8 * 8 + g * 4;
    int dsl = s0 >> 4, dh = (s0 >> 2) & 3;
    int s = i1 * 4 + dsl, hh = i2 * 4 + dh, ww0 = i3 * 4;
    float4 sc4 = *(const float4*)(x_in + (((size_t)(b * 128 + c) * SS + s)) * 1024 + hh * 32 + ww0);
    float ov[4] = { acc[0] + sc4.x, acc[1] + sc4.y, acc[2] + sc4.z, acc[3] + sc4.w };
    size_t obase = ((((size_t)(b * SS + s)) * HH_ + hh) * WW_ + ww0) * 128 + c;
#pragma unroll
    for (int jj = 0; jj < 4; jj++) lpre[obase + (size_t)jj * 128] = ov[jj];
}

// ---------------- K8: LN + MLP2 via MFMA, 32 tokens/block ----------------
// LDS: xs[32][132] f32 (16896 B) + h[32][136] bf16 (8704 B) + h1[32][520] bf16 (33280 B)
__global__ __launch_bounds__(256) void k_mlp2_mfma(const float* __restrict__ lpre,
        const float* __restrict__ ln_g, const float* __restrict__ ln_b,
        const unsigned short* __restrict__ w1t, const float* __restrict__ b1,
        const unsigned short* __restrict__ w2t, const float* __restrict__ b2,
        float* __restrict__ lout) {
    int blk = blockIdx.x;
    int T0 = blk * 32;
    int b = T0 >> 14;          // / NSP
    int sp = T0 & 16383;       // % NSP
    int t = threadIdx.x; int w = t >> 6; int lane = t & 63;
    int l15 = lane & 15, quad = lane >> 4;
    __shared__ __align__(16) float xs[32 * 132];
    __shared__ __align__(16) unsigned short h[32 * 136];
    __shared__ __align__(16) unsigned short h1[32 * 520];
    float* of32 = (float*)h1;   // aliases h1 after GEMM2 (stride 132)

    // ---- phase 0: load + LN (8 threads per token row, 16 ch each) ----
    {
        int j = t >> 3, p = t & 7, c0 = p * 16;
        const float* src = lpre + ((size_t)T0 + j) * 128 + c0;
        float4 v0 = *(const float4*)(src + 0);
        float4 v1 = *(const float4*)(src + 4);
        float4 v2 = *(const float4*)(src + 8);
        float4 v3 = *(const float4*)(src + 12);
        float s1 = (v0.x + v0.y + v0.z + v0.w) + (v1.x + v1.y + v1.z + v1.w)
                 + (v2.x + v2.y + v2.z + v2.w) + (v3.x + v3.y + v3.z + v3.w);
        s1 = shfl_sum8(s1);
        float mu = s1 * (1.0f / 128.0f);
        float vv[16] = { v0.x, v0.y, v0.z, v0.w, v1.x, v1.y, v1.z, v1.w,
                         v2.x, v2.y, v2.z, v2.w, v3.x, v3.y, v3.z, v3.w };
        float s2 = 0.f;
#pragma unroll
        for (int i = 0; i < 16; i++) { float d = vv[i] - mu; s2 += d * d; }
        s2 = shfl_sum8(s2);
        float rs = rsqrtf(s2 * (1.0f / 128.0f) + LN_EPS);
        *(float4*)&xs[j * 132 + c0 + 0] = v0;
        *(float4*)&xs[j * 132 + c0 + 4] = v1;
        *(float4*)&xs[j * 132 + c0 + 8] = v2;
        *(float4*)&xs[j * 132 + c0 + 12] = v3;
        unsigned short hb[16];
#pragma unroll
        for (int i4 = 0; i4 < 4; i4++) {
            float4 g4 = *(const float4*)(ln_g + c0 + i4 * 4);
            float4 b4 = *(const float4*)(ln_b + c0 + i4 * 4);
            hb[i4 * 4 + 0] = f2bf((vv[i4 * 4 + 0] - mu) * rs * g4.x + b4.x);
            hb[i4 * 4 + 1] = f2bf((vv[i4 * 4 + 1] - mu) * rs * g4.y + b4.y);
            hb[i4 * 4 + 2] = f2bf((vv[i4 * 4 + 2] - mu) * rs * g4.z + b4.z);
            hb[i4 * 4 + 3] = f2bf((vv[i4 * 4 + 3] - mu) * rs * g4.w + b4.w);
        }
        *(ushort4*)&h[j * 136 + c0 + 0] = *(ushort4*)&hb[0];
        *(ushort4*)&h[j * 136 + c0 + 4] = *(ushort4*)&hb[4];
        *(ushort4*)&h[j * 136 + c0 + 8] = *(ushort4*)&hb[8];
        *(ushort4*)&h[j * 136 + c0 + 12] = *(ushort4*)&hb[12];
    }
    __syncthreads();

    // ---- GEMM1: h[32x128] @ w1t^T -> gelu -> h1[32x512]; wave w owns n in [w*128, w*128+128) ----
    f32x4 zero4 = {0.f, 0.f, 0.f, 0.f};
    {
        bshort8 a[2][4];
#pragma unroll
        for (int mt = 0; mt < 2; mt++)
#pragma unroll
            for (int ks = 0; ks < 4; ks++)
                a[mt][ks] = *(const bshort8*)(h + (mt * 16 + l15) * 136 + ks * 32 + quad * 8);
        int n0w = w * 128;
#pragma unroll
        for (int nt = 0; nt < 8; nt++) {
            int n0 = n0w + nt * 16;
            f32x4 acc0 = zero4, acc1 = zero4;
#pragma unroll
            for (int ks = 0; ks < 4; ks++) {
                bshort8 bfr = *(const bshort8*)(w1t + (size_t)(n0 + l15) * 128 + ks * 32 + quad * 8);
                acc0 = __builtin_amdgcn_mfma_f32_16x16x32_bf16(a[0][ks], bfr, acc0, 0, 0, 0);
                acc1 = __builtin_amdgcn_mfma_f32_16x16x32_bf16(a[1][ks], bfr, acc1, 0, 0, 0);
            }
            float bias = b1[n0 + l15];
#pragma unroll
            for (int r = 0; r < 4; r++) {
                h1[(quad * 4 + r) * 520 + n0 + l15] = f2bf(gelu_exact(acc0[r] + bias));
                h1[(16 + quad * 4 + r) * 520 + n0 + l15] = f2bf(gelu_exact(acc1[r] + bias));
            }
        }
    }
    __syncthreads();

    // ---- GEMM2: h1[32x512] @ w2t^T -> acc; wave w owns n in [w*32, w*32+32) ----
    f32x4 acc[2][2];
    acc[0][0] = zero4; acc[0][1] = zero4; acc[1][0] = zero4; acc[1][1] = zero4;
    {
#pragma unroll 4
        for (int ks = 0; ks < 16; ks++) {
            bshort8 a0 = *(const bshort8*)(h1 + (l15) * 520 + ks * 32 + quad * 8);
            bshort8 a1 = *(const bshort8*)(h1 + (16 + l15) * 520 + ks * 32 + quad * 8);
#pragma unroll
            for (int nt = 0; nt < 2; nt++) {
                int n0 = w * 32 + nt * 16;
                bshort8 bfr = *(const bshort8*)(w2t + (size_t)(n0 + l15) * 512 + ks * 32 + quad * 8);
                acc[0][nt] = __builtin_amdgcn_mfma_f32_16x16x32_bf16(a0, bfr, acc[0][nt], 0, 0, 0);
                acc[1][nt] = __builtin_amdgcn_mfma_f32_16x16x32_bf16(a1, bfr, acc[1][nt], 0, 0, 0);
            }
        }
    }
    __syncthreads();   // h1 reads done everywhere; of32 may now overwrite

    // ---- epilogue: residual + bias into of32 (stride 132) ----
#pragma unroll
    for (int mt = 0; mt < 2; mt++) {
#pragma unroll
        for (int nt = 0; nt < 2; nt++) {
            int n0 = w * 32 + nt * 16;
            float bias = b2[n0 + l15];
#pragma unroll
            for (int r = 0; r < 4; r++) {
                int m = mt * 16 + quad * 4 + r;
                of32[m * 132 + n0 + l15] = xs[m * 132 + n0 + l15] + acc[mt][nt][r] + bias;
            }
        }
    }
    __syncthreads();

    // ---- transposed coalesced write: thread t -> channel c=t>>1, sp-range half ----
    {
        int c = t >> 1, half = t & 1, j0 = half * 16;
        float* dst = lout + ((size_t)(b * 128 + c)) * NSP + sp + j0;
#pragma unroll
        for (int i4 = 0; i4 < 4; i4++) {
            float4 ov = { of32[(j0 + i4 * 4 + 0) * 132 + c], of32[(j0 + i4 * 4 + 1) * 132 + c],
                          of32[(j0 + i4 * 4 + 2) * 132 + c], of32[(j0 + i4 * 4 + 3) * 132 + c] };
            *(float4*)(dst + i4 * 4) = ov;
        }
    }
}

extern "C" void kernel_launch(void* const* d_in, const int* in_sizes, int n_in,
                              void* d_out, int out_size, void* d_ws, size_t ws_size,
                              hipStream_t stream) {
    const float* x_in   = (const float*)d_in[0];
    const float* xg_in  = (const float*)d_in[1];
    const float* qkv_w  = (const float*)d_in[2];
    const float* qkv_b  = (const float*)d_in[3];
    const float* proj_w = (const float*)d_in[4];
    const float* proj_b = (const float*)d_in[5];
    const float* ln_g   = (const float*)d_in[6];
    const float* ln_b   = (const float*)d_in[7];
    const float* mlp_w1 = (const float*)d_in[8];
    const float* mlp_b1 = (const float*)d_in[9];
    const float* mlp_w2 = (const float*)d_in[10];
    const float* mlp_b2 = (const float*)d_in[11];
    const float* rq_w   = (const float*)d_in[12];
    const float* rq_b   = (const float*)d_in[13];
    const float* rk_w   = (const float*)d_in[14];
    const float* rk_b   = (const float*)d_in[15];
    const float* gqkv_w = (const float*)d_in[16];
    const float* gqkv_b = (const float*)d_in[17];
    const float* wo_w   = (const float*)d_in[18];
    const float* wo_b   = (const float*)d_in[19];
    const float* m2_w1  = (const float*)d_in[20];
    const float* m2_b1  = (const float*)d_in[21];
    const float* m2_w2  = (const float*)d_in[22];
    const float* m2_b2  = (const float*)d_in[23];

    float* out = (float*)d_out;
    float* ws  = (float*)d_ws;

    float* xg4 = ws;                                         // 524288
    float* xg  = ws + 524288;                                // 524288
    unsigned short* qgb  = (unsigned short*)(ws + 1048576);  // 524288 bf16
    unsigned short* kgb  = (unsigned short*)(ws + 1310720);  // 524288 bf16
    unsigned short* vgtb = (unsigned short*)(ws + 1572864);  // 524288 bf16 (V^T)
    float* og  = ws + 1835008;                               // 524288
    float* qh  = ws + 2359296;                               // 65536
    float* kh  = ws + 2424832;                               // 65536
    int*   tidx = (int*)(ws + 2490368);                      // 2048
    unsigned short* lnsc = (unsigned short*)(ws + 2492416);  // 6291456 bf16
    float* aout = ws + 2492416 + 3145728;                    // 4194304
    float* lpre = ws + 9832448;                              // 4194304
    unsigned short* wt   = (unsigned short*)(ws + 14026752); // 49152 bf16 (gqkv_w^T)
    unsigned short* w1t  = (unsigned short*)(ws + 14051328); // 65536 bf16
    unsigned short* w2t  = (unsigned short*)(ws + 14084096); // 65536 bf16

    const size_t L_OUT = (size_t)BATCH * CDIM * NSP;
    float* gout = out + L_OUT;

    hipLaunchKernelGGL(k_wtrans, dim3(192), dim3(256), 0, stream, gqkv_w, wt);
    hipLaunchKernelGGL(k_wprep_mlp2, dim3(512), dim3(256), 0, stream, m2_w1, m2_w2, w1t, w2t);
    hipLaunchKernelGGL(k_gqkv2, dim3(512), dim3(256), 0, stream,
                       xg_in, qkv_w, qkv_b, ln_g, ln_b, xg, qgb, kgb, vgtb);
    hipLaunchKernelGGL(k_gattn_mfma, dim3(2048), dim3(256), 0, stream, qgb, kgb, vgtb, og);
    hipLaunchKernelGGL(k_gmlp2, dim3(512), dim3(256), 0, stream,
                       og, xg, proj_w, proj_b, ln_g, ln_b, mlp_w1, mlp_b1, mlp_w2, mlp_b2,
                       xg4, gout);
    hipLaunchKernelGGL(k_routing_qk, dim3(512), dim3(128), 0, stream,
                       xg4, rq_w, rq_b, rk_w, rk_b, qh, kh);
    hipLaunchKernelGGL(k_topk, dim3(512), dim3(256), 0, stream, qh, kh, tidx);
    hipLaunchKernelGGL(k_lnsc_local, dim3(2048), dim3(256), 0, stream,
                       x_in, ln_g, ln_b, lnsc);
    hipLaunchKernelGGL(k_lnsc_gath, dim3(2048), dim3(256), 0, stream,
                       xg4, tidx, ln_g, ln_b, lnsc);
    hipLaunchKernelGGL(k_local_mfma, dim3(512), dim3(256), 0, stream,
                       lnsc, wt, gqkv_b, aout);
    hipLaunchKernelGGL(k_wo2, dim3(4096), dim3(256), 0, stream,
                       aout, wo_w, wo_b, x_in, lpre);
    hipLaunchKernelGGL(k_mlp2_mfma, dim3(1024), dim3(256), 0, stream,
                       lpre, ln_g, ln_b, w1t, m2_b1, w2t, m2_b2, out);
}

// Round 6
// 320.994 us; speedup vs baseline: 8.0382x; 1.0958x over previous
//
#include <hip/hip_runtime.h>
#include <hip/hip_bf16.h>
#include <math.h>

#define BATCH 2
#define CDIM 128
#define SS 16
#define HH_ 32
#define WW_ 32
#define NSP (SS*HH_*WW_)
#define GS 8
#define GH 16
#define GW 16
#define GN (GS*GH*GW)
#define HEADS 8
#define DH 16
#define NW 256
#define W3L 64
#define W3G 8
#define TOPK 4
#define W3 (W3L + TOPK*W3G)
#define LN_EPS 1e-6f
#define ROUTE_SCALE 0.08838834764831845f
#define GATTN_SCALE 0.25f

typedef short bshort8 __attribute__((ext_vector_type(8)));
typedef float f32x4 __attribute__((ext_vector_type(4)));

__device__ __forceinline__ unsigned short f2bf(float f) {
    unsigned int u = __float_as_uint(f);
    unsigned int r = (u + 0x7fffu + ((u >> 16) & 1u)) >> 16;
    return (unsigned short)r;
}
__device__ __forceinline__ float bf2f_lo(unsigned int u) { return __uint_as_float(u << 16); }
__device__ __forceinline__ float bf2f_hi(unsigned int u) { return __uint_as_float(u & 0xffff0000u); }

__device__ __forceinline__ float gelu_exact(float x) {
    return 0.5f * x * (1.0f + erff(x * 0.70710678118654752f));
}

__device__ __forceinline__ float shfl_sum32(float v) {
#pragma unroll
    for (int m = 16; m > 0; m >>= 1) v += __shfl_xor(v, m);
    return v;
}
__device__ __forceinline__ float shfl_sum16(float v) {
#pragma unroll
    for (int m = 8; m > 0; m >>= 1) v += __shfl_xor(v, m);
    return v;
}
__device__ __forceinline__ float shfl_sum8(float v) {
#pragma unroll
    for (int m = 4; m > 0; m >>= 1) v += __shfl_xor(v, m);
    return v;
}

// ---------------- K0a: transpose gqkv_w -> bf16 W^T[384][128], scale folded for Q ----------------
__global__ __launch_bounds__(256) void k_wtrans(const float* __restrict__ gqkv_w,
                                                unsigned short* __restrict__ wt) {
    int id = blockIdx.x * 256 + threadIdx.x;   // 0..49151
    int n = id >> 7, k = id & 127;
    float v = gqkv_w[k * 384 + n];
    if (n < 128) v *= ROUTE_SCALE;
    wt[id] = f2bf(v);
}

// ---------------- K0b: mlp2 weights -> bf16 transposed ----------------
__global__ __launch_bounds__(256) void k_wprep_mlp2(const float* __restrict__ w1,
        const float* __restrict__ w2, unsigned short* __restrict__ w1t,
        unsigned short* __restrict__ w2t) {
    int id = blockIdx.x * 256 + threadIdx.x;   // 0..131071
    if (id < 65536) {
        int n = id >> 7, k = id & 127;
        w1t[id] = f2bf(w1[k * 512 + n]);
    } else {
        int id2 = id - 65536;
        int n = id2 >> 9, k = id2 & 511;
        w2t[id2] = f2bf(w2[k * 128 + n]);
    }
}

// ---------------- K0c: global-branch + wo weights -> bf16 transposed ----------------
// proj_w[128][128]->projt[128][128]; mlp_w1[128][512]->gw1t[512][128];
// mlp_w2[512][128]->gw2t[128][512]; wo_w[128][128]->wot[128][128]
__global__ __launch_bounds__(256) void k_wprep_global(const float* __restrict__ proj_w,
        const float* __restrict__ mlp_w1, const float* __restrict__ mlp_w2,
        const float* __restrict__ wo_w,
        unsigned short* __restrict__ projt, unsigned short* __restrict__ gw1t,
        unsigned short* __restrict__ gw2t, unsigned short* __restrict__ wot) {
    int id = blockIdx.x * 256 + threadIdx.x;   // 0..163839
    if (id < 16384) {
        int n = id >> 7, k = id & 127;
        projt[id] = f2bf(proj_w[k * 128 + n]);
    } else if (id < 81920) {
        int i = id - 16384;
        int n = i >> 7, k = i & 127;
        gw1t[i] = f2bf(mlp_w1[k * 512 + n]);
    } else if (id < 147456) {
        int i = id - 81920;
        int n = i >> 9, k = i & 511;
        gw2t[i] = f2bf(mlp_w2[k * 128 + n]);
    } else {
        int i = id - 147456;
        int n = i >> 7, k = i & 127;
        wot[i] = f2bf(wo_w[k * 128 + n]);
    }
}

// ---------------- K1: global branch qkv (T=8 tokens/block), bf16 q/k/v^T out ----------------
__global__ __launch_bounds__(256) void k_gqkv2(const float* __restrict__ xg_in,
        const float* __restrict__ qkv_w, const float* __restrict__ qkv_b,
        const float* __restrict__ ln_g, const float* __restrict__ ln_b,
        float* __restrict__ xg, unsigned short* __restrict__ qgb,
        unsigned short* __restrict__ kgb, unsigned short* __restrict__ vgtb) {
    int blk = blockIdx.x; int b = blk >> 8; int n0 = (blk & 255) * 8;
    int t = threadIdx.x;
    __shared__ float xs[8][128];
    __shared__ float h[8][128];
    {
        int c = t >> 1, q4 = (t & 1) * 4;
        float4 v = *(const float4*)(xg_in + ((size_t)(b * 128 + c)) * GN + n0 + q4);
        xs[q4 + 0][c] = v.x; xs[q4 + 1][c] = v.y; xs[q4 + 2][c] = v.z; xs[q4 + 3][c] = v.w;
    }
    __syncthreads();
    int j = t >> 5, c4 = (t & 31) * 4;
    float4 v = *(float4*)&xs[j][c4];
    *(float4*)(xg + ((size_t)(b * GN) + n0 + j) * 128 + c4) = v;
    float s1 = shfl_sum32(v.x + v.y + v.z + v.w);
    float mu = s1 * (1.0f / 128.0f);
    float d0 = v.x - mu, d1 = v.y - mu, d2 = v.z - mu, d3 = v.w - mu;
    float s2 = shfl_sum32(d0 * d0 + d1 * d1 + d2 * d2 + d3 * d3);
    float rs = rsqrtf(s2 * (1.0f / 128.0f) + LN_EPS);
    float4 g4 = *(const float4*)(ln_g + c4);
    float4 b4 = *(const float4*)(ln_b + c4);
    float4 hn = { d0 * rs * g4.x + b4.x, d1 * rs * g4.y + b4.y,
                  d2 * rs * g4.z + b4.z, d3 * rs * g4.w + b4.w };
    *(float4*)&h[j][c4] = hn;
    __syncthreads();
    for (int c = t; c < 384; c += 256) {
        float acc[8];
        float bias = qkv_b[c];
#pragma unroll
        for (int jj = 0; jj < 8; jj++) acc[jj] = bias;
        for (int k = 0; k < 128; k++) {
            float w = qkv_w[k * 384 + c];
#pragma unroll
            for (int jj = 0; jj < 8; jj++) acc[jj] = fmaf(h[jj][k], w, acc[jj]);
        }
        int part = c >> 7, head = (c >> 4) & 7, d = c & 15;
        int bh = b * HEADS + head;
        if (part == 0) {
#pragma unroll
            for (int jj = 0; jj < 8; jj++)
                qgb[((size_t)bh * GN + n0 + jj) * DH + d] = f2bf(acc[jj] * GATTN_SCALE);
        } else if (part == 1) {
#pragma unroll
            for (int jj = 0; jj < 8; jj++)
                kgb[((size_t)bh * GN + n0 + jj) * DH + d] = f2bf(acc[jj]);
        } else {
            ushort4 u0, u1;
            u0.x = f2bf(acc[0]); u0.y = f2bf(acc[1]); u0.z = f2bf(acc[2]); u0.w = f2bf(acc[3]);
            u1.x = f2bf(acc[4]); u1.y = f2bf(acc[5]); u1.z = f2bf(acc[6]); u1.w = f2bf(acc[7]);
            unsigned short* dst = vgtb + ((size_t)bh * DH + d) * GN + n0;
            *(ushort4*)dst = u0; *(ushort4*)(dst + 4) = u1;
        }
    }
}

// ---------------- K2: global attention via MFMA bf16 ----------------
__global__ __launch_bounds__(256) void k_gattn_mfma(const unsigned short* __restrict__ qgb,
        const unsigned short* __restrict__ kgb, const unsigned short* __restrict__ vgtb,
        float* __restrict__ og) {
    int blk = blockIdx.x;
    int bh = blk >> 7; int qt = (blk & 127) << 4;
    int b = bh >> 3, hh = bh & 7;
    int t = threadIdx.x; int w = t >> 6; int lane = t & 63;
    int col = lane & 15, quad = lane >> 4;
    __shared__ __align__(16) unsigned short Pbuf[4 * 16 * 40];
    __shared__ float po[4][64][4];
    __shared__ float pl[4][64][4];

    bshort8 aq = {0, 0, 0, 0, 0, 0, 0, 0};
    if (quad < 2)
        aq = *(const bshort8*)(qgb + ((size_t)bh * GN + qt + col) * DH + quad * 8);

    f32x4 o = {0.f, 0.f, 0.f, 0.f};
    float lsum[4] = {0.f, 0.f, 0.f, 0.f};
    const unsigned short* kb = kgb + (size_t)bh * GN * DH;
    const unsigned short* vb = vgtb + (size_t)bh * DH * GN;
    unsigned short* pb = Pbuf + w * (16 * 40);
    int row0 = quad * 4;
    int kbeg = w * 512;
    for (int kc = kbeg; kc < kbeg + 512; kc += 32) {
        bshort8 bk0 = {0, 0, 0, 0, 0, 0, 0, 0};
        bshort8 bk1 = {0, 0, 0, 0, 0, 0, 0, 0};
        if (quad < 2) {
            bk0 = *(const bshort8*)(kb + (size_t)(kc + col) * DH + quad * 8);
            bk1 = *(const bshort8*)(kb + (size_t)(kc + 16 + col) * DH + quad * 8);
        }
        f32x4 z = {0.f, 0.f, 0.f, 0.f};
        f32x4 s0 = __builtin_amdgcn_mfma_f32_16x16x32_bf16(aq, bk0, z, 0, 0, 0);
        f32x4 s1 = __builtin_amdgcn_mfma_f32_16x16x32_bf16(aq, bk1, z, 0, 0, 0);
        float p0[4], p1[4];
#pragma unroll
        for (int r = 0; r < 4; r++) {
            p0[r] = __expf(s0[r]); p1[r] = __expf(s1[r]);
            lsum[r] += p0[r] + p1[r];
        }
#pragma unroll
        for (int r = 0; r < 4; r++) {
            pb[(row0 + r) * 40 + col] = f2bf(p0[r]);
            pb[(row0 + r) * 40 + 16 + col] = f2bf(p1[r]);
        }
        bshort8 pA = *(const bshort8*)(pb + col * 40 + quad * 8);
        bshort8 bv = *(const bshort8*)(vb + (size_t)col * GN + kc + quad * 8);
        o = __builtin_amdgcn_mfma_f32_16x16x32_bf16(pA, bv, o, 0, 0, 0);
    }
#pragma unroll
    for (int r = 0; r < 4; r++) {
        float v = lsum[r];
        v += __shfl_xor(v, 1); v += __shfl_xor(v, 2);
        v += __shfl_xor(v, 4); v += __shfl_xor(v, 8);
        lsum[r] = v;
    }
#pragma unroll
    for (int r = 0; r < 4; r++) { po[w][lane][r] = o[r]; pl[w][lane][r] = lsum[r]; }
    __syncthreads();
    if (w == 0) {
#pragma unroll
        for (int r = 0; r < 4; r++) {
            float os = po[0][lane][r] + po[1][lane][r] + po[2][lane][r] + po[3][lane][r];
            float ls = pl[0][lane][r] + pl[1][lane][r] + pl[2][lane][r] + pl[3][lane][r];
            og[((size_t)(b * GN) + qt + quad * 4 + r) * 128 + hh * 16 + col] = os / ls;
        }
    }
}

// ---------------- K3: global proj+residual+LN+MLP via MFMA, 16 tokens/block ----------------
// LDS: ao[16][136] bf16 + xs[16][132] f32 + h[16][136] bf16 + h1[16][520] bf16 = 33792 B
__global__ __launch_bounds__(256) void k_gmlp_mfma(const float* __restrict__ og,
        const float* __restrict__ xg,
        const unsigned short* __restrict__ projt, const float* __restrict__ proj_b,
        const float* __restrict__ ln_g, const float* __restrict__ ln_b,
        const unsigned short* __restrict__ gw1t, const float* __restrict__ b1,
        const unsigned short* __restrict__ gw2t, const float* __restrict__ b2,
        float* __restrict__ xg4, float* __restrict__ gout) {
    int blk = blockIdx.x; int b = blk >> 7; int n0g = (blk & 127) * 16;
    int t = threadIdx.x; int w = t >> 6; int lane = t & 63;
    int l15 = lane & 15, quad = lane >> 4;
    __shared__ __align__(16) unsigned short ao[16 * 136];
    __shared__ __align__(16) float xs[16 * 132];
    __shared__ __align__(16) unsigned short h[16 * 136];
    __shared__ __align__(16) unsigned short h1[16 * 520];
    float* of32 = (float*)h1;
    f32x4 zero4 = {0.f, 0.f, 0.f, 0.f};

    {   // load og (-> bf16 ao) and xg (-> f32 xs); 16 threads/token, 8 ch each
        int j = t >> 4, p = t & 15, c0 = p * 8;
        size_t base = ((size_t)(b * GN) + n0g + j) * 128 + c0;
        float4 v0 = *(const float4*)(og + base);
        float4 v1 = *(const float4*)(og + base + 4);
        ushort4 u0 = { f2bf(v0.x), f2bf(v0.y), f2bf(v0.z), f2bf(v0.w) };
        ushort4 u1 = { f2bf(v1.x), f2bf(v1.y), f2bf(v1.z), f2bf(v1.w) };
        *(ushort4*)&ao[j * 136 + c0] = u0;
        *(ushort4*)&ao[j * 136 + c0 + 4] = u1;
        *(float4*)&xs[j * 132 + c0] = *(const float4*)(xg + base);
        *(float4*)&xs[j * 132 + c0 + 4] = *(const float4*)(xg + base + 4);
    }
    __syncthreads();

    {   // proj GEMM: M=16, K=128, N=128; wave w owns n0 = w*32 (2 tiles); xs += result
        bshort8 a[4];
#pragma unroll
        for (int ks = 0; ks < 4; ks++)
            a[ks] = *(const bshort8*)(ao + l15 * 136 + ks * 32 + quad * 8);
#pragma unroll
        for (int nt = 0; nt < 2; nt++) {
            int n0 = w * 32 + nt * 16;
            f32x4 acc = zero4;
#pragma unroll
            for (int ks = 0; ks < 4; ks++) {
                bshort8 bfr = *(const bshort8*)(projt + (n0 + l15) * 128 + ks * 32 + quad * 8);
                acc = __builtin_amdgcn_mfma_f32_16x16x32_bf16(a[ks], bfr, acc, 0, 0, 0);
            }
            float bias = proj_b[n0 + l15];
#pragma unroll
            for (int r = 0; r < 4; r++) {
                int m = quad * 4 + r;
                xs[m * 132 + n0 + l15] += acc[r] + bias;
            }
        }
    }
    __syncthreads();

    {   // LN -> h bf16
        int j = t >> 4, p = t & 15, c0 = p * 8;
        float vv[8]; float s1 = 0.f;
#pragma unroll
        for (int i = 0; i < 8; i++) { vv[i] = xs[j * 132 + c0 + i]; s1 += vv[i]; }
        s1 = shfl_sum16(s1);
        float mu = s1 * (1.0f / 128.0f);
        float s2 = 0.f;
#pragma unroll
        for (int i = 0; i < 8; i++) { float d = vv[i] - mu; s2 += d * d; }
        s2 = shfl_sum16(s2);
        float rs = rsqrtf(s2 * (1.0f / 128.0f) + LN_EPS);
        unsigned short hb[8];
#pragma unroll
        for (int i4 = 0; i4 < 2; i4++) {
            float4 g4 = *(const float4*)(ln_g + c0 + i4 * 4);
            float4 b4 = *(const float4*)(ln_b + c0 + i4 * 4);
            hb[i4 * 4 + 0] = f2bf((vv[i4 * 4 + 0] - mu) * rs * g4.x + b4.x);
            hb[i4 * 4 + 1] = f2bf((vv[i4 * 4 + 1] - mu) * rs * g4.y + b4.y);
            hb[i4 * 4 + 2] = f2bf((vv[i4 * 4 + 2] - mu) * rs * g4.z + b4.z);
            hb[i4 * 4 + 3] = f2bf((vv[i4 * 4 + 3] - mu) * rs * g4.w + b4.w);
        }
        *(ushort4*)&h[j * 136 + c0] = *(ushort4*)&hb[0];
        *(ushort4*)&h[j * 136 + c0 + 4] = *(ushort4*)&hb[4];
    }
    __syncthreads();

    {   // GEMM1: M=16, K=128, N=512; wave w owns n in [w*128, w*128+128)
        bshort8 a[4];
#pragma unroll
        for (int ks = 0; ks < 4; ks++)
            a[ks] = *(const bshort8*)(h + l15 * 136 + ks * 32 + quad * 8);
#pragma unroll
        for (int nt = 0; nt < 8; nt++) {
            int n0 = w * 128 + nt * 16;
            f32x4 acc = zero4;
#pragma unroll
            for (int ks = 0; ks < 4; ks++) {
                bshort8 bfr = *(const bshort8*)(gw1t + (size_t)(n0 + l15) * 128 + ks * 32 + quad * 8);
                acc = __builtin_amdgcn_mfma_f32_16x16x32_bf16(a[ks], bfr, acc, 0, 0, 0);
            }
            float bias = b1[n0 + l15];
#pragma unroll
            for (int r = 0; r < 4; r++)
                h1[(quad * 4 + r) * 520 + n0 + l15] = f2bf(gelu_exact(acc[r] + bias));
        }
    }
    __syncthreads();

    // GEMM2: M=16, K=512, N=128; wave w owns n0 = w*32 (2 tiles)
    f32x4 acc2[2]; acc2[0] = zero4; acc2[1] = zero4;
#pragma unroll 4
    for (int ks = 0; ks < 16; ks++) {
        bshort8 a = *(const bshort8*)(h1 + l15 * 520 + ks * 32 + quad * 8);
#pragma unroll
        for (int nt = 0; nt < 2; nt++) {
            int n0 = w * 32 + nt * 16;
            bshort8 bfr = *(const bshort8*)(gw2t + (size_t)(n0 + l15) * 512 + ks * 32 + quad * 8);
            acc2[nt] = __builtin_amdgcn_mfma_f32_16x16x32_bf16(a, bfr, acc2[nt], 0, 0, 0);
        }
    }
    __syncthreads();   // h1 reads done; of32 may overwrite

    {   // epilogue: residual + bias -> of32 + direct xg4 store
#pragma unroll
        for (int nt = 0; nt < 2; nt++) {
            int n0 = w * 32 + nt * 16;
            float bias = b2[n0 + l15];
#pragma unroll
            for (int r = 0; r < 4; r++) {
                int m = quad * 4 + r;
                float ov = xs[m * 132 + n0 + l15] + acc2[nt][r] + bias;
                of32[m * 132 + n0 + l15] = ov;
                xg4[((size_t)(b * GN) + n0g + m) * 128 + n0 + l15] = ov;
            }
        }
    }
    __syncthreads();

    {   // transposed gout write: thread t -> channel cw, 8 tokens
        int cw = t >> 1, hf = t & 1, j0 = hf * 8;
        float* dst = gout + ((size_t)(b * 128 + cw)) * GN + n0g + j0;
#pragma unroll
        for (int i4 = 0; i4 < 2; i4++) {
            float4 ov = { of32[(j0 + i4 * 4 + 0) * 132 + cw], of32[(j0 + i4 * 4 + 1) * 132 + cw],
                          of32[(j0 + i4 * 4 + 2) * 132 + cw], of32[(j0 + i4 * 4 + 3) * 132 + cw] };
            *(float4*)(dst + i4 * 4) = ov;
        }
    }
}

// ---------------- K4a: routing q/k ----------------
__global__ void k_routing_qk(const float* __restrict__ xg4,
                             const float* __restrict__ rq_w, const float* __restrict__ rq_b,
                             const float* __restrict__ rk_w, const float* __restrict__ rk_b,
                             float* __restrict__ qh, float* __restrict__ kh) {
    int wid = blockIdx.x; int b = wid / NW, n = wid % NW;
    int c = threadIdx.x;
    int i1 = n / 64, i2 = (n / 8) % 8, i3 = n % 8;
    __shared__ float g[CDIM];
    float s = 0.f;
#pragma unroll
    for (int j = 0; j < W3G; j++) {
        int ds = j >> 2, dh = (j >> 1) & 1, dw = j & 1;
        int gi = ((i1 * 2 + ds) * GH + (i2 * 2 + dh)) * GW + (i3 * 2 + dw);
        s += xg4[((size_t)(b * GN + gi)) * CDIM + c];
    }
    g[c] = s * (1.0f / W3G);
    __syncthreads();
    float aq = rq_b[c], ak = rk_b[c];
    for (int k = 0; k < CDIM; k++) { float gv = g[k]; aq = fmaf(gv, rq_w[k * CDIM + c], aq); ak = fmaf(gv, rk_w[k * CDIM + c], ak); }
    qh[(size_t)wid * CDIM + c] = aq;
    kh[(size_t)wid * CDIM + c] = ak;
}

// ---------------- K4b: top-k ----------------
__global__ void k_topk(const float* __restrict__ qh, const float* __restrict__ kh,
                       int* __restrict__ tidx) {
    int wid = blockIdx.x; int b = wid / NW;
    int m = threadIdx.x;
    __shared__ float q[CDIM];
    __shared__ float lv[NW];
    __shared__ int li[NW];
    if (m < CDIM) q[m] = qh[(size_t)wid * CDIM + m] * ROUTE_SCALE;
    __syncthreads();
    float acc = 0.f;
    const float* kr = kh + ((size_t)b * NW + m) * CDIM;
    for (int k = 0; k < CDIM; k++) acc = fmaf(q[k], kr[k], acc);
#pragma unroll
    for (int sel = 0; sel < TOPK; sel++) {
        lv[m] = acc; li[m] = m; __syncthreads();
#pragma unroll
        for (int s = 128; s > 0; s >>= 1) {
            if (m < s) {
                if (lv[m + s] > lv[m] || (lv[m + s] == lv[m] && li[m + s] < li[m])) {
                    lv[m] = lv[m + s]; li[m] = li[m + s];
                }
            }
            __syncthreads();
        }
        int best = li[0]; __syncthreads();
        if (m == best) acc = -1e30f;
        if (m == 0) tidx[wid * TOPK + sel] = best;
    }
}

// ---------------- K5a: LN local tokens -> lnsc bf16 ----------------
__global__ __launch_bounds__(256) void k_lnsc_local(const float* __restrict__ x_in,
        const float* __restrict__ ln_g, const float* __restrict__ ln_b,
        unsigned short* __restrict__ lnsc) {
    int blk = blockIdx.x;
    int wt = blk & 1; int hh = (blk >> 1) & 31; int s = (blk >> 6) & 15; int b = blk >> 10;
    int w0 = wt * 16;
    int t = threadIdx.x;
    __shared__ float tile[16][132];
    {
        int c = t >> 1; int wq = (t & 1) * 8;
        const float* src = x_in + (((size_t)(b * 128 + c) * SS + s)) * 1024 + hh * 32 + w0 + wq;
        float4 v0 = *(const float4*)src;
        float4 v1 = *(const float4*)(src + 4);
        tile[wq + 0][c] = v0.x; tile[wq + 1][c] = v0.y; tile[wq + 2][c] = v0.z; tile[wq + 3][c] = v0.w;
        tile[wq + 4][c] = v1.x; tile[wq + 5][c] = v1.y; tile[wq + 6][c] = v1.z; tile[wq + 7][c] = v1.w;
    }
    __syncthreads();
    int w = t >> 4; int j = t & 15;
    float vals[8];
    float s1 = 0.f;
#pragma unroll
    for (int i = 0; i < 8; i++) { vals[i] = tile[w][j * 8 + i]; s1 += vals[i]; }
    s1 = shfl_sum16(s1);
    float mu = s1 * (1.0f / 128.0f);
    float s2 = 0.f;
#pragma unroll
    for (int i = 0; i < 8; i++) { float d = vals[i] - mu; s2 += d * d; }
    s2 = shfl_sum16(s2);
    float rs = rsqrtf(s2 * (1.0f / 128.0f) + LN_EPS);
    float4 g0 = *(const float4*)(ln_g + j * 8);
    float4 g1 = *(const float4*)(ln_g + j * 8 + 4);
    float4 b0 = *(const float4*)(ln_b + j * 8);
    float4 b1 = *(const float4*)(ln_b + j * 8 + 4);
    float gv[8] = { g0.x, g0.y, g0.z, g0.w, g1.x, g1.y, g1.z, g1.w };
    float bv[8] = { b0.x, b0.y, b0.z, b0.w, b1.x, b1.y, b1.z, b1.w };
    int ww = w0 + w;
    int n = (s >> 2) * 64 + (hh >> 2) * 8 + (ww >> 2);
    int slot = (s & 3) * 16 + (hh & 3) * 4 + (ww & 3);
    unsigned short* dst = lnsc + ((size_t)(b * NW + n) * W3 + slot) * 128 + j * 8;
    ushort4 u0, u1;
    u0.x = f2bf((vals[0] - mu) * rs * gv[0] + bv[0]);
    u0.y = f2bf((vals[1] - mu) * rs * gv[1] + bv[1]);
    u0.z = f2bf((vals[2] - mu) * rs * gv[2] + bv[2]);
    u0.w = f2bf((vals[3] - mu) * rs * gv[3] + bv[3]);
    u1.x = f2bf((vals[4] - mu) * rs * gv[4] + bv[4]);
    u1.y = f2bf((vals[5] - mu) * rs * gv[5] + bv[5]);
    u1.z = f2bf((vals[6] - mu) * rs * gv[6] + bv[6]);
    u1.w = f2bf((vals[7] - mu) * rs * gv[7] + bv[7]);
    *(ushort4*)dst = u0;
    *(ushort4*)(dst + 4) = u1;
}

// ---------------- K5b: LN gathered global tokens -> lnsc bf16 ----------------
__global__ __launch_bounds__(256) void k_lnsc_gath(const float* __restrict__ xg4,
        const int* __restrict__ tidx,
        const float* __restrict__ ln_g, const float* __restrict__ ln_b,
        unsigned short* __restrict__ lnsc) {
    int blk = blockIdx.x;
    int kk = blk & 3; int wn = blk >> 2;
    int b = wn >> 8;
    int g = tidx[wn * TOPK + kk];
    int gi1 = g >> 6, gi2 = (g >> 3) & 7, gi3 = g & 7;
    int t = threadIdx.x; int j = t >> 5, lj = t & 31;
    int ds = j >> 2, dh = (j >> 1) & 1, dw = j & 1;
    int gi = ((gi1 * 2 + ds) * GH + (gi2 * 2 + dh)) * GW + (gi3 * 2 + dw);
    float4 v = *(const float4*)(xg4 + ((size_t)(b * GN + gi)) * 128 + lj * 4);
    float s1 = shfl_sum32(v.x + v.y + v.z + v.w);
    float mu = s1 * (1.0f / 128.0f);
    float d0 = v.x - mu, d1 = v.y - mu, d2 = v.z - mu, d3 = v.w - mu;
    float s2 = shfl_sum32(d0 * d0 + d1 * d1 + d2 * d2 + d3 * d3);
    float rs = rsqrtf(s2 * (1.0f / 128.0f) + LN_EPS);
    float4 g4 = *(const float4*)(ln_g + lj * 4);
    float4 b4 = *(const float4*)(ln_b + lj * 4);
    ushort4 u;
    u.x = f2bf(d0 * rs * g4.x + b4.x);
    u.y = f2bf(d1 * rs * g4.y + b4.y);
    u.z = f2bf(d2 * rs * g4.z + b4.z);
    u.w = f2bf(d3 * rs * g4.w + b4.w);
    *(ushort4*)(lnsc + ((size_t)wn * W3 + 64 + kk * 8 + j) * 128 + lj * 4) = u;
}

// ---------------- K6: local attention via MFMA ----------------
__global__ __launch_bounds__(256) void k_local_mfma(const unsigned short* __restrict__ lnsc,
        const unsigned short* __restrict__ wt, const float* __restrict__ gqkv_b,
        float* __restrict__ aout) {
    int wn = blockIdx.x;
    int t = threadIdx.x; int w = t >> 6; int lane = t & 63;
    int l15 = lane & 15, quad = lane >> 4;
    __shared__ __align__(16) unsigned short Qs[64 * 136];
    __shared__ __align__(16) unsigned short Ks2[96 * 136];
    __shared__ __align__(16) unsigned short Vts[128 * 104];
    __shared__ __align__(16) unsigned short Ps[4][16 * 40];

    const unsigned short* Xb = lnsc + (size_t)wn * W3 * 128;
    f32x4 zero4 = {0.f, 0.f, 0.f, 0.f};

    for (int mt = 0; mt < 4; mt++) {
        bshort8 a[4];
#pragma unroll
        for (int ks = 0; ks < 4; ks++)
            a[ks] = *(const bshort8*)(Xb + (mt * 16 + l15) * 128 + ks * 32 + quad * 8);
#pragma unroll
        for (int which = 0; which < 2; which++) {
            int n0 = (w + which * 4) * 16;
            f32x4 acc = zero4;
#pragma unroll
            for (int ks = 0; ks < 4; ks++) {
                bshort8 bfr = *(const bshort8*)(wt + (n0 + l15) * 128 + ks * 32 + quad * 8);
                acc = __builtin_amdgcn_mfma_f32_16x16x32_bf16(a[ks], bfr, acc, 0, 0, 0);
            }
            float bias = gqkv_b[n0 + l15] * ROUTE_SCALE;
#pragma unroll
            for (int r = 0; r < 4; r++)
                Qs[(mt * 16 + quad * 4 + r) * 136 + n0 + l15] = f2bf(acc[r] + bias);
        }
    }
    for (int mt = 0; mt < 6; mt++) {
        bshort8 a[4];
#pragma unroll
        for (int ks = 0; ks < 4; ks++)
            a[ks] = *(const bshort8*)(Xb + (mt * 16 + l15) * 128 + ks * 32 + quad * 8);
#pragma unroll
        for (int which = 0; which < 2; which++) {
            int nt8 = w + which * 4;
            int n0g = 128 + nt8 * 16;
            f32x4 acc = zero4;
#pragma unroll
            for (int ks = 0; ks < 4; ks++) {
                bshort8 bfr = *(const bshort8*)(wt + (n0g + l15) * 128 + ks * 32 + quad * 8);
                acc = __builtin_amdgcn_mfma_f32_16x16x32_bf16(a[ks], bfr, acc, 0, 0, 0);
            }
            float bias = gqkv_b[n0g + l15];
#pragma unroll
            for (int r = 0; r < 4; r++)
                Ks2[(mt * 16 + quad * 4 + r) * 136 + nt8 * 16 + l15] = f2bf(acc[r] + bias);
        }
    }
    for (int which = 0; which < 2; which++) {
        int mtv = 2 * w + which;
        bshort8 a[4];
#pragma unroll
        for (int ks = 0; ks < 4; ks++)
            a[ks] = *(const bshort8*)(wt + (256 + mtv * 16 + l15) * 128 + ks * 32 + quad * 8);
        float biasr[4];
#pragma unroll
        for (int r = 0; r < 4; r++) biasr[r] = gqkv_b[256 + mtv * 16 + quad * 4 + r];
        for (int ntv = 0; ntv < 6; ntv++) {
            f32x4 acc = zero4;
#pragma unroll
            for (int ks = 0; ks < 4; ks++) {
                bshort8 bfr = *(const bshort8*)(Xb + (ntv * 16 + l15) * 128 + ks * 32 + quad * 8);
                acc = __builtin_amdgcn_mfma_f32_16x16x32_bf16(a[ks], bfr, acc, 0, 0, 0);
            }
#pragma unroll
            for (int r = 0; r < 4; r++)
                Vts[(mtv * 16 + quad * 4 + r) * 104 + ntv * 16 + l15] = f2bf(acc[r] + biasr[r]);
        }
    }
    __syncthreads();

    unsigned short* Pw = &Ps[w][0];
    bshort8 zfrag = {0, 0, 0, 0, 0, 0, 0, 0};
#pragma unroll
    for (int hh2 = 0; hh2 < 2; hh2++) {
        int h = 2 * w + hh2;
        for (int mt = 0; mt < 4; mt++) {
            bshort8 aq = zfrag;
            if (quad < 2)
                aq = *(const bshort8*)(Qs + (mt * 16 + l15) * 136 + h * 16 + quad * 8);
            float rsum[4] = {0.f, 0.f, 0.f, 0.f};
            f32x4 oacc = zero4;
#pragma unroll
            for (int kc = 0; kc < 96; kc += 32) {
#pragma unroll
                for (int sub = 0; sub < 2; sub++) {
                    int nt = (kc >> 4) + sub;
                    bshort8 bk = zfrag;
                    if (quad < 2)
                        bk = *(const bshort8*)(Ks2 + (nt * 16 + l15) * 136 + h * 16 + quad * 8);
                    f32x4 s = __builtin_amdgcn_mfma_f32_16x16x32_bf16(aq, bk, zero4, 0, 0, 0);
#pragma unroll
                    for (int r = 0; r < 4; r++) {
                        float p = __expf(s[r]);
                        rsum[r] += p;
                        Pw[(quad * 4 + r) * 40 + sub * 16 + l15] = f2bf(p);
                    }
                }
                bshort8 ap = *(const bshort8*)(Pw + l15 * 40 + quad * 8);
                bshort8 bv = *(const bshort8*)(Vts + (h * 16 + l15) * 104 + kc + quad * 8);
                oacc = __builtin_amdgcn_mfma_f32_16x16x32_bf16(ap, bv, oacc, 0, 0, 0);
            }
#pragma unroll
            for (int r = 0; r < 4; r++) {
                float v = rsum[r];
                v += __shfl_xor(v, 1); v += __shfl_xor(v, 2);
                v += __shfl_xor(v, 4); v += __shfl_xor(v, 8);
                rsum[r] = v;
            }
#pragma unroll
            for (int r = 0; r < 4; r++)
                aout[((size_t)wn * W3L + mt * 16 + quad * 4 + r) * 128 + h * 16 + l15]
                    = oacc[r] / rsum[r];
        }
    }
}

// ---------------- K7: wo projection + shortcut via MFMA, 32 spatial tokens/block ----------------
// LDS: as2[32][136] bf16 (8704) + xs[32][132] f32 (16896) = 25600 B
__global__ __launch_bounds__(256) void k_wo_mfma(const float* __restrict__ aout,
        const unsigned short* __restrict__ wot, const float* __restrict__ wo_b,
        const float* __restrict__ x_in, float* __restrict__ lpre) {
    int blk = blockIdx.x; int T0 = blk * 32;
    int b = T0 >> 14; int sp0 = T0 & 16383;
    int t = threadIdx.x; int w = t >> 6; int lane = t & 63;
    int l15 = lane & 15, quad = lane >> 4;
    __shared__ __align__(16) unsigned short as2[32 * 136];
    __shared__ __align__(16) float xs[32 * 132];
    f32x4 zero4 = {0.f, 0.f, 0.f, 0.f};

    {   // gather A-rows from window-ordered aout -> bf16 LDS (8 threads/token, 16 ch each)
        int j = t >> 3, p = t & 7, c0 = p * 16;
        int sp = sp0 + j;
        int s = sp >> 10, hh = (sp >> 5) & 31, ww = sp & 31;
        int n = (s >> 2) * 64 + (hh >> 2) * 8 + (ww >> 2);
        int slot = (s & 3) * 16 + (hh & 3) * 4 + (ww & 3);
        const float* src = aout + (((size_t)(b * NW + n)) * W3L + slot) * 128 + c0;
#pragma unroll
        for (int i4 = 0; i4 < 4; i4++) {
            float4 v = *(const float4*)(src + i4 * 4);
            ushort4 u = { f2bf(v.x), f2bf(v.y), f2bf(v.z), f2bf(v.w) };
            *(ushort4*)&as2[j * 136 + c0 + i4 * 4] = u;
        }
    }
    {   // shortcut transpose-load from x_in (channel-major) -> xs[token][c]
        int c = t >> 1, half = t & 1, j0 = half * 16;
        const float* src = x_in + ((size_t)(b * 128 + c)) * 16384 + sp0 + j0;
#pragma unroll
        for (int i4 = 0; i4 < 4; i4++) {
            float4 v = *(const float4*)(src + i4 * 4);
            xs[(j0 + i4 * 4 + 0) * 132 + c] = v.x;
            xs[(j0 + i4 * 4 + 1) * 132 + c] = v.y;
            xs[(j0 + i4 * 4 + 2) * 132 + c] = v.z;
            xs[(j0 + i4 * 4 + 3) * 132 + c] = v.w;
        }
    }
    __syncthreads();

    // GEMM: M=32 (2 tiles), K=128, N=128; wave w owns n0 = w*32 (2 tiles)
    bshort8 a[2][4];
#pragma unroll
    for (int mt = 0; mt < 2; mt++)
#pragma unroll
        for (int ks = 0; ks < 4; ks++)
            a[mt][ks] = *(const bshort8*)(as2 + (mt * 16 + l15) * 136 + ks * 32 + quad * 8);
#pragma unroll
    for (int nt = 0; nt < 2; nt++) {
        int n0 = w * 32 + nt * 16;
        f32x4 acc0 = zero4, acc1 = zero4;
#pragma unroll
        for (int ks = 0; ks < 4; ks++) {
            bshort8 bfr = *(const bshort8*)(wot + (n0 + l15) * 128 + ks * 32 + quad * 8);
            acc0 = __builtin_amdgcn_mfma_f32_16x16x32_bf16(a[0][ks], bfr, acc0, 0, 0, 0);
            acc1 = __builtin_amdgcn_mfma_f32_16x16x32_bf16(a[1][ks], bfr, acc1, 0, 0, 0);
        }
        float bias = wo_b[n0 + l15];
#pragma unroll
        for (int r = 0; r < 4; r++) {
            int m0 = quad * 4 + r;
            int m1 = 16 + quad * 4 + r;
            lpre[((size_t)T0 + m0) * 128 + n0 + l15] = acc0[r] + bias + xs[m0 * 132 + n0 + l15];
            lpre[((size_t)T0 + m1) * 128 + n0 + l15] = acc1[r] + bias + xs[m1 * 132 + n0 + l15];
        }
    }
}

// ---------------- K8: LN + MLP2 via MFMA, 32 tokens/block ----------------
__global__ __launch_bounds__(256) void k_mlp2_mfma(const float* __restrict__ lpre,
        const float* __restrict__ ln_g, const float* __restrict__ ln_b,
        const unsigned short* __restrict__ w1t, const float* __restrict__ b1,
        const unsigned short* __restrict__ w2t, const float* __restrict__ b2,
        float* __restrict__ lout) {
    int blk = blockIdx.x;
    int T0 = blk * 32;
    int b = T0 >> 14;
    int sp = T0 & 16383;
    int t = threadIdx.x; int w = t >> 6; int lane = t & 63;
    int l15 = lane & 15, quad = lane >> 4;
    __shared__ __align__(16) float xs[32 * 132];
    __shared__ __align__(16) unsigned short h[32 * 136];
    __shared__ __align__(16) unsigned short h1[32 * 520];
    float* of32 = (float*)h1;

    {
        int j = t >> 3, p = t & 7, c0 = p * 16;
        const float* src = lpre + ((size_t)T0 + j) * 128 + c0;
        float4 v0 = *(const float4*)(src + 0);
        float4 v1 = *(const float4*)(src + 4);
        float4 v2 = *(const float4*)(src + 8);
        float4 v3 = *(const float4*)(src + 12);
        float s1 = (v0.x + v0.y + v0.z + v0.w) + (v1.x + v1.y + v1.z + v1.w)
                 + (v2.x + v2.y + v2.z + v2.w) + (v3.x + v3.y + v3.z + v3.w);
        s1 = shfl_sum8(s1);
        float mu = s1 * (1.0f / 128.0f);
        float vv[16] = { v0.x, v0.y, v0.z, v0.w, v1.x, v1.y, v1.z, v1.w,
                         v2.x, v2.y, v2.z, v2.w, v3.x, v3.y, v3.z, v3.w };
        float s2 = 0.f;
#pragma unroll
        for (int i = 0; i < 16; i++) { float d = vv[i] - mu; s2 += d * d; }
        s2 = shfl_sum8(s2);
        float rs = rsqrtf(s2 * (1.0f / 128.0f) + LN_EPS);
        *(float4*)&xs[j * 132 + c0 + 0] = v0;
        *(float4*)&xs[j * 132 + c0 + 4] = v1;
        *(float4*)&xs[j * 132 + c0 + 8] = v2;
        *(float4*)&xs[j * 132 + c0 + 12] = v3;
        unsigned short hb[16];
#pragma unroll
        for (int i4 = 0; i4 < 4; i4++) {
            float4 g4 = *(const float4*)(ln_g + c0 + i4 * 4);
            float4 b4 = *(const float4*)(ln_b + c0 + i4 * 4);
            hb[i4 * 4 + 0] = f2bf((vv[i4 * 4 + 0] - mu) * rs * g4.x + b4.x);
            hb[i4 * 4 + 1] = f2bf((vv[i4 * 4 + 1] - mu) * rs * g4.y + b4.y);
            hb[i4 * 4 + 2] = f2bf((vv[i4 * 4 + 2] - mu) * rs * g4.z + b4.z);
            hb[i4 * 4 + 3] = f2bf((vv[i4 * 4 + 3] - mu) * rs * g4.w + b4.w);
        }
        *(ushort4*)&h[j * 136 + c0 + 0] = *(ushort4*)&hb[0];
        *(ushort4*)&h[j * 136 + c0 + 4] = *(ushort4*)&hb[4];
        *(ushort4*)&h[j * 136 + c0 + 8] = *(ushort4*)&hb[8];
        *(ushort4*)&h[j * 136 + c0 + 12] = *(ushort4*)&hb[12];
    }
    __syncthreads();

    f32x4 zero4 = {0.f, 0.f, 0.f, 0.f};
    {
        bshort8 a[2][4];
#pragma unroll
        for (int mt = 0; mt < 2; mt++)
#pragma unroll
            for (int ks = 0; ks < 4; ks++)
                a[mt][ks] = *(const bshort8*)(h + (mt * 16 + l15) * 136 + ks * 32 + quad * 8);
        int n0w = w * 128;
#pragma unroll
        for (int nt = 0; nt < 8; nt++) {
            int n0 = n0w + nt * 16;
            f32x4 acc0 = zero4, acc1 = zero4;
#pragma unroll
            for (int ks = 0; ks < 4; ks++) {
                bshort8 bfr = *(const bshort8*)(w1t + (size_t)(n0 + l15) * 128 + ks * 32 + quad * 8);
                acc0 = __builtin_amdgcn_mfma_f32_16x16x32_bf16(a[0][ks], bfr, acc0, 0, 0, 0);
                acc1 = __builtin_amdgcn_mfma_f32_16x16x32_bf16(a[1][ks], bfr, acc1, 0, 0, 0);
            }
            float bias = b1[n0 + l15];
#pragma unroll
            for (int r = 0; r < 4; r++) {
                h1[(quad * 4 + r) * 520 + n0 + l15] = f2bf(gelu_exact(acc0[r] + bias));
                h1[(16 + quad * 4 + r) * 520 + n0 + l15] = f2bf(gelu_exact(acc1[r] + bias));
            }
        }
    }
    __syncthreads();

    f32x4 acc[2][2];
    acc[0][0] = zero4; acc[0][1] = zero4; acc[1][0] = zero4; acc[1][1] = zero4;
    {
#pragma unroll 4
        for (int ks = 0; ks < 16; ks++) {
            bshort8 a0 = *(const bshort8*)(h1 + (l15) * 520 + ks * 32 + quad * 8);
            bshort8 a1 = *(const bshort8*)(h1 + (16 + l15) * 520 + ks * 32 + quad * 8);
#pragma unroll
            for (int nt = 0; nt < 2; nt++) {
                int n0 = w * 32 + nt * 16;
                bshort8 bfr = *(const bshort8*)(w2t + (size_t)(n0 + l15) * 512 + ks * 32 + quad * 8);
                acc[0][nt] = __builtin_amdgcn_mfma_f32_16x16x32_bf16(a0, bfr, acc[0][nt], 0, 0, 0);
                acc[1][nt] = __builtin_amdgcn_mfma_f32_16x16x32_bf16(a1, bfr, acc[1][nt], 0, 0, 0);
            }
        }
    }
    __syncthreads();

#pragma unroll
    for (int mt = 0; mt < 2; mt++) {
#pragma unroll
        for (int nt = 0; nt < 2; nt++) {
            int n0 = w * 32 + nt * 16;
            float bias = b2[n0 + l15];
#pragma unroll
            for (int r = 0; r < 4; r++) {
                int m = mt * 16 + quad * 4 + r;
                of32[m * 132 + n0 + l15] = xs[m * 132 + n0 + l15] + acc[mt][nt][r] + bias;
            }
        }
    }
    __syncthreads();

    {
        int c = t >> 1, half = t & 1, j0 = half * 16;
        float* dst = lout + ((size_t)(b * 128 + c)) * NSP + sp + j0;
#pragma unroll
        for (int i4 = 0; i4 < 4; i4++) {
            float4 ov = { of32[(j0 + i4 * 4 + 0) * 132 + c], of32[(j0 + i4 * 4 + 1) * 132 + c],
                          of32[(j0 + i4 * 4 + 2) * 132 + c], of32[(j0 + i4 * 4 + 3) * 132 + c] };
            *(float4*)(dst + i4 * 4) = ov;
        }
    }
}

extern "C" void kernel_launch(void* const* d_in, const int* in_sizes, int n_in,
                              void* d_out, int out_size, void* d_ws, size_t ws_size,
                              hipStream_t stream) {
    const float* x_in   = (const float*)d_in[0];
    const float* xg_in  = (const float*)d_in[1];
    const float* qkv_w  = (const float*)d_in[2];
    const float* qkv_b  = (const float*)d_in[3];
    const float* proj_w = (const float*)d_in[4];
    const float* proj_b = (const float*)d_in[5];
    const float* ln_g   = (const float*)d_in[6];
    const float* ln_b   = (const float*)d_in[7];
    const float* mlp_w1 = (const float*)d_in[8];
    const float* mlp_b1 = (const float*)d_in[9];
    const float* mlp_w2 = (const float*)d_in[10];
    const float* mlp_b2 = (const float*)d_in[11];
    const float* rq_w   = (const float*)d_in[12];
    const float* rq_b   = (const float*)d_in[13];
    const float* rk_w   = (const float*)d_in[14];
    const float* rk_b   = (const float*)d_in[15];
    const float* gqkv_w = (const float*)d_in[16];
    const float* gqkv_b = (const float*)d_in[17];
    const float* wo_w   = (const float*)d_in[18];
    const float* wo_b   = (const float*)d_in[19];
    const float* m2_w1  = (const float*)d_in[20];
    const float* m2_b1  = (const float*)d_in[21];
    const float* m2_w2  = (const float*)d_in[22];
    const float* m2_b2  = (const float*)d_in[23];

    float* out = (float*)d_out;
    float* ws  = (float*)d_ws;

    float* xg4 = ws;                                         // 524288
    float* xg  = ws + 524288;                                // 524288
    unsigned short* qgb  = (unsigned short*)(ws + 1048576);  // 524288 bf16
    unsigned short* kgb  = (unsigned short*)(ws + 1310720);  // 524288 bf16
    unsigned short* vgtb = (unsigned short*)(ws + 1572864);  // 524288 bf16 (V^T)
    float* og  = ws + 1835008;                               // 524288
    float* qh  = ws + 2359296;                               // 65536
    float* kh  = ws + 2424832;                               // 65536
    int*   tidx = (int*)(ws + 2490368);                      // 2048
    unsigned short* lnsc = (unsigned short*)(ws + 2492416);  // 6291456 bf16
    float* aout = ws + 2492416 + 3145728;                    // 4194304
    float* lpre = ws + 9832448;                              // 4194304
    unsigned short* wt   = (unsigned short*)(ws + 14026752); // 49152 bf16
    unsigned short* w1t  = (unsigned short*)(ws + 14051328); // 65536 bf16
    unsigned short* w2t  = (unsigned short*)(ws + 14084096); // 65536 bf16
    unsigned short* projt = (unsigned short*)(ws + 14116864); // 16384 bf16
    unsigned short* gw1t  = (unsigned short*)(ws + 14125056); // 65536 bf16
    unsigned short* gw2t  = (unsigned short*)(ws + 14157824); // 65536 bf16
    unsigned short* wot   = (unsigned short*)(ws + 14190592); // 16384 bf16

    const size_t L_OUT = (size_t)BATCH * CDIM * NSP;
    float* gout = out + L_OUT;

    hipLaunchKernelGGL(k_wtrans, dim3(192), dim3(256), 0, stream, gqkv_w, wt);
    hipLaunchKernelGGL(k_wprep_mlp2, dim3(512), dim3(256), 0, stream, m2_w1, m2_w2, w1t, w2t);
    hipLaunchKernelGGL(k_wprep_global, dim3(640), dim3(256), 0, stream,
                       proj_w, mlp_w1, mlp_w2, wo_w, projt, gw1t, gw2t, wot);
    hipLaunchKernelGGL(k_gqkv2, dim3(512), dim3(256), 0, stream,
                       xg_in, qkv_w, qkv_b, ln_g, ln_b, xg, qgb, kgb, vgtb);
    hipLaunchKernelGGL(k_gattn_mfma, dim3(2048), dim3(256), 0, stream, qgb, kgb, vgtb, og);
    hipLaunchKernelGGL(k_gmlp_mfma, dim3(256), dim3(256), 0, stream,
                       og, xg, projt, proj_b, ln_g, ln_b, gw1t, mlp_b1, gw2t, mlp_b2,
                       xg4, gout);
    hipLaunchKernelGGL(k_routing_qk, dim3(512), dim3(128), 0, stream,
                       xg4, rq_w, rq_b, rk_w, rk_b, qh, kh);
    hipLaunchKernelGGL(k_topk, dim3(512), dim3(256), 0, stream, qh, kh, tidx);
    hipLaunchKernelGGL(k_lnsc_local, dim3(2048), dim3(256), 0, stream,
                       x_in, ln_g, ln_b, lnsc);
    hipLaunchKernelGGL(k_lnsc_gath, dim3(2048), dim3(256), 0, stream,
                       xg4, tidx, ln_g, ln_b, lnsc);
    hipLaunchKernelGGL(k_local_mfma, dim3(512), dim3(256), 0, stream,
                       lnsc, wt, gqkv_b, aout);
    hipLaunchKernelGGL(k_wo_mfma, dim3(1024), dim3(256), 0, stream,
                       aout, wot, wo_b, x_in, lpre);
    hipLaunchKernelGGL(k_mlp2_mfma, dim3(1024), dim3(256), 0, stream,
                       lpre, ln_g, ln_b, w1t, m2_b1, w2t, m2_b2, out);
}

// Round 7
// 307.272 us; speedup vs baseline: 8.3972x; 1.0447x over previous
//
#include <hip/hip_runtime.h>
#include <hip/hip_bf16.h>
#include <math.h>

#define BATCH 2
#define CDIM 128
#define SS 16
#define HH_ 32
#define WW_ 32
#define NSP (SS*HH_*WW_)
#define GS 8
#define GH 16
#define GW 16
#define GN (GS*GH*GW)
#define HEADS 8
#define DH 16
#define NW 256
#define W3L 64
#define W3G 8
#define TOPK 4
#define W3 (W3L + TOPK*W3G)
#define LN_EPS 1e-6f
#define ROUTE_SCALE 0.08838834764831845f
#define GATTN_SCALE 0.25f

typedef short bshort8 __attribute__((ext_vector_type(8)));
typedef float f32x4 __attribute__((ext_vector_type(4)));

__device__ __forceinline__ unsigned short f2bf(float f) {
    unsigned int u = __float_as_uint(f);
    unsigned int r = (u + 0x7fffu + ((u >> 16) & 1u)) >> 16;
    return (unsigned short)r;
}
__device__ __forceinline__ float bf2f_lo(unsigned int u) { return __uint_as_float(u << 16); }
__device__ __forceinline__ float bf2f_hi(unsigned int u) { return __uint_as_float(u & 0xffff0000u); }

__device__ __forceinline__ float gelu_exact(float x) {
    return 0.5f * x * (1.0f + erff(x * 0.70710678118654752f));
}

__device__ __forceinline__ float shfl_sum32(float v) {
#pragma unroll
    for (int m = 16; m > 0; m >>= 1) v += __shfl_xor(v, m);
    return v;
}
__device__ __forceinline__ float shfl_sum16(float v) {
#pragma unroll
    for (int m = 8; m > 0; m >>= 1) v += __shfl_xor(v, m);
    return v;
}
__device__ __forceinline__ float shfl_sum8(float v) {
#pragma unroll
    for (int m = 4; m > 0; m >>= 1) v += __shfl_xor(v, m);
    return v;
}

// ---------------- K0: ALL weight prep in one kernel ----------------
// wt:    gqkv_w[128][384] -> [384][128] bf16, ROUTE_SCALE folded into q cols
// w1t:   m2_w1[128][512]  -> [512][128] bf16
// w2t:   m2_w2[512][128]  -> [128][512] bf16
// projt: proj_w[128][128] -> [128][128] bf16
// gw1t:  mlp_w1[128][512] -> [512][128] bf16
// gw2t:  mlp_w2[512][128] -> [128][512] bf16
// wot:   wo_w[128][128]   -> [128][128] bf16
__global__ __launch_bounds__(256) void k_wprep_all(const float* __restrict__ gqkv_w,
        const float* __restrict__ m2_w1, const float* __restrict__ m2_w2,
        const float* __restrict__ proj_w, const float* __restrict__ mlp_w1,
        const float* __restrict__ mlp_w2, const float* __restrict__ wo_w,
        unsigned short* __restrict__ wt, unsigned short* __restrict__ w1t,
        unsigned short* __restrict__ w2t, unsigned short* __restrict__ projt,
        unsigned short* __restrict__ gw1t, unsigned short* __restrict__ gw2t,
        unsigned short* __restrict__ wot) {
    int id = blockIdx.x * 256 + threadIdx.x;   // 0..344063
    if (id < 49152) {
        int n = id >> 7, k = id & 127;
        float v = gqkv_w[k * 384 + n];
        if (n < 128) v *= ROUTE_SCALE;
        wt[id] = f2bf(v);
    } else if (id < 114688) {
        int i = id - 49152; int n = i >> 7, k = i & 127;
        w1t[i] = f2bf(m2_w1[k * 512 + n]);
    } else if (id < 180224) {
        int i = id - 114688; int n = i >> 9, k = i & 511;
        w2t[i] = f2bf(m2_w2[k * 128 + n]);
    } else if (id < 196608) {
        int i = id - 180224; int n = i >> 7, k = i & 127;
        projt[i] = f2bf(proj_w[k * 128 + n]);
    } else if (id < 262144) {
        int i = id - 196608; int n = i >> 7, k = i & 127;
        gw1t[i] = f2bf(mlp_w1[k * 512 + n]);
    } else if (id < 327680) {
        int i = id - 262144; int n = i >> 9, k = i & 511;
        gw2t[i] = f2bf(mlp_w2[k * 128 + n]);
    } else {
        int i = id - 327680; int n = i >> 7, k = i & 127;
        wot[i] = f2bf(wo_w[k * 128 + n]);
    }
}

// ---------------- K1: global branch qkv (T=8 tokens/block), bf16 q/k/v^T out ----------------
__global__ __launch_bounds__(256) void k_gqkv2(const float* __restrict__ xg_in,
        const float* __restrict__ qkv_w, const float* __restrict__ qkv_b,
        const float* __restrict__ ln_g, const float* __restrict__ ln_b,
        float* __restrict__ xg, unsigned short* __restrict__ qgb,
        unsigned short* __restrict__ kgb, unsigned short* __restrict__ vgtb) {
    int blk = blockIdx.x; int b = blk >> 8; int n0 = (blk & 255) * 8;
    int t = threadIdx.x;
    __shared__ float xs[8][128];
    __shared__ float h[8][128];
    {
        int c = t >> 1, q4 = (t & 1) * 4;
        float4 v = *(const float4*)(xg_in + ((size_t)(b * 128 + c)) * GN + n0 + q4);
        xs[q4 + 0][c] = v.x; xs[q4 + 1][c] = v.y; xs[q4 + 2][c] = v.z; xs[q4 + 3][c] = v.w;
    }
    __syncthreads();
    int j = t >> 5, c4 = (t & 31) * 4;
    float4 v = *(float4*)&xs[j][c4];
    *(float4*)(xg + ((size_t)(b * GN) + n0 + j) * 128 + c4) = v;
    float s1 = shfl_sum32(v.x + v.y + v.z + v.w);
    float mu = s1 * (1.0f / 128.0f);
    float d0 = v.x - mu, d1 = v.y - mu, d2 = v.z - mu, d3 = v.w - mu;
    float s2 = shfl_sum32(d0 * d0 + d1 * d1 + d2 * d2 + d3 * d3);
    float rs = rsqrtf(s2 * (1.0f / 128.0f) + LN_EPS);
    float4 g4 = *(const float4*)(ln_g + c4);
    float4 b4 = *(const float4*)(ln_b + c4);
    float4 hn = { d0 * rs * g4.x + b4.x, d1 * rs * g4.y + b4.y,
                  d2 * rs * g4.z + b4.z, d3 * rs * g4.w + b4.w };
    *(float4*)&h[j][c4] = hn;
    __syncthreads();
    for (int c = t; c < 384; c += 256) {
        float acc[8];
        float bias = qkv_b[c];
#pragma unroll
        for (int jj = 0; jj < 8; jj++) acc[jj] = bias;
        for (int k = 0; k < 128; k++) {
            float w = qkv_w[k * 384 + c];
#pragma unroll
            for (int jj = 0; jj < 8; jj++) acc[jj] = fmaf(h[jj][k], w, acc[jj]);
        }
        int part = c >> 7, head = (c >> 4) & 7, d = c & 15;
        int bh = b * HEADS + head;
        if (part == 0) {
#pragma unroll
            for (int jj = 0; jj < 8; jj++)
                qgb[((size_t)bh * GN + n0 + jj) * DH + d] = f2bf(acc[jj] * GATTN_SCALE);
        } else if (part == 1) {
#pragma unroll
            for (int jj = 0; jj < 8; jj++)
                kgb[((size_t)bh * GN + n0 + jj) * DH + d] = f2bf(acc[jj]);
        } else {
            ushort4 u0, u1;
            u0.x = f2bf(acc[0]); u0.y = f2bf(acc[1]); u0.z = f2bf(acc[2]); u0.w = f2bf(acc[3]);
            u1.x = f2bf(acc[4]); u1.y = f2bf(acc[5]); u1.z = f2bf(acc[6]); u1.w = f2bf(acc[7]);
            unsigned short* dst = vgtb + ((size_t)bh * DH + d) * GN + n0;
            *(ushort4*)dst = u0; *(ushort4*)(dst + 4) = u1;
        }
    }
}

// ---------------- K2: global attention via MFMA bf16 ----------------
__global__ __launch_bounds__(256) void k_gattn_mfma(const unsigned short* __restrict__ qgb,
        const unsigned short* __restrict__ kgb, const unsigned short* __restrict__ vgtb,
        float* __restrict__ og) {
    int blk = blockIdx.x;
    int bh = blk >> 7; int qt = (blk & 127) << 4;
    int b = bh >> 3, hh = bh & 7;
    int t = threadIdx.x; int w = t >> 6; int lane = t & 63;
    int col = lane & 15, quad = lane >> 4;
    __shared__ __align__(16) unsigned short Pbuf[4 * 16 * 40];
    __shared__ float po[4][64][4];
    __shared__ float pl[4][64][4];

    bshort8 aq = {0, 0, 0, 0, 0, 0, 0, 0};
    if (quad < 2)
        aq = *(const bshort8*)(qgb + ((size_t)bh * GN + qt + col) * DH + quad * 8);

    f32x4 o = {0.f, 0.f, 0.f, 0.f};
    float lsum[4] = {0.f, 0.f, 0.f, 0.f};
    const unsigned short* kb = kgb + (size_t)bh * GN * DH;
    const unsigned short* vb = vgtb + (size_t)bh * DH * GN;
    unsigned short* pb = Pbuf + w * (16 * 40);
    int row0 = quad * 4;
    int kbeg = w * 512;
    for (int kc = kbeg; kc < kbeg + 512; kc += 32) {
        bshort8 bk0 = {0, 0, 0, 0, 0, 0, 0, 0};
        bshort8 bk1 = {0, 0, 0, 0, 0, 0, 0, 0};
        if (quad < 2) {
            bk0 = *(const bshort8*)(kb + (size_t)(kc + col) * DH + quad * 8);
            bk1 = *(const bshort8*)(kb + (size_t)(kc + 16 + col) * DH + quad * 8);
        }
        f32x4 z = {0.f, 0.f, 0.f, 0.f};
        f32x4 s0 = __builtin_amdgcn_mfma_f32_16x16x32_bf16(aq, bk0, z, 0, 0, 0);
        f32x4 s1 = __builtin_amdgcn_mfma_f32_16x16x32_bf16(aq, bk1, z, 0, 0, 0);
        float p0[4], p1[4];
#pragma unroll
        for (int r = 0; r < 4; r++) {
            p0[r] = __expf(s0[r]); p1[r] = __expf(s1[r]);
            lsum[r] += p0[r] + p1[r];
        }
#pragma unroll
        for (int r = 0; r < 4; r++) {
            pb[(row0 + r) * 40 + col] = f2bf(p0[r]);
            pb[(row0 + r) * 40 + 16 + col] = f2bf(p1[r]);
        }
        bshort8 pA = *(const bshort8*)(pb + col * 40 + quad * 8);
        bshort8 bv = *(const bshort8*)(vb + (size_t)col * GN + kc + quad * 8);
        o = __builtin_amdgcn_mfma_f32_16x16x32_bf16(pA, bv, o, 0, 0, 0);
    }
#pragma unroll
    for (int r = 0; r < 4; r++) {
        float v = lsum[r];
        v += __shfl_xor(v, 1); v += __shfl_xor(v, 2);
        v += __shfl_xor(v, 4); v += __shfl_xor(v, 8);
        lsum[r] = v;
    }
#pragma unroll
    for (int r = 0; r < 4; r++) { po[w][lane][r] = o[r]; pl[w][lane][r] = lsum[r]; }
    __syncthreads();
    if (w == 0) {
#pragma unroll
        for (int r = 0; r < 4; r++) {
            float os = po[0][lane][r] + po[1][lane][r] + po[2][lane][r] + po[3][lane][r];
            float ls = pl[0][lane][r] + pl[1][lane][r] + pl[2][lane][r] + pl[3][lane][r];
            og[((size_t)(b * GN) + qt + quad * 4 + r) * 128 + hh * 16 + col] = os / ls;
        }
    }
}

// ---------------- K3: global proj+residual+LN+MLP via MFMA, 16 tokens/block ----------------
__global__ __launch_bounds__(256) void k_gmlp_mfma(const float* __restrict__ og,
        const float* __restrict__ xg,
        const unsigned short* __restrict__ projt, const float* __restrict__ proj_b,
        const float* __restrict__ ln_g, const float* __restrict__ ln_b,
        const unsigned short* __restrict__ gw1t, const float* __restrict__ b1,
        const unsigned short* __restrict__ gw2t, const float* __restrict__ b2,
        float* __restrict__ xg4, float* __restrict__ gout) {
    int blk = blockIdx.x; int b = blk >> 7; int n0g = (blk & 127) * 16;
    int t = threadIdx.x; int w = t >> 6; int lane = t & 63;
    int l15 = lane & 15, quad = lane >> 4;
    __shared__ __align__(16) unsigned short ao[16 * 136];
    __shared__ __align__(16) float xs[16 * 132];
    __shared__ __align__(16) unsigned short h[16 * 136];
    __shared__ __align__(16) unsigned short h1[16 * 520];
    float* of32 = (float*)h1;
    f32x4 zero4 = {0.f, 0.f, 0.f, 0.f};

    {
        int j = t >> 4, p = t & 15, c0 = p * 8;
        size_t base = ((size_t)(b * GN) + n0g + j) * 128 + c0;
        float4 v0 = *(const float4*)(og + base);
        float4 v1 = *(const float4*)(og + base + 4);
        ushort4 u0 = { f2bf(v0.x), f2bf(v0.y), f2bf(v0.z), f2bf(v0.w) };
        ushort4 u1 = { f2bf(v1.x), f2bf(v1.y), f2bf(v1.z), f2bf(v1.w) };
        *(ushort4*)&ao[j * 136 + c0] = u0;
        *(ushort4*)&ao[j * 136 + c0 + 4] = u1;
        *(float4*)&xs[j * 132 + c0] = *(const float4*)(xg + base);
        *(float4*)&xs[j * 132 + c0 + 4] = *(const float4*)(xg + base + 4);
    }
    __syncthreads();

    {
        bshort8 a[4];
#pragma unroll
        for (int ks = 0; ks < 4; ks++)
            a[ks] = *(const bshort8*)(ao + l15 * 136 + ks * 32 + quad * 8);
#pragma unroll
        for (int nt = 0; nt < 2; nt++) {
            int n0 = w * 32 + nt * 16;
            f32x4 acc = zero4;
#pragma unroll
            for (int ks = 0; ks < 4; ks++) {
                bshort8 bfr = *(const bshort8*)(projt + (n0 + l15) * 128 + ks * 32 + quad * 8);
                acc = __builtin_amdgcn_mfma_f32_16x16x32_bf16(a[ks], bfr, acc, 0, 0, 0);
            }
            float bias = proj_b[n0 + l15];
#pragma unroll
            for (int r = 0; r < 4; r++) {
                int m = quad * 4 + r;
                xs[m * 132 + n0 + l15] += acc[r] + bias;
            }
        }
    }
    __syncthreads();

    {
        int j = t >> 4, p = t & 15, c0 = p * 8;
        float vv[8]; float s1 = 0.f;
#pragma unroll
        for (int i = 0; i < 8; i++) { vv[i] = xs[j * 132 + c0 + i]; s1 += vv[i]; }
        s1 = shfl_sum16(s1);
        float mu = s1 * (1.0f / 128.0f);
        float s2 = 0.f;
#pragma unroll
        for (int i = 0; i < 8; i++) { float d = vv[i] - mu; s2 += d * d; }
        s2 = shfl_sum16(s2);
        float rs = rsqrtf(s2 * (1.0f / 128.0f) + LN_EPS);
        unsigned short hb[8];
#pragma unroll
        for (int i4 = 0; i4 < 2; i4++) {
            float4 g4 = *(const float4*)(ln_g + c0 + i4 * 4);
            float4 b4 = *(const float4*)(ln_b + c0 + i4 * 4);
            hb[i4 * 4 + 0] = f2bf((vv[i4 * 4 + 0] - mu) * rs * g4.x + b4.x);
            hb[i4 * 4 + 1] = f2bf((vv[i4 * 4 + 1] - mu) * rs * g4.y + b4.y);
            hb[i4 * 4 + 2] = f2bf((vv[i4 * 4 + 2] - mu) * rs * g4.z + b4.z);
            hb[i4 * 4 + 3] = f2bf((vv[i4 * 4 + 3] - mu) * rs * g4.w + b4.w);
        }
        *(ushort4*)&h[j * 136 + c0] = *(ushort4*)&hb[0];
        *(ushort4*)&h[j * 136 + c0 + 4] = *(ushort4*)&hb[4];
    }
    __syncthreads();

    {
        bshort8 a[4];
#pragma unroll
        for (int ks = 0; ks < 4; ks++)
            a[ks] = *(const bshort8*)(h + l15 * 136 + ks * 32 + quad * 8);
#pragma unroll
        for (int nt = 0; nt < 8; nt++) {
            int n0 = w * 128 + nt * 16;
            f32x4 acc = zero4;
#pragma unroll
            for (int ks = 0; ks < 4; ks++) {
                bshort8 bfr = *(const bshort8*)(gw1t + (size_t)(n0 + l15) * 128 + ks * 32 + quad * 8);
                acc = __builtin_amdgcn_mfma_f32_16x16x32_bf16(a[ks], bfr, acc, 0, 0, 0);
            }
            float bias = b1[n0 + l15];
#pragma unroll
            for (int r = 0; r < 4; r++)
                h1[(quad * 4 + r) * 520 + n0 + l15] = f2bf(gelu_exact(acc[r] + bias));
        }
    }
    __syncthreads();

    f32x4 acc2[2]; acc2[0] = zero4; acc2[1] = zero4;
#pragma unroll 4
    for (int ks = 0; ks < 16; ks++) {
        bshort8 a = *(const bshort8*)(h1 + l15 * 520 + ks * 32 + quad * 8);
#pragma unroll
        for (int nt = 0; nt < 2; nt++) {
            int n0 = w * 32 + nt * 16;
            bshort8 bfr = *(const bshort8*)(gw2t + (size_t)(n0 + l15) * 512 + ks * 32 + quad * 8);
            acc2[nt] = __builtin_amdgcn_mfma_f32_16x16x32_bf16(a, bfr, acc2[nt], 0, 0, 0);
        }
    }
    __syncthreads();

    {
#pragma unroll
        for (int nt = 0; nt < 2; nt++) {
            int n0 = w * 32 + nt * 16;
            float bias = b2[n0 + l15];
#pragma unroll
            for (int r = 0; r < 4; r++) {
                int m = quad * 4 + r;
                float ov = xs[m * 132 + n0 + l15] + acc2[nt][r] + bias;
                of32[m * 132 + n0 + l15] = ov;
                xg4[((size_t)(b * GN) + n0g + m) * 128 + n0 + l15] = ov;
            }
        }
    }
    __syncthreads();

    {
        int cw = t >> 1, hf = t & 1, j0 = hf * 8;
        float* dst = gout + ((size_t)(b * 128 + cw)) * GN + n0g + j0;
#pragma unroll
        for (int i4 = 0; i4 < 2; i4++) {
            float4 ov = { of32[(j0 + i4 * 4 + 0) * 132 + cw], of32[(j0 + i4 * 4 + 1) * 132 + cw],
                          of32[(j0 + i4 * 4 + 2) * 132 + cw], of32[(j0 + i4 * 4 + 3) * 132 + cw] };
            *(float4*)(dst + i4 * 4) = ov;
        }
    }
}

// ---------------- K4a: routing q/k ----------------
__global__ void k_routing_qk(const float* __restrict__ xg4,
                             const float* __restrict__ rq_w, const float* __restrict__ rq_b,
                             const float* __restrict__ rk_w, const float* __restrict__ rk_b,
                             float* __restrict__ qh, float* __restrict__ kh) {
    int wid = blockIdx.x; int b = wid / NW, n = wid % NW;
    int c = threadIdx.x;
    int i1 = n / 64, i2 = (n / 8) % 8, i3 = n % 8;
    __shared__ float g[CDIM];
    float s = 0.f;
#pragma unroll
    for (int j = 0; j < W3G; j++) {
        int ds = j >> 2, dh = (j >> 1) & 1, dw = j & 1;
        int gi = ((i1 * 2 + ds) * GH + (i2 * 2 + dh)) * GW + (i3 * 2 + dw);
        s += xg4[((size_t)(b * GN + gi)) * CDIM + c];
    }
    g[c] = s * (1.0f / W3G);
    __syncthreads();
    float aq = rq_b[c], ak = rk_b[c];
    for (int k = 0; k < CDIM; k++) { float gv = g[k]; aq = fmaf(gv, rq_w[k * CDIM + c], aq); ak = fmaf(gv, rk_w[k * CDIM + c], ak); }
    qh[(size_t)wid * CDIM + c] = aq;
    kh[(size_t)wid * CDIM + c] = ak;
}

// ---------------- K4b: top-k ----------------
__global__ void k_topk(const float* __restrict__ qh, const float* __restrict__ kh,
                       int* __restrict__ tidx) {
    int wid = blockIdx.x; int b = wid / NW;
    int m = threadIdx.x;
    __shared__ float q[CDIM];
    __shared__ float lv[NW];
    __shared__ int li[NW];
    if (m < CDIM) q[m] = qh[(size_t)wid * CDIM + m] * ROUTE_SCALE;
    __syncthreads();
    float acc = 0.f;
    const float* kr = kh + ((size_t)b * NW + m) * CDIM;
    for (int k = 0; k < CDIM; k++) acc = fmaf(q[k], kr[k], acc);
#pragma unroll
    for (int sel = 0; sel < TOPK; sel++) {
        lv[m] = acc; li[m] = m; __syncthreads();
#pragma unroll
        for (int s = 128; s > 0; s >>= 1) {
            if (m < s) {
                if (lv[m + s] > lv[m] || (lv[m + s] == lv[m] && li[m + s] < li[m])) {
                    lv[m] = lv[m + s]; li[m] = li[m + s];
                }
            }
            __syncthreads();
        }
        int best = li[0]; __syncthreads();
        if (m == best) acc = -1e30f;
        if (m == 0) tidx[wid * TOPK + sel] = best;
    }
}

// ---------------- K5a: LN local tokens -> lnsc bf16 ----------------
__global__ __launch_bounds__(256) void k_lnsc_local(const float* __restrict__ x_in,
        const float* __restrict__ ln_g, const float* __restrict__ ln_b,
        unsigned short* __restrict__ lnsc) {
    int blk = blockIdx.x;
    int wt = blk & 1; int hh = (blk >> 1) & 31; int s = (blk >> 6) & 15; int b = blk >> 10;
    int w0 = wt * 16;
    int t = threadIdx.x;
    __shared__ float tile[16][132];
    {
        int c = t >> 1; int wq = (t & 1) * 8;
        const float* src = x_in + (((size_t)(b * 128 + c) * SS + s)) * 1024 + hh * 32 + w0 + wq;
        float4 v0 = *(const float4*)src;
        float4 v1 = *(const float4*)(src + 4);
        tile[wq + 0][c] = v0.x; tile[wq + 1][c] = v0.y; tile[wq + 2][c] = v0.z; tile[wq + 3][c] = v0.w;
        tile[wq + 4][c] = v1.x; tile[wq + 5][c] = v1.y; tile[wq + 6][c] = v1.z; tile[wq + 7][c] = v1.w;
    }
    __syncthreads();
    int w = t >> 4; int j = t & 15;
    float vals[8];
    float s1 = 0.f;
#pragma unroll
    for (int i = 0; i < 8; i++) { vals[i] = tile[w][j * 8 + i]; s1 += vals[i]; }
    s1 = shfl_sum16(s1);
    float mu = s1 * (1.0f / 128.0f);
    float s2 = 0.f;
#pragma unroll
    for (int i = 0; i < 8; i++) { float d = vals[i] - mu; s2 += d * d; }
    s2 = shfl_sum16(s2);
    float rs = rsqrtf(s2 * (1.0f / 128.0f) + LN_EPS);
    float4 g0 = *(const float4*)(ln_g + j * 8);
    float4 g1 = *(const float4*)(ln_g + j * 8 + 4);
    float4 b0 = *(const float4*)(ln_b + j * 8);
    float4 b1 = *(const float4*)(ln_b + j * 8 + 4);
    float gv[8] = { g0.x, g0.y, g0.z, g0.w, g1.x, g1.y, g1.z, g1.w };
    float bv[8] = { b0.x, b0.y, b0.z, b0.w, b1.x, b1.y, b1.z, b1.w };
    int ww = w0 + w;
    int n = (s >> 2) * 64 + (hh >> 2) * 8 + (ww >> 2);
    int slot = (s & 3) * 16 + (hh & 3) * 4 + (ww & 3);
    unsigned short* dst = lnsc + ((size_t)(b * NW + n) * W3 + slot) * 128 + j * 8;
    ushort4 u0, u1;
    u0.x = f2bf((vals[0] - mu) * rs * gv[0] + bv[0]);
    u0.y = f2bf((vals[1] - mu) * rs * gv[1] + bv[1]);
    u0.z = f2bf((vals[2] - mu) * rs * gv[2] + bv[2]);
    u0.w = f2bf((vals[3] - mu) * rs * gv[3] + bv[3]);
    u1.x = f2bf((vals[4] - mu) * rs * gv[4] + bv[4]);
    u1.y = f2bf((vals[5] - mu) * rs * gv[5] + bv[5]);
    u1.z = f2bf((vals[6] - mu) * rs * gv[6] + bv[6]);
    u1.w = f2bf((vals[7] - mu) * rs * gv[7] + bv[7]);
    *(ushort4*)dst = u0;
    *(ushort4*)(dst + 4) = u1;
}

// ---------------- K5b: LN gathered global tokens -> lnsc bf16 ----------------
__global__ __launch_bounds__(256) void k_lnsc_gath(const float* __restrict__ xg4,
        const int* __restrict__ tidx,
        const float* __restrict__ ln_g, const float* __restrict__ ln_b,
        unsigned short* __restrict__ lnsc) {
    int blk = blockIdx.x;
    int kk = blk & 3; int wn = blk >> 2;
    int b = wn >> 8;
    int g = tidx[wn * TOPK + kk];
    int gi1 = g >> 6, gi2 = (g >> 3) & 7, gi3 = g & 7;
    int t = threadIdx.x; int j = t >> 5, lj = t & 31;
    int ds = j >> 2, dh = (j >> 1) & 1, dw = j & 1;
    int gi = ((gi1 * 2 + ds) * GH + (gi2 * 2 + dh)) * GW + (gi3 * 2 + dw);
    float4 v = *(const float4*)(xg4 + ((size_t)(b * GN + gi)) * 128 + lj * 4);
    float s1 = shfl_sum32(v.x + v.y + v.z + v.w);
    float mu = s1 * (1.0f / 128.0f);
    float d0 = v.x - mu, d1 = v.y - mu, d2 = v.z - mu, d3 = v.w - mu;
    float s2 = shfl_sum32(d0 * d0 + d1 * d1 + d2 * d2 + d3 * d3);
    float rs = rsqrtf(s2 * (1.0f / 128.0f) + LN_EPS);
    float4 g4 = *(const float4*)(ln_g + lj * 4);
    float4 b4 = *(const float4*)(ln_b + lj * 4);
    ushort4 u;
    u.x = f2bf(d0 * rs * g4.x + b4.x);
    u.y = f2bf(d1 * rs * g4.y + b4.y);
    u.z = f2bf(d2 * rs * g4.z + b4.z);
    u.w = f2bf(d3 * rs * g4.w + b4.w);
    *(ushort4*)(lnsc + ((size_t)wn * W3 + 64 + kk * 8 + j) * 128 + lj * 4) = u;
}

// ---------------- K6: local attention via MFMA ----------------
__global__ __launch_bounds__(256) void k_local_mfma(const unsigned short* __restrict__ lnsc,
        const unsigned short* __restrict__ wt, const float* __restrict__ gqkv_b,
        float* __restrict__ aout) {
    int wn = blockIdx.x;
    int t = threadIdx.x; int w = t >> 6; int lane = t & 63;
    int l15 = lane & 15, quad = lane >> 4;
    __shared__ __align__(16) unsigned short Qs[64 * 136];
    __shared__ __align__(16) unsigned short Ks2[96 * 136];
    __shared__ __align__(16) unsigned short Vts[128 * 104];
    __shared__ __align__(16) unsigned short Ps[4][16 * 40];

    const unsigned short* Xb = lnsc + (size_t)wn * W3 * 128;
    f32x4 zero4 = {0.f, 0.f, 0.f, 0.f};

    for (int mt = 0; mt < 4; mt++) {
        bshort8 a[4];
#pragma unroll
        for (int ks = 0; ks < 4; ks++)
            a[ks] = *(const bshort8*)(Xb + (mt * 16 + l15) * 128 + ks * 32 + quad * 8);
#pragma unroll
        for (int which = 0; which < 2; which++) {
            int n0 = (w + which * 4) * 16;
            f32x4 acc = zero4;
#pragma unroll
            for (int ks = 0; ks < 4; ks++) {
                bshort8 bfr = *(const bshort8*)(wt + (n0 + l15) * 128 + ks * 32 + quad * 8);
                acc = __builtin_amdgcn_mfma_f32_16x16x32_bf16(a[ks], bfr, acc, 0, 0, 0);
            }
            float bias = gqkv_b[n0 + l15] * ROUTE_SCALE;
#pragma unroll
            for (int r = 0; r < 4; r++)
                Qs[(mt * 16 + quad * 4 + r) * 136 + n0 + l15] = f2bf(acc[r] + bias);
        }
    }
    for (int mt = 0; mt < 6; mt++) {
        bshort8 a[4];
#pragma unroll
        for (int ks = 0; ks < 4; ks++)
            a[ks] = *(const bshort8*)(Xb + (mt * 16 + l15) * 128 + ks * 32 + quad * 8);
#pragma unroll
        for (int which = 0; which < 2; which++) {
            int nt8 = w + which * 4;
            int n0g = 128 + nt8 * 16;
            f32x4 acc = zero4;
#pragma unroll
            for (int ks = 0; ks < 4; ks++) {
                bshort8 bfr = *(const bshort8*)(wt + (n0g + l15) * 128 + ks * 32 + quad * 8);
                acc = __builtin_amdgcn_mfma_f32_16x16x32_bf16(a[ks], bfr, acc, 0, 0, 0);
            }
            float bias = gqkv_b[n0g + l15];
#pragma unroll
            for (int r = 0; r < 4; r++)
                Ks2[(mt * 16 + quad * 4 + r) * 136 + nt8 * 16 + l15] = f2bf(acc[r] + bias);
        }
    }
    for (int which = 0; which < 2; which++) {
        int mtv = 2 * w + which;
        bshort8 a[4];
#pragma unroll
        for (int ks = 0; ks < 4; ks++)
            a[ks] = *(const bshort8*)(wt + (256 + mtv * 16 + l15) * 128 + ks * 32 + quad * 8);
        float biasr[4];
#pragma unroll
        for (int r = 0; r < 4; r++) biasr[r] = gqkv_b[256 + mtv * 16 + quad * 4 + r];
        for (int ntv = 0; ntv < 6; ntv++) {
            f32x4 acc = zero4;
#pragma unroll
            for (int ks = 0; ks < 4; ks++) {
                bshort8 bfr = *(const bshort8*)(Xb + (ntv * 16 + l15) * 128 + ks * 32 + quad * 8);
                acc = __builtin_amdgcn_mfma_f32_16x16x32_bf16(a[ks], bfr, acc, 0, 0, 0);
            }
#pragma unroll
            for (int r = 0; r < 4; r++)
                Vts[(mtv * 16 + quad * 4 + r) * 104 + ntv * 16 + l15] = f2bf(acc[r] + biasr[r]);
        }
    }
    __syncthreads();

    unsigned short* Pw = &Ps[w][0];
    bshort8 zfrag = {0, 0, 0, 0, 0, 0, 0, 0};
#pragma unroll
    for (int hh2 = 0; hh2 < 2; hh2++) {
        int h = 2 * w + hh2;
        for (int mt = 0; mt < 4; mt++) {
            bshort8 aq = zfrag;
            if (quad < 2)
                aq = *(const bshort8*)(Qs + (mt * 16 + l15) * 136 + h * 16 + quad * 8);
            float rsum[4] = {0.f, 0.f, 0.f, 0.f};
            f32x4 oacc = zero4;
#pragma unroll
            for (int kc = 0; kc < 96; kc += 32) {
#pragma unroll
                for (int sub = 0; sub < 2; sub++) {
                    int nt = (kc >> 4) + sub;
                    bshort8 bk = zfrag;
                    if (quad < 2)
                        bk = *(const bshort8*)(Ks2 + (nt * 16 + l15) * 136 + h * 16 + quad * 8);
                    f32x4 s = __builtin_amdgcn_mfma_f32_16x16x32_bf16(aq, bk, zero4, 0, 0, 0);
#pragma unroll
                    for (int r = 0; r < 4; r++) {
                        float p = __expf(s[r]);
                        rsum[r] += p;
                        Pw[(quad * 4 + r) * 40 + sub * 16 + l15] = f2bf(p);
                    }
                }
                bshort8 ap = *(const bshort8*)(Pw + l15 * 40 + quad * 8);
                bshort8 bv = *(const bshort8*)(Vts + (h * 16 + l15) * 104 + kc + quad * 8);
                oacc = __builtin_amdgcn_mfma_f32_16x16x32_bf16(ap, bv, oacc, 0, 0, 0);
            }
#pragma unroll
            for (int r = 0; r < 4; r++) {
                float v = rsum[r];
                v += __shfl_xor(v, 1); v += __shfl_xor(v, 2);
                v += __shfl_xor(v, 4); v += __shfl_xor(v, 8);
                rsum[r] = v;
            }
#pragma unroll
            for (int r = 0; r < 4; r++)
                aout[((size_t)wn * W3L + mt * 16 + quad * 4 + r) * 128 + h * 16 + l15]
                    = oacc[r] / rsum[r];
        }
    }
}

// ---------------- K7: wo projection + shortcut via MFMA, 32 spatial tokens/block ----------------
__global__ __launch_bounds__(256) void k_wo_mfma(const float* __restrict__ aout,
        const unsigned short* __restrict__ wot, const float* __restrict__ wo_b,
        const float* __restrict__ x_in, float* __restrict__ lpre) {
    int blk = blockIdx.x; int T0 = blk * 32;
    int b = T0 >> 14; int sp0 = T0 & 16383;
    int t = threadIdx.x; int w = t >> 6; int lane = t & 63;
    int l15 = lane & 15, quad = lane >> 4;
    __shared__ __align__(16) unsigned short as2[32 * 136];
    __shared__ __align__(16) float xs[32 * 132];
    f32x4 zero4 = {0.f, 0.f, 0.f, 0.f};

    {
        int j = t >> 3, p = t & 7, c0 = p * 16;
        int sp = sp0 + j;
        int s = sp >> 10, hh = (sp >> 5) & 31, ww = sp & 31;
        int n = (s >> 2) * 64 + (hh >> 2) * 8 + (ww >> 2);
        int slot = (s & 3) * 16 + (hh & 3) * 4 + (ww & 3);
        const float* src = aout + (((size_t)(b * NW + n)) * W3L + slot) * 128 + c0;
#pragma unroll
        for (int i4 = 0; i4 < 4; i4++) {
            float4 v = *(const float4*)(src + i4 * 4);
            ushort4 u = { f2bf(v.x), f2bf(v.y), f2bf(v.z), f2bf(v.w) };
            *(ushort4*)&as2[j * 136 + c0 + i4 * 4] = u;
        }
    }
    {
        int c = t >> 1, half = t & 1, j0 = half * 16;
        const float* src = x_in + ((size_t)(b * 128 + c)) * 16384 + sp0 + j0;
#pragma unroll
        for (int i4 = 0; i4 < 4; i4++) {
            float4 v = *(const float4*)(src + i4 * 4);
            xs[(j0 + i4 * 4 + 0) * 132 + c] = v.x;
            xs[(j0 + i4 * 4 + 1) * 132 + c] = v.y;
            xs[(j0 + i4 * 4 + 2) * 132 + c] = v.z;
            xs[(j0 + i4 * 4 + 3) * 132 + c] = v.w;
        }
    }
    __syncthreads();

    bshort8 a[2][4];
#pragma unroll
    for (int mt = 0; mt < 2; mt++)
#pragma unroll
        for (int ks = 0; ks < 4; ks++)
            a[mt][ks] = *(const bshort8*)(as2 + (mt * 16 + l15) * 136 + ks * 32 + quad * 8);
#pragma unroll
    for (int nt = 0; nt < 2; nt++) {
        int n0 = w * 32 + nt * 16;
        f32x4 acc0 = zero4, acc1 = zero4;
#pragma unroll
        for (int ks = 0; ks < 4; ks++) {
            bshort8 bfr = *(const bshort8*)(wot + (n0 + l15) * 128 + ks * 32 + quad * 8);
            acc0 = __builtin_amdgcn_mfma_f32_16x16x32_bf16(a[0][ks], bfr, acc0, 0, 0, 0);
            acc1 = __builtin_amdgcn_mfma_f32_16x16x32_bf16(a[1][ks], bfr, acc1, 0, 0, 0);
        }
        float bias = wo_b[n0 + l15];
#pragma unroll
        for (int r = 0; r < 4; r++) {
            int m0 = quad * 4 + r;
            int m1 = 16 + quad * 4 + r;
            lpre[((size_t)T0 + m0) * 128 + n0 + l15] = acc0[r] + bias + xs[m0 * 132 + n0 + l15];
            lpre[((size_t)T0 + m1) * 128 + n0 + l15] = acc1[r] + bias + xs[m1 * 132 + n0 + l15];
        }
    }
}

// ---------------- K8: LN + MLP2 via MFMA, 32 tokens/block, single aliased LDS buffer ----------------
// buf serves as: h (stride 136, 8.7 KB) -> h1 (stride 520, 33.3 KB) -> of32 fp32 (stride 132, 16.9 KB)
// LDS total 33280 B -> 4 blocks/CU.
__global__ __launch_bounds__(256) void k_mlp2_mfma(const float* __restrict__ lpre,
        const float* __restrict__ ln_g, const float* __restrict__ ln_b,
        const unsigned short* __restrict__ w1t, const float* __restrict__ b1,
        const unsigned short* __restrict__ w2t, const float* __restrict__ b2,
        float* __restrict__ lout) {
    int blk = blockIdx.x;
    int T0 = blk * 32;
    int b = T0 >> 14;
    int sp = T0 & 16383;
    int t = threadIdx.x; int w = t >> 6; int lane = t & 63;
    int l15 = lane & 15, quad = lane >> 4;
    __shared__ __align__(16) unsigned short buf[32 * 520];
    float* of32 = (float*)buf;

    // phase 0: load lpre coalesced + LN -> h (bf16, stride 136) in buf
    {
        int j = t >> 3, p = t & 7, c0 = p * 16;
        const float* src = lpre + ((size_t)T0 + j) * 128 + c0;
        float4 v0 = *(const float4*)(src + 0);
        float4 v1 = *(const float4*)(src + 4);
        float4 v2 = *(const float4*)(src + 8);
        float4 v3 = *(const float4*)(src + 12);
        float s1 = (v0.x + v0.y + v0.z + v0.w) + (v1.x + v1.y + v1.z + v1.w)
                 + (v2.x + v2.y + v2.z + v2.w) + (v3.x + v3.y + v3.z + v3.w);
        s1 = shfl_sum8(s1);
        float mu = s1 * (1.0f / 128.0f);
        float vv[16] = { v0.x, v0.y, v0.z, v0.w, v1.x, v1.y, v1.z, v1.w,
                         v2.x, v2.y, v2.z, v2.w, v3.x, v3.y, v3.z, v3.w };
        float s2 = 0.f;
#pragma unroll
        for (int i = 0; i < 16; i++) { float d = vv[i] - mu; s2 += d * d; }
        s2 = shfl_sum8(s2);
        float rs = rsqrtf(s2 * (1.0f / 128.0f) + LN_EPS);
        unsigned short hb[16];
#pragma unroll
        for (int i4 = 0; i4 < 4; i4++) {
            float4 g4 = *(const float4*)(ln_g + c0 + i4 * 4);
            float4 b4 = *(const float4*)(ln_b + c0 + i4 * 4);
            hb[i4 * 4 + 0] = f2bf((vv[i4 * 4 + 0] - mu) * rs * g4.x + b4.x);
            hb[i4 * 4 + 1] = f2bf((vv[i4 * 4 + 1] - mu) * rs * g4.y + b4.y);
            hb[i4 * 4 + 2] = f2bf((vv[i4 * 4 + 2] - mu) * rs * g4.z + b4.z);
            hb[i4 * 4 + 3] = f2bf((vv[i4 * 4 + 3] - mu) * rs * g4.w + b4.w);
        }
        *(ushort4*)&buf[j * 136 + c0 + 0] = *(ushort4*)&hb[0];
        *(ushort4*)&buf[j * 136 + c0 + 4] = *(ushort4*)&hb[4];
        *(ushort4*)&buf[j * 136 + c0 + 8] = *(ushort4*)&hb[8];
        *(ushort4*)&buf[j * 136 + c0 + 12] = *(ushort4*)&hb[12];
    }
    __syncthreads();

    // load GEMM1 A-fragments into registers, then free buf for h1
    bshort8 a1[2][4];
#pragma unroll
    for (int mt = 0; mt < 2; mt++)
#pragma unroll
        for (int ks = 0; ks < 4; ks++)
            a1[mt][ks] = *(const bshort8*)(buf + (mt * 16 + l15) * 136 + ks * 32 + quad * 8);
    __syncthreads();

    // GEMM1 + gelu -> h1 (bf16, stride 520) in buf; wave w owns n in [w*128, w*128+128)
    f32x4 zero4 = {0.f, 0.f, 0.f, 0.f};
    {
        int n0w = w * 128;
#pragma unroll
        for (int nt = 0; nt < 8; nt++) {
            int n0 = n0w + nt * 16;
            f32x4 acc0 = zero4, acc1 = zero4;
#pragma unroll
            for (int ks = 0; ks < 4; ks++) {
                bshort8 bfr = *(const bshort8*)(w1t + (size_t)(n0 + l15) * 128 + ks * 32 + quad * 8);
                acc0 = __builtin_amdgcn_mfma_f32_16x16x32_bf16(a1[0][ks], bfr, acc0, 0, 0, 0);
                acc1 = __builtin_amdgcn_mfma_f32_16x16x32_bf16(a1[1][ks], bfr, acc1, 0, 0, 0);
            }
            float bias = b1[n0 + l15];
#pragma unroll
            for (int r = 0; r < 4; r++) {
                buf[(quad * 4 + r) * 520 + n0 + l15] = f2bf(gelu_exact(acc0[r] + bias));
                buf[(16 + quad * 4 + r) * 520 + n0 + l15] = f2bf(gelu_exact(acc1[r] + bias));
            }
        }
    }
    __syncthreads();

    // GEMM2: reads h1 from buf; wave w owns n in [w*32, w*32+32)
    f32x4 acc[2][2];
    acc[0][0] = zero4; acc[0][1] = zero4; acc[1][0] = zero4; acc[1][1] = zero4;
    {
#pragma unroll 4
        for (int ks = 0; ks < 16; ks++) {
            bshort8 a0 = *(const bshort8*)(buf + (l15) * 520 + ks * 32 + quad * 8);
            bshort8 a1b = *(const bshort8*)(buf + (16 + l15) * 520 + ks * 32 + quad * 8);
#pragma unroll
            for (int nt = 0; nt < 2; nt++) {
                int n0 = w * 32 + nt * 16;
                bshort8 bfr = *(const bshort8*)(w2t + (size_t)(n0 + l15) * 512 + ks * 32 + quad * 8);
                acc[0][nt] = __builtin_amdgcn_mfma_f32_16x16x32_bf16(a0, bfr, acc[0][nt], 0, 0, 0);
                acc[1][nt] = __builtin_amdgcn_mfma_f32_16x16x32_bf16(a1b, bfr, acc[1][nt], 0, 0, 0);
            }
        }
    }
    __syncthreads();   // h1 reads done; of32 may overwrite

    // epilogue: residual re-read from global lpre (L2-hot) + bias -> of32 (stride 132)
#pragma unroll
    for (int mt = 0; mt < 2; mt++) {
#pragma unroll
        for (int nt = 0; nt < 2; nt++) {
            int n0 = w * 32 + nt * 16;
            float bias = b2[n0 + l15];
#pragma unroll
            for (int r = 0; r < 4; r++) {
                int m = mt * 16 + quad * 4 + r;
                float res = lpre[((size_t)T0 + m) * 128 + n0 + l15];
                of32[m * 132 + n0 + l15] = res + acc[mt][nt][r] + bias;
            }
        }
    }
    __syncthreads();

    // transposed coalesced write
    {
        int c = t >> 1, half = t & 1, j0 = half * 16;
        float* dst = lout + ((size_t)(b * 128 + c)) * NSP + sp + j0;
#pragma unroll
        for (int i4 = 0; i4 < 4; i4++) {
            float4 ov = { of32[(j0 + i4 * 4 + 0) * 132 + c], of32[(j0 + i4 * 4 + 1) * 132 + c],
                          of32[(j0 + i4 * 4 + 2) * 132 + c], of32[(j0 + i4 * 4 + 3) * 132 + c] };
            *(float4*)(dst + i4 * 4) = ov;
        }
    }
}

extern "C" void kernel_launch(void* const* d_in, const int* in_sizes, int n_in,
                              void* d_out, int out_size, void* d_ws, size_t ws_size,
                              hipStream_t stream) {
    const float* x_in   = (const float*)d_in[0];
    const float* xg_in  = (const float*)d_in[1];
    const float* qkv_w  = (const float*)d_in[2];
    const float* qkv_b  = (const float*)d_in[3];
    const float* proj_w = (const float*)d_in[4];
    const float* proj_b = (const float*)d_in[5];
    const float* ln_g   = (const float*)d_in[6];
    const float* ln_b   = (const float*)d_in[7];
    const float* mlp_w1 = (const float*)d_in[8];
    const float* mlp_b1 = (const float*)d_in[9];
    const float* mlp_w2 = (const float*)d_in[10];
    const float* mlp_b2 = (const float*)d_in[11];
    const float* rq_w   = (const float*)d_in[12];
    const float* rq_b   = (const float*)d_in[13];
    const float* rk_w   = (const float*)d_in[14];
    const float* rk_b   = (const float*)d_in[15];
    const float* gqkv_w = (const float*)d_in[16];
    const float* gqkv_b = (const float*)d_in[17];
    const float* wo_w   = (const float*)d_in[18];
    const float* wo_b   = (const float*)d_in[19];
    const float* m2_w1  = (const float*)d_in[20];
    const float* m2_b1  = (const float*)d_in[21];
    const float* m2_w2  = (const float*)d_in[22];
    const float* m2_b2  = (const float*)d_in[23];

    float* out = (float*)d_out;
    float* ws  = (float*)d_ws;

    float* xg4 = ws;                                         // 524288
    float* xg  = ws + 524288;                                // 524288
    unsigned short* qgb  = (unsigned short*)(ws + 1048576);  // 524288 bf16
    unsigned short* kgb  = (unsigned short*)(ws + 1310720);  // 524288 bf16
    unsigned short* vgtb = (unsigned short*)(ws + 1572864);  // 524288 bf16 (V^T)
    float* og  = ws + 1835008;                               // 524288
    float* qh  = ws + 2359296;                               // 65536
    float* kh  = ws + 2424832;                               // 65536
    int*   tidx = (int*)(ws + 2490368);                      // 2048
    unsigned short* lnsc = (unsigned short*)(ws + 2492416);  // 6291456 bf16
    float* aout = ws + 2492416 + 3145728;                    // 4194304
    float* lpre = ws + 9832448;                              // 4194304
    unsigned short* wt   = (unsigned short*)(ws + 14026752); // 49152 bf16
    unsigned short* w1t  = (unsigned short*)(ws + 14051328); // 65536 bf16
    unsigned short* w2t  = (unsigned short*)(ws + 14084096); // 65536 bf16
    unsigned short* projt = (unsigned short*)(ws + 14116864); // 16384 bf16
    unsigned short* gw1t  = (unsigned short*)(ws + 14125056); // 65536 bf16
    unsigned short* gw2t  = (unsigned short*)(ws + 14157824); // 65536 bf16
    unsigned short* wot   = (unsigned short*)(ws + 14190592); // 16384 bf16

    const size_t L_OUT = (size_t)BATCH * CDIM * NSP;
    float* gout = out + L_OUT;

    hipLaunchKernelGGL(k_wprep_all, dim3(1344), dim3(256), 0, stream,
                       gqkv_w, m2_w1, m2_w2, proj_w, mlp_w1, mlp_w2, wo_w,
                       wt, w1t, w2t, projt, gw1t, gw2t, wot);
    hipLaunchKernelGGL(k_gqkv2, dim3(512), dim3(256), 0, stream,
                       xg_in, qkv_w, qkv_b, ln_g, ln_b, xg, qgb, kgb, vgtb);
    hipLaunchKernelGGL(k_gattn_mfma, dim3(2048), dim3(256), 0, stream, qgb, kgb, vgtb, og);
    hipLaunchKernelGGL(k_gmlp_mfma, dim3(256), dim3(256), 0, stream,
                       og, xg, projt, proj_b, ln_g, ln_b, gw1t, mlp_b1, gw2t, mlp_b2,
                       xg4, gout);
    hipLaunchKernelGGL(k_routing_qk, dim3(512), dim3(128), 0, stream,
                       xg4, rq_w, rq_b, rk_w, rk_b, qh, kh);
    hipLaunchKernelGGL(k_topk, dim3(512), dim3(256), 0, stream, qh, kh, tidx);
    hipLaunchKernelGGL(k_lnsc_local, dim3(2048), dim3(256), 0, stream,
                       x_in, ln_g, ln_b, lnsc);
    hipLaunchKernelGGL(k_lnsc_gath, dim3(2048), dim3(256), 0, stream,
                       xg4, tidx, ln_g, ln_b, lnsc);
    hipLaunchKernelGGL(k_local_mfma, dim3(512), dim3(256), 0, stream,
                       lnsc, wt, gqkv_b, aout);
    hipLaunchKernelGGL(k_wo_mfma, dim3(1024), dim3(256), 0, stream,
                       aout, wot, wo_b, x_in, lpre);
    hipLaunchKernelGGL(k_mlp2_mfma, dim3(1024), dim3(256), 0, stream,
                       lpre, ln_g, ln_b, w1t, m2_b1, w2t, m2_b2, out);
}